// Round 1
// baseline (1146.807 us; speedup 1.0000x reference)
//
#include <hip/hip_runtime.h>
#include <math.h>

#define HID 128
#define TILE_ROWS 64

// ---------------------------------------------------------------------------
// CSR build: count in-degrees
__global__ __launch_bounds__(256) void count_kernel(const int* __restrict__ dst,
                                                    int* __restrict__ cnt, int nE) {
    int e = blockIdx.x * 256 + threadIdx.x;
    if (e < nE) atomicAdd(&cnt[dst[e]], 1);
}

// dinv[v] = rsqrt(indeg + 1)  (self loop adds 1; always > 0)
__global__ __launch_bounds__(256) void dinv_kernel(const int* __restrict__ cnt,
                                                   float* __restrict__ dinv, int nN) {
    int v = blockIdx.x * 256 + threadIdx.x;
    if (v < nN) dinv[v] = rsqrtf((float)cnt[v] + 1.0f);
}

// single-block exclusive scan of cnt -> rowptr (nN up to ~100k)
__global__ __launch_bounds__(1024) void scan_kernel(const int* __restrict__ cnt,
                                                    int* __restrict__ rowptr, int nN, int nE) {
    __shared__ int sums[1024];
    const int t = threadIdx.x;
    const int chunk = (nN + 1023) / 1024;
    const int s0 = t * chunk;
    const int s1 = min(s0 + chunk, nN);
    int local = 0;
    for (int i = s0; i < s1; ++i) local += cnt[i];
    sums[t] = local;
    __syncthreads();
    for (int off = 1; off < 1024; off <<= 1) {
        int v = sums[t];
        int add = (t >= off) ? sums[t - off] : 0;
        __syncthreads();
        sums[t] = v + add;
        __syncthreads();
    }
    int run = (t > 0) ? sums[t - 1] : 0;  // exclusive base
    for (int i = s0; i < s1; ++i) { rowptr[i] = run; run += cnt[i]; }
    if (t == 1023) rowptr[nN] = nE;
}

// scatter edge src ids into CSR order (cur must be zeroed)
__global__ __launch_bounds__(256) void scatter_kernel(const int* __restrict__ src,
                                                      const int* __restrict__ dst,
                                                      const int* __restrict__ rowptr,
                                                      int* __restrict__ cur,
                                                      int* __restrict__ ssrc, int nE) {
    int e = blockIdx.x * 256 + threadIdx.x;
    if (e < nE) {
        int d = dst[e];
        int pos = rowptr[d] + atomicAdd(&cur[d], 1);
        ssrc[pos] = src[e];
    }
}

// ---------------------------------------------------------------------------
// P = dinv ⊙ (X @ W); 64-row tile per block, 256 threads, thread = 4 rows x 8 cols
__global__ __launch_bounds__(256) void gemm_scale_kernel(const float* __restrict__ X,
                                                         const float* __restrict__ W,
                                                         const float* __restrict__ dinv,
                                                         float* __restrict__ P, int nN) {
    __shared__ float Xs[128 * 65];  // transposed tile Xs[k][row], pad 65 -> conflict-free reads
    const int tid = threadIdx.x;
    const int rowBase = blockIdx.x * TILE_ROWS;
    // stage 64x128 tile, transposed
#pragma unroll
    for (int it = 0; it < 8; ++it) {
        int f4 = it * 256 + tid;
        int row = f4 >> 5;            // 0..63
        int kc = (f4 & 31) << 2;      // 0,4,...,124
        int grow = rowBase + row;
        float4 v = make_float4(0.f, 0.f, 0.f, 0.f);
        if (grow < nN) v = *(const float4*)(X + (size_t)grow * HID + kc);
        Xs[(kc + 0) * 65 + row] = v.x;
        Xs[(kc + 1) * 65 + row] = v.y;
        Xs[(kc + 2) * 65 + row] = v.z;
        Xs[(kc + 3) * 65 + row] = v.w;
    }
    __syncthreads();
    const int tx = tid & 15;   // col group: cols tx*8 .. tx*8+7
    const int ty = tid >> 4;   // row group: rows ty*4 .. ty*4+3
    float acc[4][8];
#pragma unroll
    for (int r = 0; r < 4; ++r)
#pragma unroll
        for (int c = 0; c < 8; ++c) acc[r][c] = 0.f;
    const float* Wp = W + tx * 8;
#pragma unroll 2
    for (int k = 0; k < 128; ++k) {
        float4 w0 = *(const float4*)(Wp + k * HID);
        float4 w1 = *(const float4*)(Wp + k * HID + 4);
        float xr[4];
#pragma unroll
        for (int r = 0; r < 4; ++r) xr[r] = Xs[k * 65 + ty * 4 + r];
#pragma unroll
        for (int r = 0; r < 4; ++r) {
            acc[r][0] = fmaf(xr[r], w0.x, acc[r][0]);
            acc[r][1] = fmaf(xr[r], w0.y, acc[r][1]);
            acc[r][2] = fmaf(xr[r], w0.z, acc[r][2]);
            acc[r][3] = fmaf(xr[r], w0.w, acc[r][3]);
            acc[r][4] = fmaf(xr[r], w1.x, acc[r][4]);
            acc[r][5] = fmaf(xr[r], w1.y, acc[r][5]);
            acc[r][6] = fmaf(xr[r], w1.z, acc[r][6]);
            acc[r][7] = fmaf(xr[r], w1.w, acc[r][7]);
        }
    }
#pragma unroll
    for (int r = 0; r < 4; ++r) {
        int grow = rowBase + ty * 4 + r;
        if (grow < nN) {
            float dv = dinv[grow];
            float4 o0, o1;
            o0.x = dv * acc[r][0]; o0.y = dv * acc[r][1];
            o0.z = dv * acc[r][2]; o0.w = dv * acc[r][3];
            o1.x = dv * acc[r][4]; o1.y = dv * acc[r][5];
            o1.z = dv * acc[r][6]; o1.w = dv * acc[r][7];
            *(float4*)(P + (size_t)grow * HID + tx * 8) = o0;
            *(float4*)(P + (size_t)grow * HID + tx * 8 + 4) = o1;
        }
    }
}

// ---------------------------------------------------------------------------
// Xout[v] = relu(dinv[v]*(P[v] + sum_{in-edges} P[src]) + b); 32 lanes per node
__global__ __launch_bounds__(256) void agg_kernel(const float* __restrict__ P,
                                                  const int* __restrict__ rowptr,
                                                  const int* __restrict__ ssrc,
                                                  const float* __restrict__ dinv,
                                                  const float* __restrict__ bias,
                                                  float* __restrict__ Xout, int nN) {
    const int lane = threadIdx.x & 31;
    const int grp = threadIdx.x >> 5;
    const int v = blockIdx.x * 8 + grp;
    if (v >= nN) return;
    const float4* P4 = (const float4*)P;
    float4 acc = P4[(size_t)v * 32 + lane];
    const int e0 = rowptr[v], e1 = rowptr[v + 1];
    for (int e = e0; e < e1; ++e) {
        int u = ssrc[e];
        float4 pu = P4[(size_t)u * 32 + lane];
        acc.x += pu.x; acc.y += pu.y; acc.z += pu.z; acc.w += pu.w;
    }
    const float dv = dinv[v];
    const float4 bb = ((const float4*)bias)[lane];
    float4 o;
    o.x = fmaxf(fmaf(dv, acc.x, bb.x), 0.f);
    o.y = fmaxf(fmaf(dv, acc.y, bb.y), 0.f);
    o.z = fmaxf(fmaf(dv, acc.z, bb.z), 0.f);
    o.w = fmaxf(fmaf(dv, acc.w, bb.w), 0.f);
    ((float4*)Xout)[(size_t)v * 32 + lane] = o;
}

// ---------------------------------------------------------------------------
// global mean pool; one block per graph, batch ids are sorted
__global__ __launch_bounds__(128) void pool_kernel(const float* __restrict__ X,
                                                   const int* __restrict__ batch,
                                                   float* __restrict__ pooled, int nN) {
    const int g = blockIdx.x;
    int lo = 0, hi = nN;
    while (lo < hi) { int m = (lo + hi) >> 1; if (batch[m] < g) lo = m + 1; else hi = m; }
    const int start = lo;
    hi = nN;
    while (lo < hi) { int m = (lo + hi) >> 1; if (batch[m] < g + 1) lo = m + 1; else hi = m; }
    const int end = lo;
    float acc = 0.f;
    for (int n = start; n < end; ++n) acc += X[(size_t)n * HID + threadIdx.x];
    const float c = (float)max(end - start, 1);
    pooled[g * HID + threadIdx.x] = acc / c;
}

// ---------------------------------------------------------------------------
// single-step LSTM from zero state + FC(2); f-gate irrelevant (c0=0)
__device__ __forceinline__ float sigmoidf_(float x) { return 1.0f / (1.0f + expf(-x)); }

__global__ __launch_bounds__(128) void lstm_fc_kernel(const float* __restrict__ pooled,
                                                      const float* __restrict__ W_ih,
                                                      const float* __restrict__ b_ih,
                                                      const float* __restrict__ b_hh,
                                                      const float* __restrict__ W_fc,
                                                      const float* __restrict__ b_fc,
                                                      float* __restrict__ out) {
    __shared__ float pv[HID];
    __shared__ float r0[2], r1[2];
    const int g = blockIdx.x, j = threadIdx.x;
    pv[j] = pooled[g * HID + j];
    __syncthreads();
    float di = b_ih[j] + b_hh[j];                 // i gate, rows 0..127
    float dg = b_ih[256 + j] + b_hh[256 + j];     // g gate, rows 256..383
    float dO = b_ih[384 + j] + b_hh[384 + j];     // o gate, rows 384..511
    const float4* pv4 = (const float4*)pv;
#pragma unroll 4
    for (int k4 = 0; k4 < 32; ++k4) {
        float4 p = pv4[k4];
        float4 wi = *(const float4*)(W_ih + (size_t)j * HID + k4 * 4);
        float4 wg = *(const float4*)(W_ih + (size_t)(256 + j) * HID + k4 * 4);
        float4 wo = *(const float4*)(W_ih + (size_t)(384 + j) * HID + k4 * 4);
        di += p.x * wi.x + p.y * wi.y + p.z * wi.z + p.w * wi.w;
        dg += p.x * wg.x + p.y * wg.y + p.z * wg.z + p.w * wg.w;
        dO += p.x * wo.x + p.y * wo.y + p.z * wo.z + p.w * wo.w;
    }
    float c = sigmoidf_(di) * tanhf(dg);
    float hn = sigmoidf_(dO) * tanhf(c);
    float p0 = hn * W_fc[j];
    float p1 = hn * W_fc[HID + j];
#pragma unroll
    for (int off = 32; off > 0; off >>= 1) {
        p0 += __shfl_down(p0, off, 64);
        p1 += __shfl_down(p1, off, 64);
    }
    const int w = j >> 6, l = j & 63;
    if (l == 0) { r0[w] = p0; r1[w] = p1; }
    __syncthreads();
    if (j == 0) {
        out[g * 2 + 0] = r0[0] + r0[1] + b_fc[0];
        out[g * 2 + 1] = r1[0] + r1[1] + b_fc[1];
    }
}

// ---------------------------------------------------------------------------
extern "C" void kernel_launch(void* const* d_in, const int* in_sizes, int n_in,
                              void* d_out, int out_size, void* d_ws, size_t ws_size,
                              hipStream_t stream) {
    const float* x      = (const float*)d_in[0];
    const int*   eidx   = (const int*)d_in[1];
    const int*   batch  = (const int*)d_in[2];
    const float* W0     = (const float*)d_in[4];
    const float* b0     = (const float*)d_in[5];
    const float* W1     = (const float*)d_in[6];
    const float* b1     = (const float*)d_in[7];
    const float* W2     = (const float*)d_in[8];
    const float* b2     = (const float*)d_in[9];
    const float* W_ih   = (const float*)d_in[10];
    const float* b_ih   = (const float*)d_in[12];
    const float* b_hh   = (const float*)d_in[13];
    const float* W_fc   = (const float*)d_in[14];
    const float* b_fc   = (const float*)d_in[15];
    float* out = (float*)d_out;

    const int nN = in_sizes[0] / HID;     // 100000
    const int nE = in_sizes[1] / 2;       // 1600000
    const int nG = out_size / 2;          // 256
    const int* src = eidx;
    const int* dst = eidx + nE;

    // workspace layout
    size_t off = 0;
    auto alloc = [&](size_t bytes) -> void* {
        void* p = (char*)d_ws + off;
        off += (bytes + 255) & ~(size_t)255;
        return p;
    };
    float* P      = (float*)alloc((size_t)nN * HID * sizeof(float));
    float* B0     = (float*)alloc((size_t)nN * HID * sizeof(float));
    float* dinv   = (float*)alloc((size_t)nN * sizeof(float));
    int*   cnt    = (int*)alloc((size_t)nN * sizeof(int));
    int*   rowptr = (int*)alloc((size_t)(nN + 1) * sizeof(int));
    int*   ssrc   = (int*)alloc((size_t)nE * sizeof(int));
    float* pooled = (float*)alloc((size_t)nG * HID * sizeof(float));
    (void)ws_size;

    const int eBlocks = (nE + 255) / 256;
    const int nBlocks = (nN + 255) / 256;

    // CSR build + dinv
    hipMemsetAsync(cnt, 0, (size_t)nN * sizeof(int), stream);
    count_kernel<<<eBlocks, 256, 0, stream>>>(dst, cnt, nE);
    dinv_kernel<<<nBlocks, 256, 0, stream>>>(cnt, dinv, nN);
    scan_kernel<<<1, 1024, 0, stream>>>(cnt, rowptr, nN, nE);
    hipMemsetAsync(cnt, 0, (size_t)nN * sizeof(int), stream);
    scatter_kernel<<<eBlocks, 256, 0, stream>>>(src, dst, rowptr, cnt, ssrc, nE);

    const int gemmBlocks = (nN + TILE_ROWS - 1) / TILE_ROWS;
    const int aggBlocks = (nN + 7) / 8;

    // layer 0
    gemm_scale_kernel<<<gemmBlocks, 256, 0, stream>>>(x, W0, dinv, P, nN);
    agg_kernel<<<aggBlocks, 256, 0, stream>>>(P, rowptr, ssrc, dinv, b0, B0, nN);
    // layer 1
    gemm_scale_kernel<<<gemmBlocks, 256, 0, stream>>>(B0, W1, dinv, P, nN);
    agg_kernel<<<aggBlocks, 256, 0, stream>>>(P, rowptr, ssrc, dinv, b1, B0, nN);
    // layer 2
    gemm_scale_kernel<<<gemmBlocks, 256, 0, stream>>>(B0, W2, dinv, P, nN);
    agg_kernel<<<aggBlocks, 256, 0, stream>>>(P, rowptr, ssrc, dinv, b2, B0, nN);

    // pool + LSTM + FC
    pool_kernel<<<nG, 128, 0, stream>>>(B0, batch, pooled, nN);
    lstm_fc_kernel<<<nG, 128, 0, stream>>>(pooled, W_ih, b_ih, b_hh, W_fc, b_fc, out);
}

// Round 2
// 1001.875 us; speedup vs baseline: 1.1447x; 1.1447x over previous
//
#include <hip/hip_runtime.h>
#include <math.h>

#define HID 128
#define TILE_ROWS 64
#define SCAN_CHUNK 1024   // elements per scan block (256 thr x 4)

// ---------------------------------------------------------------------------
// CSR build: count in-degrees
__global__ __launch_bounds__(256) void count_kernel(const int* __restrict__ dst,
                                                    int* __restrict__ cnt, int nE) {
    int e = blockIdx.x * 256 + threadIdx.x;
    if (e < nE) atomicAdd(&cnt[dst[e]], 1);
}

// ---------------------------------------------------------------------------
// Hierarchical scan, phase 1: per-block sums of cnt (1024 elems/block) + fused dinv
__global__ __launch_bounds__(256) void scan_phase1(const int* __restrict__ cnt,
                                                   int* __restrict__ blockSums,
                                                   float* __restrict__ dinv, int nN) {
    __shared__ int sdata[256];
    const int t = threadIdx.x;
    const int idx = blockIdx.x * SCAN_CHUNK + t * 4;
    int v0 = 0, v1 = 0, v2 = 0, v3 = 0;
    if (idx + 3 < nN) {
        int4 v = *(const int4*)(cnt + idx);
        v0 = v.x; v1 = v.y; v2 = v.z; v3 = v.w;
        float4 dv;
        dv.x = rsqrtf((float)v0 + 1.0f);
        dv.y = rsqrtf((float)v1 + 1.0f);
        dv.z = rsqrtf((float)v2 + 1.0f);
        dv.w = rsqrtf((float)v3 + 1.0f);
        *(float4*)(dinv + idx) = dv;
    } else {
        if (idx     < nN) { v0 = cnt[idx];     dinv[idx]     = rsqrtf((float)v0 + 1.0f); }
        if (idx + 1 < nN) { v1 = cnt[idx + 1]; dinv[idx + 1] = rsqrtf((float)v1 + 1.0f); }
        if (idx + 2 < nN) { v2 = cnt[idx + 2]; dinv[idx + 2] = rsqrtf((float)v2 + 1.0f); }
        if (idx + 3 < nN) { v3 = cnt[idx + 3]; dinv[idx + 3] = rsqrtf((float)v3 + 1.0f); }
    }
    sdata[t] = v0 + v1 + v2 + v3;
    __syncthreads();
#pragma unroll
    for (int off = 128; off > 0; off >>= 1) {
        if (t < off) sdata[t] += sdata[t + off];
        __syncthreads();
    }
    if (t == 0) blockSums[blockIdx.x] = sdata[0];
}

// phase 2: single small block converts blockSums -> exclusive offsets (nB <= 256)
__global__ __launch_bounds__(256) void scan_phase2(int* __restrict__ blockSums, int nB) {
    __shared__ int sd[256];
    const int t = threadIdx.x;
    sd[t] = (t < nB) ? blockSums[t] : 0;
    __syncthreads();
#pragma unroll
    for (int off = 1; off < 256; off <<= 1) {
        int v = sd[t];
        int add = (t >= off) ? sd[t - off] : 0;
        __syncthreads();
        sd[t] = v + add;
        __syncthreads();
    }
    if (t < nB) blockSums[t] = (t > 0) ? sd[t - 1] : 0;  // exclusive
}

// phase 3: per-block exclusive scan + global offset -> rowptr
__global__ __launch_bounds__(256) void scan_phase3(const int* __restrict__ cnt,
                                                   const int* __restrict__ blockOffsets,
                                                   int* __restrict__ rowptr, int nN, int nE) {
    __shared__ int sdata[256];
    const int t = threadIdx.x;
    const int idx = blockIdx.x * SCAN_CHUNK + t * 4;
    int v0 = 0, v1 = 0, v2 = 0, v3 = 0;
    if (idx + 3 < nN) {
        int4 v = *(const int4*)(cnt + idx);
        v0 = v.x; v1 = v.y; v2 = v.z; v3 = v.w;
    } else {
        if (idx     < nN) v0 = cnt[idx];
        if (idx + 1 < nN) v1 = cnt[idx + 1];
        if (idx + 2 < nN) v2 = cnt[idx + 2];
        if (idx + 3 < nN) v3 = cnt[idx + 3];
    }
    sdata[t] = v0 + v1 + v2 + v3;
    __syncthreads();
#pragma unroll
    for (int off = 1; off < 256; off <<= 1) {
        int v = sdata[t];
        int add = (t >= off) ? sdata[t - off] : 0;
        __syncthreads();
        sdata[t] = v + add;
        __syncthreads();
    }
    const int pre = blockOffsets[blockIdx.x] + ((t > 0) ? sdata[t - 1] : 0);
    if (idx + 3 < nN) {
        *(int4*)(rowptr + idx) = make_int4(pre, pre + v0, pre + v0 + v1, pre + v0 + v1 + v2);
    } else {
        if (idx     < nN) rowptr[idx]     = pre;
        if (idx + 1 < nN) rowptr[idx + 1] = pre + v0;
        if (idx + 2 < nN) rowptr[idx + 2] = pre + v0 + v1;
        if (idx + 3 < nN) rowptr[idx + 3] = pre + v0 + v1 + v2;
    }
    if (blockIdx.x == 0 && t == 0) rowptr[nN] = nE;
}

// scatter edge src ids into CSR order (cur must be zeroed)
__global__ __launch_bounds__(256) void scatter_kernel(const int* __restrict__ src,
                                                      const int* __restrict__ dst,
                                                      const int* __restrict__ rowptr,
                                                      int* __restrict__ cur,
                                                      int* __restrict__ ssrc, int nE) {
    int e = blockIdx.x * 256 + threadIdx.x;
    if (e < nE) {
        int d = dst[e];
        int pos = rowptr[d] + atomicAdd(&cur[d], 1);
        ssrc[pos] = src[e];
    }
}

// ---------------------------------------------------------------------------
// P = dinv ⊙ (X @ W); 64-row tile per block, 256 threads, thread = 4 rows x 8 cols
__global__ __launch_bounds__(256) void gemm_scale_kernel(const float* __restrict__ X,
                                                         const float* __restrict__ W,
                                                         const float* __restrict__ dinv,
                                                         float* __restrict__ P, int nN) {
    __shared__ float Xs[128 * 65];  // transposed tile Xs[k][row], pad 65 -> conflict-free reads
    const int tid = threadIdx.x;
    const int rowBase = blockIdx.x * TILE_ROWS;
#pragma unroll
    for (int it = 0; it < 8; ++it) {
        int f4 = it * 256 + tid;
        int row = f4 >> 5;            // 0..63
        int kc = (f4 & 31) << 2;      // 0,4,...,124
        int grow = rowBase + row;
        float4 v = make_float4(0.f, 0.f, 0.f, 0.f);
        if (grow < nN) v = *(const float4*)(X + (size_t)grow * HID + kc);
        Xs[(kc + 0) * 65 + row] = v.x;
        Xs[(kc + 1) * 65 + row] = v.y;
        Xs[(kc + 2) * 65 + row] = v.z;
        Xs[(kc + 3) * 65 + row] = v.w;
    }
    __syncthreads();
    const int tx = tid & 15;   // col group: cols tx*8 .. tx*8+7
    const int ty = tid >> 4;   // row group: rows ty*4 .. ty*4+3
    float acc[4][8];
#pragma unroll
    for (int r = 0; r < 4; ++r)
#pragma unroll
        for (int c = 0; c < 8; ++c) acc[r][c] = 0.f;
    const float* Wp = W + tx * 8;
#pragma unroll 2
    for (int k = 0; k < 128; ++k) {
        float4 w0 = *(const float4*)(Wp + k * HID);
        float4 w1 = *(const float4*)(Wp + k * HID + 4);
        float xr[4];
#pragma unroll
        for (int r = 0; r < 4; ++r) xr[r] = Xs[k * 65 + ty * 4 + r];
#pragma unroll
        for (int r = 0; r < 4; ++r) {
            acc[r][0] = fmaf(xr[r], w0.x, acc[r][0]);
            acc[r][1] = fmaf(xr[r], w0.y, acc[r][1]);
            acc[r][2] = fmaf(xr[r], w0.z, acc[r][2]);
            acc[r][3] = fmaf(xr[r], w0.w, acc[r][3]);
            acc[r][4] = fmaf(xr[r], w1.x, acc[r][4]);
            acc[r][5] = fmaf(xr[r], w1.y, acc[r][5]);
            acc[r][6] = fmaf(xr[r], w1.z, acc[r][6]);
            acc[r][7] = fmaf(xr[r], w1.w, acc[r][7]);
        }
    }
#pragma unroll
    for (int r = 0; r < 4; ++r) {
        int grow = rowBase + ty * 4 + r;
        if (grow < nN) {
            float dv = dinv[grow];
            float4 o0, o1;
            o0.x = dv * acc[r][0]; o0.y = dv * acc[r][1];
            o0.z = dv * acc[r][2]; o0.w = dv * acc[r][3];
            o1.x = dv * acc[r][4]; o1.y = dv * acc[r][5];
            o1.z = dv * acc[r][6]; o1.w = dv * acc[r][7];
            *(float4*)(P + (size_t)grow * HID + tx * 8) = o0;
            *(float4*)(P + (size_t)grow * HID + tx * 8 + 4) = o1;
        }
    }
}

// ---------------------------------------------------------------------------
// Xout[v] = relu(dinv[v]*(P[v] + sum_{in-edges} P[src]) + b); 32 lanes per node
__global__ __launch_bounds__(256) void agg_kernel(const float* __restrict__ P,
                                                  const int* __restrict__ rowptr,
                                                  const int* __restrict__ ssrc,
                                                  const float* __restrict__ dinv,
                                                  const float* __restrict__ bias,
                                                  float* __restrict__ Xout, int nN) {
    const int lane = threadIdx.x & 31;
    const int grp = threadIdx.x >> 5;
    const int v = blockIdx.x * 8 + grp;
    if (v >= nN) return;
    const float4* P4 = (const float4*)P;
    float4 acc = P4[(size_t)v * 32 + lane];
    const int e0 = rowptr[v], e1 = rowptr[v + 1];
    for (int e = e0; e < e1; ++e) {
        int u = ssrc[e];
        float4 pu = P4[(size_t)u * 32 + lane];
        acc.x += pu.x; acc.y += pu.y; acc.z += pu.z; acc.w += pu.w;
    }
    const float dv = dinv[v];
    const float4 bb = ((const float4*)bias)[lane];
    float4 o;
    o.x = fmaxf(fmaf(dv, acc.x, bb.x), 0.f);
    o.y = fmaxf(fmaf(dv, acc.y, bb.y), 0.f);
    o.z = fmaxf(fmaf(dv, acc.z, bb.z), 0.f);
    o.w = fmaxf(fmaf(dv, acc.w, bb.w), 0.f);
    ((float4*)Xout)[(size_t)v * 32 + lane] = o;
}

// ---------------------------------------------------------------------------
// global mean pool; one block per graph, batch ids are sorted
__global__ __launch_bounds__(128) void pool_kernel(const float* __restrict__ X,
                                                   const int* __restrict__ batch,
                                                   float* __restrict__ pooled, int nN) {
    const int g = blockIdx.x;
    int lo = 0, hi = nN;
    while (lo < hi) { int m = (lo + hi) >> 1; if (batch[m] < g) lo = m + 1; else hi = m; }
    const int start = lo;
    hi = nN;
    while (lo < hi) { int m = (lo + hi) >> 1; if (batch[m] < g + 1) lo = m + 1; else hi = m; }
    const int end = lo;
    float acc = 0.f;
    for (int n = start; n < end; ++n) acc += X[(size_t)n * HID + threadIdx.x];
    const float c = (float)max(end - start, 1);
    pooled[g * HID + threadIdx.x] = acc / c;
}

// ---------------------------------------------------------------------------
// single-step LSTM from zero state + FC(2); f-gate irrelevant (c0=0)
__device__ __forceinline__ float sigmoidf_(float x) { return 1.0f / (1.0f + expf(-x)); }

__global__ __launch_bounds__(128) void lstm_fc_kernel(const float* __restrict__ pooled,
                                                      const float* __restrict__ W_ih,
                                                      const float* __restrict__ b_ih,
                                                      const float* __restrict__ b_hh,
                                                      const float* __restrict__ W_fc,
                                                      const float* __restrict__ b_fc,
                                                      float* __restrict__ out) {
    __shared__ float pv[HID];
    __shared__ float r0[2], r1[2];
    const int g = blockIdx.x, j = threadIdx.x;
    pv[j] = pooled[g * HID + j];
    __syncthreads();
    float di = b_ih[j] + b_hh[j];                 // i gate, rows 0..127
    float dg = b_ih[256 + j] + b_hh[256 + j];     // g gate, rows 256..383
    float dO = b_ih[384 + j] + b_hh[384 + j];     // o gate, rows 384..511
    const float4* pv4 = (const float4*)pv;
#pragma unroll 4
    for (int k4 = 0; k4 < 32; ++k4) {
        float4 p = pv4[k4];
        float4 wi = *(const float4*)(W_ih + (size_t)j * HID + k4 * 4);
        float4 wg = *(const float4*)(W_ih + (size_t)(256 + j) * HID + k4 * 4);
        float4 wo = *(const float4*)(W_ih + (size_t)(384 + j) * HID + k4 * 4);
        di += p.x * wi.x + p.y * wi.y + p.z * wi.z + p.w * wi.w;
        dg += p.x * wg.x + p.y * wg.y + p.z * wg.z + p.w * wg.w;
        dO += p.x * wo.x + p.y * wo.y + p.z * wo.z + p.w * wo.w;
    }
    float c = sigmoidf_(di) * tanhf(dg);
    float hn = sigmoidf_(dO) * tanhf(c);
    float p0 = hn * W_fc[j];
    float p1 = hn * W_fc[HID + j];
#pragma unroll
    for (int off = 32; off > 0; off >>= 1) {
        p0 += __shfl_down(p0, off, 64);
        p1 += __shfl_down(p1, off, 64);
    }
    const int w = j >> 6, l = j & 63;
    if (l == 0) { r0[w] = p0; r1[w] = p1; }
    __syncthreads();
    if (j == 0) {
        out[g * 2 + 0] = r0[0] + r0[1] + b_fc[0];
        out[g * 2 + 1] = r1[0] + r1[1] + b_fc[1];
    }
}

// ---------------------------------------------------------------------------
extern "C" void kernel_launch(void* const* d_in, const int* in_sizes, int n_in,
                              void* d_out, int out_size, void* d_ws, size_t ws_size,
                              hipStream_t stream) {
    const float* x      = (const float*)d_in[0];
    const int*   eidx   = (const int*)d_in[1];
    const int*   batch  = (const int*)d_in[2];
    const float* W0     = (const float*)d_in[4];
    const float* b0     = (const float*)d_in[5];
    const float* W1     = (const float*)d_in[6];
    const float* b1     = (const float*)d_in[7];
    const float* W2     = (const float*)d_in[8];
    const float* b2     = (const float*)d_in[9];
    const float* W_ih   = (const float*)d_in[10];
    const float* b_ih   = (const float*)d_in[12];
    const float* b_hh   = (const float*)d_in[13];
    const float* W_fc   = (const float*)d_in[14];
    const float* b_fc   = (const float*)d_in[15];
    float* out = (float*)d_out;

    const int nN = in_sizes[0] / HID;     // 100000
    const int nE = in_sizes[1] / 2;       // 1600000
    const int nG = out_size / 2;          // 256
    const int* src = eidx;
    const int* dst = eidx + nE;

    // workspace layout
    size_t off = 0;
    auto alloc = [&](size_t bytes) -> void* {
        void* p = (char*)d_ws + off;
        off += (bytes + 255) & ~(size_t)255;
        return p;
    };
    float* P      = (float*)alloc((size_t)nN * HID * sizeof(float));
    float* B0     = (float*)alloc((size_t)nN * HID * sizeof(float));
    float* dinv   = (float*)alloc((size_t)nN * sizeof(float));
    int*   cnt    = (int*)alloc((size_t)nN * sizeof(int));
    int*   rowptr = (int*)alloc((size_t)(nN + 1) * sizeof(int));
    int*   ssrc   = (int*)alloc((size_t)nE * sizeof(int));
    float* pooled = (float*)alloc((size_t)nG * HID * sizeof(float));
    int*   blockSums = (int*)alloc(1024 * sizeof(int));
    (void)ws_size;

    const int eBlocks = (nE + 255) / 256;
    const int scanBlocks = (nN + SCAN_CHUNK - 1) / SCAN_CHUNK;   // 98 for nN=100000

    // CSR build + dinv
    hipMemsetAsync(cnt, 0, (size_t)nN * sizeof(int), stream);
    count_kernel<<<eBlocks, 256, 0, stream>>>(dst, cnt, nE);
    scan_phase1<<<scanBlocks, 256, 0, stream>>>(cnt, blockSums, dinv, nN);
    scan_phase2<<<1, 256, 0, stream>>>(blockSums, scanBlocks);
    scan_phase3<<<scanBlocks, 256, 0, stream>>>(cnt, blockSums, rowptr, nN, nE);
    hipMemsetAsync(cnt, 0, (size_t)nN * sizeof(int), stream);
    scatter_kernel<<<eBlocks, 256, 0, stream>>>(src, dst, rowptr, cnt, ssrc, nE);

    const int gemmBlocks = (nN + TILE_ROWS - 1) / TILE_ROWS;
    const int aggBlocks = (nN + 7) / 8;

    // layer 0
    gemm_scale_kernel<<<gemmBlocks, 256, 0, stream>>>(x, W0, dinv, P, nN);
    agg_kernel<<<aggBlocks, 256, 0, stream>>>(P, rowptr, ssrc, dinv, b0, B0, nN);
    // layer 1
    gemm_scale_kernel<<<gemmBlocks, 256, 0, stream>>>(B0, W1, dinv, P, nN);
    agg_kernel<<<aggBlocks, 256, 0, stream>>>(P, rowptr, ssrc, dinv, b1, B0, nN);
    // layer 2
    gemm_scale_kernel<<<gemmBlocks, 256, 0, stream>>>(B0, W2, dinv, P, nN);
    agg_kernel<<<aggBlocks, 256, 0, stream>>>(P, rowptr, ssrc, dinv, b2, B0, nN);

    // pool + LSTM + FC
    pool_kernel<<<nG, 128, 0, stream>>>(B0, batch, pooled, nN);
    lstm_fc_kernel<<<nG, 128, 0, stream>>>(pooled, W_ih, b_ih, b_hh, W_fc, b_fc, out);
}

// Round 3
// 984.050 us; speedup vs baseline: 1.1654x; 1.0181x over previous
//
#include <hip/hip_runtime.h>
#include <math.h>

#define HID 128
#define TILE_ROWS 64
#define SCAN_CHUNK 1024   // elements per scan block (256 thr x 4)

// ---------------------------------------------------------------------------
// CSR build: count in-degrees
__global__ __launch_bounds__(256) void count_kernel(const int* __restrict__ dst,
                                                    int* __restrict__ cnt, int nE) {
    int e = blockIdx.x * 256 + threadIdx.x;
    if (e < nE) atomicAdd(&cnt[dst[e]], 1);
}

// ---------------------------------------------------------------------------
// Hierarchical scan, phase 1: per-block sums of cnt (1024 elems/block) + fused dinv
__global__ __launch_bounds__(256) void scan_phase1(const int* __restrict__ cnt,
                                                   int* __restrict__ blockSums,
                                                   float* __restrict__ dinv, int nN) {
    __shared__ int sdata[256];
    const int t = threadIdx.x;
    const int idx = blockIdx.x * SCAN_CHUNK + t * 4;
    int v0 = 0, v1 = 0, v2 = 0, v3 = 0;
    if (idx + 3 < nN) {
        int4 v = *(const int4*)(cnt + idx);
        v0 = v.x; v1 = v.y; v2 = v.z; v3 = v.w;
        float4 dv;
        dv.x = rsqrtf((float)v0 + 1.0f);
        dv.y = rsqrtf((float)v1 + 1.0f);
        dv.z = rsqrtf((float)v2 + 1.0f);
        dv.w = rsqrtf((float)v3 + 1.0f);
        *(float4*)(dinv + idx) = dv;
    } else {
        if (idx     < nN) { v0 = cnt[idx];     dinv[idx]     = rsqrtf((float)v0 + 1.0f); }
        if (idx + 1 < nN) { v1 = cnt[idx + 1]; dinv[idx + 1] = rsqrtf((float)v1 + 1.0f); }
        if (idx + 2 < nN) { v2 = cnt[idx + 2]; dinv[idx + 2] = rsqrtf((float)v2 + 1.0f); }
        if (idx + 3 < nN) { v3 = cnt[idx + 3]; dinv[idx + 3] = rsqrtf((float)v3 + 1.0f); }
    }
    sdata[t] = v0 + v1 + v2 + v3;
    __syncthreads();
#pragma unroll
    for (int off = 128; off > 0; off >>= 1) {
        if (t < off) sdata[t] += sdata[t + off];
        __syncthreads();
    }
    if (t == 0) blockSums[blockIdx.x] = sdata[0];
}

// phase 2: single small block converts blockSums -> exclusive offsets (nB <= 256)
__global__ __launch_bounds__(256) void scan_phase2(int* __restrict__ blockSums, int nB) {
    __shared__ int sd[256];
    const int t = threadIdx.x;
    sd[t] = (t < nB) ? blockSums[t] : 0;
    __syncthreads();
#pragma unroll
    for (int off = 1; off < 256; off <<= 1) {
        int v = sd[t];
        int add = (t >= off) ? sd[t - off] : 0;
        __syncthreads();
        sd[t] = v + add;
        __syncthreads();
    }
    if (t < nB) blockSums[t] = (t > 0) ? sd[t - 1] : 0;  // exclusive
}

// phase 3: per-block exclusive scan + global offset -> rowptr
__global__ __launch_bounds__(256) void scan_phase3(const int* __restrict__ cnt,
                                                   const int* __restrict__ blockOffsets,
                                                   int* __restrict__ rowptr, int nN, int nE) {
    __shared__ int sdata[256];
    const int t = threadIdx.x;
    const int idx = blockIdx.x * SCAN_CHUNK + t * 4;
    int v0 = 0, v1 = 0, v2 = 0, v3 = 0;
    if (idx + 3 < nN) {
        int4 v = *(const int4*)(cnt + idx);
        v0 = v.x; v1 = v.y; v2 = v.z; v3 = v.w;
    } else {
        if (idx     < nN) v0 = cnt[idx];
        if (idx + 1 < nN) v1 = cnt[idx + 1];
        if (idx + 2 < nN) v2 = cnt[idx + 2];
        if (idx + 3 < nN) v3 = cnt[idx + 3];
    }
    sdata[t] = v0 + v1 + v2 + v3;
    __syncthreads();
#pragma unroll
    for (int off = 1; off < 256; off <<= 1) {
        int v = sdata[t];
        int add = (t >= off) ? sdata[t - off] : 0;
        __syncthreads();
        sdata[t] = v + add;
        __syncthreads();
    }
    const int pre = blockOffsets[blockIdx.x] + ((t > 0) ? sdata[t - 1] : 0);
    if (idx + 3 < nN) {
        *(int4*)(rowptr + idx) = make_int4(pre, pre + v0, pre + v0 + v1, pre + v0 + v1 + v2);
    } else {
        if (idx     < nN) rowptr[idx]     = pre;
        if (idx + 1 < nN) rowptr[idx + 1] = pre + v0;
        if (idx + 2 < nN) rowptr[idx + 2] = pre + v0 + v1;
        if (idx + 3 < nN) rowptr[idx + 3] = pre + v0 + v1 + v2;
    }
    if (blockIdx.x == 0 && t == 0) rowptr[nN] = nE;
}

// scatter edge src ids into CSR order (cur must be zeroed)
__global__ __launch_bounds__(256) void scatter_kernel(const int* __restrict__ src,
                                                      const int* __restrict__ dst,
                                                      const int* __restrict__ rowptr,
                                                      int* __restrict__ cur,
                                                      int* __restrict__ ssrc, int nE) {
    int e = blockIdx.x * 256 + threadIdx.x;
    if (e < nE) {
        int d = dst[e];
        int pos = rowptr[d] + atomicAdd(&cur[d], 1);
        ssrc[pos] = src[e];
    }
}

// ---------------------------------------------------------------------------
// P = dinv ⊙ (X @ W); 64-row tile per block, 256 threads, thread = 4 rows x 8 cols
__global__ __launch_bounds__(256) void gemm_scale_kernel(const float* __restrict__ X,
                                                         const float* __restrict__ W,
                                                         const float* __restrict__ dinv,
                                                         float* __restrict__ P, int nN) {
    __shared__ float Xs[128 * 65];  // transposed tile Xs[k][row], pad 65 -> conflict-free reads
    const int tid = threadIdx.x;
    const int rowBase = blockIdx.x * TILE_ROWS;
#pragma unroll
    for (int it = 0; it < 8; ++it) {
        int f4 = it * 256 + tid;
        int row = f4 >> 5;            // 0..63
        int kc = (f4 & 31) << 2;      // 0,4,...,124
        int grow = rowBase + row;
        float4 v = make_float4(0.f, 0.f, 0.f, 0.f);
        if (grow < nN) v = *(const float4*)(X + (size_t)grow * HID + kc);
        Xs[(kc + 0) * 65 + row] = v.x;
        Xs[(kc + 1) * 65 + row] = v.y;
        Xs[(kc + 2) * 65 + row] = v.z;
        Xs[(kc + 3) * 65 + row] = v.w;
    }
    __syncthreads();
    const int tx = tid & 15;   // col group: cols tx*8 .. tx*8+7
    const int ty = tid >> 4;   // row group: rows ty*4 .. ty*4+3
    float acc[4][8];
#pragma unroll
    for (int r = 0; r < 4; ++r)
#pragma unroll
        for (int c = 0; c < 8; ++c) acc[r][c] = 0.f;
    const float* Wp = W + tx * 8;
#pragma unroll 2
    for (int k = 0; k < 128; ++k) {
        float4 w0 = *(const float4*)(Wp + k * HID);
        float4 w1 = *(const float4*)(Wp + k * HID + 4);
        float xr[4];
#pragma unroll
        for (int r = 0; r < 4; ++r) xr[r] = Xs[k * 65 + ty * 4 + r];
#pragma unroll
        for (int r = 0; r < 4; ++r) {
            acc[r][0] = fmaf(xr[r], w0.x, acc[r][0]);
            acc[r][1] = fmaf(xr[r], w0.y, acc[r][1]);
            acc[r][2] = fmaf(xr[r], w0.z, acc[r][2]);
            acc[r][3] = fmaf(xr[r], w0.w, acc[r][3]);
            acc[r][4] = fmaf(xr[r], w1.x, acc[r][4]);
            acc[r][5] = fmaf(xr[r], w1.y, acc[r][5]);
            acc[r][6] = fmaf(xr[r], w1.z, acc[r][6]);
            acc[r][7] = fmaf(xr[r], w1.w, acc[r][7]);
        }
    }
#pragma unroll
    for (int r = 0; r < 4; ++r) {
        int grow = rowBase + ty * 4 + r;
        if (grow < nN) {
            float dv = dinv[grow];
            float4 o0, o1;
            o0.x = dv * acc[r][0]; o0.y = dv * acc[r][1];
            o0.z = dv * acc[r][2]; o0.w = dv * acc[r][3];
            o1.x = dv * acc[r][4]; o1.y = dv * acc[r][5];
            o1.z = dv * acc[r][6]; o1.w = dv * acc[r][7];
            *(float4*)(P + (size_t)grow * HID + tx * 8) = o0;
            *(float4*)(P + (size_t)grow * HID + tx * 8 + 4) = o1;
        }
    }
}

// ---------------------------------------------------------------------------
// Xout[v] = relu(dinv[v]*(P[v] + sum_{in-edges} P[src]) + b); 32 lanes per node.
// Unroll-8 gather: 8 independent row fetches in flight per 32-lane group (MLP).
__global__ __launch_bounds__(256) void agg_kernel(const float* __restrict__ P,
                                                  const int* __restrict__ rowptr,
                                                  const int* __restrict__ ssrc,
                                                  const float* __restrict__ dinv,
                                                  const float* __restrict__ bias,
                                                  float* __restrict__ Xout, int nN) {
    const int lane = threadIdx.x & 31;
    const int grp = threadIdx.x >> 5;
    const int v = blockIdx.x * 8 + grp;
    if (v >= nN) return;
    const float4* P4 = (const float4*)P;
    float4 a0 = P4[(size_t)v * 32 + lane];
    float4 a1 = make_float4(0.f, 0.f, 0.f, 0.f);
    float4 a2 = make_float4(0.f, 0.f, 0.f, 0.f);
    float4 a3 = make_float4(0.f, 0.f, 0.f, 0.f);
    int e = rowptr[v];
    const int e1 = rowptr[v + 1];
    for (; e + 8 <= e1; e += 8) {
        const int u0 = ssrc[e + 0], u1 = ssrc[e + 1], u2 = ssrc[e + 2], u3 = ssrc[e + 3];
        const int u4 = ssrc[e + 4], u5 = ssrc[e + 5], u6 = ssrc[e + 6], u7 = ssrc[e + 7];
        float4 p0 = P4[(size_t)u0 * 32 + lane];
        float4 p1 = P4[(size_t)u1 * 32 + lane];
        float4 p2 = P4[(size_t)u2 * 32 + lane];
        float4 p3 = P4[(size_t)u3 * 32 + lane];
        float4 p4 = P4[(size_t)u4 * 32 + lane];
        float4 p5 = P4[(size_t)u5 * 32 + lane];
        float4 p6 = P4[(size_t)u6 * 32 + lane];
        float4 p7 = P4[(size_t)u7 * 32 + lane];
        a0.x += p0.x; a0.y += p0.y; a0.z += p0.z; a0.w += p0.w;
        a1.x += p1.x; a1.y += p1.y; a1.z += p1.z; a1.w += p1.w;
        a2.x += p2.x; a2.y += p2.y; a2.z += p2.z; a2.w += p2.w;
        a3.x += p3.x; a3.y += p3.y; a3.z += p3.z; a3.w += p3.w;
        a0.x += p4.x; a0.y += p4.y; a0.z += p4.z; a0.w += p4.w;
        a1.x += p5.x; a1.y += p5.y; a1.z += p5.z; a1.w += p5.w;
        a2.x += p6.x; a2.y += p6.y; a2.z += p6.z; a2.w += p6.w;
        a3.x += p7.x; a3.y += p7.y; a3.z += p7.z; a3.w += p7.w;
    }
    for (; e + 2 <= e1; e += 2) {
        const int u0 = ssrc[e + 0], u1 = ssrc[e + 1];
        float4 p0 = P4[(size_t)u0 * 32 + lane];
        float4 p1 = P4[(size_t)u1 * 32 + lane];
        a0.x += p0.x; a0.y += p0.y; a0.z += p0.z; a0.w += p0.w;
        a1.x += p1.x; a1.y += p1.y; a1.z += p1.z; a1.w += p1.w;
    }
    if (e < e1) {
        const int u0 = ssrc[e];
        float4 p0 = P4[(size_t)u0 * 32 + lane];
        a2.x += p0.x; a2.y += p0.y; a2.z += p0.z; a2.w += p0.w;
    }
    float4 acc;
    acc.x = (a0.x + a1.x) + (a2.x + a3.x);
    acc.y = (a0.y + a1.y) + (a2.y + a3.y);
    acc.z = (a0.z + a1.z) + (a2.z + a3.z);
    acc.w = (a0.w + a1.w) + (a2.w + a3.w);
    const float dv = dinv[v];
    const float4 bb = ((const float4*)bias)[lane];
    float4 o;
    o.x = fmaxf(fmaf(dv, acc.x, bb.x), 0.f);
    o.y = fmaxf(fmaf(dv, acc.y, bb.y), 0.f);
    o.z = fmaxf(fmaf(dv, acc.z, bb.z), 0.f);
    o.w = fmaxf(fmaf(dv, acc.w, bb.w), 0.f);
    ((float4*)Xout)[(size_t)v * 32 + lane] = o;
}

// ---------------------------------------------------------------------------
// global mean pool; one block per graph, batch ids are sorted
__global__ __launch_bounds__(128) void pool_kernel(const float* __restrict__ X,
                                                   const int* __restrict__ batch,
                                                   float* __restrict__ pooled, int nN) {
    const int g = blockIdx.x;
    int lo = 0, hi = nN;
    while (lo < hi) { int m = (lo + hi) >> 1; if (batch[m] < g) lo = m + 1; else hi = m; }
    const int start = lo;
    hi = nN;
    while (lo < hi) { int m = (lo + hi) >> 1; if (batch[m] < g + 1) lo = m + 1; else hi = m; }
    const int end = lo;
    float acc = 0.f;
    for (int n = start; n < end; ++n) acc += X[(size_t)n * HID + threadIdx.x];
    const float c = (float)max(end - start, 1);
    pooled[g * HID + threadIdx.x] = acc / c;
}

// ---------------------------------------------------------------------------
// single-step LSTM from zero state + FC(2); f-gate irrelevant (c0=0)
__device__ __forceinline__ float sigmoidf_(float x) { return 1.0f / (1.0f + expf(-x)); }

__global__ __launch_bounds__(128) void lstm_fc_kernel(const float* __restrict__ pooled,
                                                      const float* __restrict__ W_ih,
                                                      const float* __restrict__ b_ih,
                                                      const float* __restrict__ b_hh,
                                                      const float* __restrict__ W_fc,
                                                      const float* __restrict__ b_fc,
                                                      float* __restrict__ out) {
    __shared__ float pv[HID];
    __shared__ float r0[2], r1[2];
    const int g = blockIdx.x, j = threadIdx.x;
    pv[j] = pooled[g * HID + j];
    __syncthreads();
    float di = b_ih[j] + b_hh[j];                 // i gate, rows 0..127
    float dg = b_ih[256 + j] + b_hh[256 + j];     // g gate, rows 256..383
    float dO = b_ih[384 + j] + b_hh[384 + j];     // o gate, rows 384..511
    const float4* pv4 = (const float4*)pv;
#pragma unroll 4
    for (int k4 = 0; k4 < 32; ++k4) {
        float4 p = pv4[k4];
        float4 wi = *(const float4*)(W_ih + (size_t)j * HID + k4 * 4);
        float4 wg = *(const float4*)(W_ih + (size_t)(256 + j) * HID + k4 * 4);
        float4 wo = *(const float4*)(W_ih + (size_t)(384 + j) * HID + k4 * 4);
        di += p.x * wi.x + p.y * wi.y + p.z * wi.z + p.w * wi.w;
        dg += p.x * wg.x + p.y * wg.y + p.z * wg.z + p.w * wg.w;
        dO += p.x * wo.x + p.y * wo.y + p.z * wo.z + p.w * wo.w;
    }
    float c = sigmoidf_(di) * tanhf(dg);
    float hn = sigmoidf_(dO) * tanhf(c);
    float p0 = hn * W_fc[j];
    float p1 = hn * W_fc[HID + j];
#pragma unroll
    for (int off = 32; off > 0; off >>= 1) {
        p0 += __shfl_down(p0, off, 64);
        p1 += __shfl_down(p1, off, 64);
    }
    const int w = j >> 6, l = j & 63;
    if (l == 0) { r0[w] = p0; r1[w] = p1; }
    __syncthreads();
    if (j == 0) {
        out[g * 2 + 0] = r0[0] + r0[1] + b_fc[0];
        out[g * 2 + 1] = r1[0] + r1[1] + b_fc[1];
    }
}

// ---------------------------------------------------------------------------
extern "C" void kernel_launch(void* const* d_in, const int* in_sizes, int n_in,
                              void* d_out, int out_size, void* d_ws, size_t ws_size,
                              hipStream_t stream) {
    const float* x      = (const float*)d_in[0];
    const int*   eidx   = (const int*)d_in[1];
    const int*   batch  = (const int*)d_in[2];
    const float* W0     = (const float*)d_in[4];
    const float* b0     = (const float*)d_in[5];
    const float* W1     = (const float*)d_in[6];
    const float* b1     = (const float*)d_in[7];
    const float* W2     = (const float*)d_in[8];
    const float* b2     = (const float*)d_in[9];
    const float* W_ih   = (const float*)d_in[10];
    const float* b_ih   = (const float*)d_in[12];
    const float* b_hh   = (const float*)d_in[13];
    const float* W_fc   = (const float*)d_in[14];
    const float* b_fc   = (const float*)d_in[15];
    float* out = (float*)d_out;

    const int nN = in_sizes[0] / HID;     // 100000
    const int nE = in_sizes[1] / 2;       // 1600000
    const int nG = out_size / 2;          // 256
    const int* src = eidx;
    const int* dst = eidx + nE;

    // workspace layout
    size_t off = 0;
    auto alloc = [&](size_t bytes) -> void* {
        void* p = (char*)d_ws + off;
        off += (bytes + 255) & ~(size_t)255;
        return p;
    };
    float* P      = (float*)alloc((size_t)nN * HID * sizeof(float));
    float* B0     = (float*)alloc((size_t)nN * HID * sizeof(float));
    float* dinv   = (float*)alloc((size_t)nN * sizeof(float));
    int*   cnt    = (int*)alloc((size_t)nN * sizeof(int));
    int*   rowptr = (int*)alloc((size_t)(nN + 1) * sizeof(int));
    int*   ssrc   = (int*)alloc((size_t)nE * sizeof(int));
    float* pooled = (float*)alloc((size_t)nG * HID * sizeof(float));
    int*   blockSums = (int*)alloc(1024 * sizeof(int));
    (void)ws_size;

    const int eBlocks = (nE + 255) / 256;
    const int scanBlocks = (nN + SCAN_CHUNK - 1) / SCAN_CHUNK;   // 98 for nN=100000

    // CSR build + dinv
    hipMemsetAsync(cnt, 0, (size_t)nN * sizeof(int), stream);
    count_kernel<<<eBlocks, 256, 0, stream>>>(dst, cnt, nE);
    scan_phase1<<<scanBlocks, 256, 0, stream>>>(cnt, blockSums, dinv, nN);
    scan_phase2<<<1, 256, 0, stream>>>(blockSums, scanBlocks);
    scan_phase3<<<scanBlocks, 256, 0, stream>>>(cnt, blockSums, rowptr, nN, nE);
    hipMemsetAsync(cnt, 0, (size_t)nN * sizeof(int), stream);
    scatter_kernel<<<eBlocks, 256, 0, stream>>>(src, dst, rowptr, cnt, ssrc, nE);

    const int gemmBlocks = (nN + TILE_ROWS - 1) / TILE_ROWS;
    const int aggBlocks = (nN + 7) / 8;

    // layer 0
    gemm_scale_kernel<<<gemmBlocks, 256, 0, stream>>>(x, W0, dinv, P, nN);
    agg_kernel<<<aggBlocks, 256, 0, stream>>>(P, rowptr, ssrc, dinv, b0, B0, nN);
    // layer 1
    gemm_scale_kernel<<<gemmBlocks, 256, 0, stream>>>(B0, W1, dinv, P, nN);
    agg_kernel<<<aggBlocks, 256, 0, stream>>>(P, rowptr, ssrc, dinv, b1, B0, nN);
    // layer 2
    gemm_scale_kernel<<<gemmBlocks, 256, 0, stream>>>(B0, W2, dinv, P, nN);
    agg_kernel<<<aggBlocks, 256, 0, stream>>>(P, rowptr, ssrc, dinv, b2, B0, nN);

    // pool + LSTM + FC
    pool_kernel<<<nG, 128, 0, stream>>>(B0, batch, pooled, nN);
    lstm_fc_kernel<<<nG, 128, 0, stream>>>(pooled, W_ih, b_ih, b_hh, W_fc, b_fc, out);
}

// Round 4
// 802.237 us; speedup vs baseline: 1.4295x; 1.2266x over previous
//
#include <hip/hip_runtime.h>
#include <math.h>
#include <stdint.h>

#define HID 128
#define TILE_ROWS 64
#define SCAN_CHUNK 1024   // elements per scan block (256 thr x 4)

// ---------------------------------------------------------------------------
// CSR build: count in-degrees
__global__ __launch_bounds__(256) void count_kernel(const int* __restrict__ dst,
                                                    int* __restrict__ cnt, int nE) {
    int e = blockIdx.x * 256 + threadIdx.x;
    if (e < nE) atomicAdd(&cnt[dst[e]], 1);
}

// ---------------------------------------------------------------------------
// Hierarchical scan, phase 1: per-block sums of cnt (1024 elems/block) + fused dinv
__global__ __launch_bounds__(256) void scan_phase1(const int* __restrict__ cnt,
                                                   int* __restrict__ blockSums,
                                                   float* __restrict__ dinv, int nN) {
    __shared__ int sdata[256];
    const int t = threadIdx.x;
    const int idx = blockIdx.x * SCAN_CHUNK + t * 4;
    int v0 = 0, v1 = 0, v2 = 0, v3 = 0;
    if (idx + 3 < nN) {
        int4 v = *(const int4*)(cnt + idx);
        v0 = v.x; v1 = v.y; v2 = v.z; v3 = v.w;
        float4 dv;
        dv.x = rsqrtf((float)v0 + 1.0f);
        dv.y = rsqrtf((float)v1 + 1.0f);
        dv.z = rsqrtf((float)v2 + 1.0f);
        dv.w = rsqrtf((float)v3 + 1.0f);
        *(float4*)(dinv + idx) = dv;
    } else {
        if (idx     < nN) { v0 = cnt[idx];     dinv[idx]     = rsqrtf((float)v0 + 1.0f); }
        if (idx + 1 < nN) { v1 = cnt[idx + 1]; dinv[idx + 1] = rsqrtf((float)v1 + 1.0f); }
        if (idx + 2 < nN) { v2 = cnt[idx + 2]; dinv[idx + 2] = rsqrtf((float)v2 + 1.0f); }
        if (idx + 3 < nN) { v3 = cnt[idx + 3]; dinv[idx + 3] = rsqrtf((float)v3 + 1.0f); }
    }
    sdata[t] = v0 + v1 + v2 + v3;
    __syncthreads();
#pragma unroll
    for (int off = 128; off > 0; off >>= 1) {
        if (t < off) sdata[t] += sdata[t + off];
        __syncthreads();
    }
    if (t == 0) blockSums[blockIdx.x] = sdata[0];
}

// phase 2: single small block converts blockSums -> exclusive offsets (nB <= 256)
__global__ __launch_bounds__(256) void scan_phase2(int* __restrict__ blockSums, int nB) {
    __shared__ int sd[256];
    const int t = threadIdx.x;
    sd[t] = (t < nB) ? blockSums[t] : 0;
    __syncthreads();
#pragma unroll
    for (int off = 1; off < 256; off <<= 1) {
        int v = sd[t];
        int add = (t >= off) ? sd[t - off] : 0;
        __syncthreads();
        sd[t] = v + add;
        __syncthreads();
    }
    if (t < nB) blockSums[t] = (t > 0) ? sd[t - 1] : 0;  // exclusive
}

// phase 3: per-block exclusive scan + global offset -> rowptr
__global__ __launch_bounds__(256) void scan_phase3(const int* __restrict__ cnt,
                                                   const int* __restrict__ blockOffsets,
                                                   int* __restrict__ rowptr, int nN, int nE) {
    __shared__ int sdata[256];
    const int t = threadIdx.x;
    const int idx = blockIdx.x * SCAN_CHUNK + t * 4;
    int v0 = 0, v1 = 0, v2 = 0, v3 = 0;
    if (idx + 3 < nN) {
        int4 v = *(const int4*)(cnt + idx);
        v0 = v.x; v1 = v.y; v2 = v.z; v3 = v.w;
    } else {
        if (idx     < nN) v0 = cnt[idx];
        if (idx + 1 < nN) v1 = cnt[idx + 1];
        if (idx + 2 < nN) v2 = cnt[idx + 2];
        if (idx + 3 < nN) v3 = cnt[idx + 3];
    }
    sdata[t] = v0 + v1 + v2 + v3;
    __syncthreads();
#pragma unroll
    for (int off = 1; off < 256; off <<= 1) {
        int v = sdata[t];
        int add = (t >= off) ? sdata[t - off] : 0;
        __syncthreads();
        sdata[t] = v + add;
        __syncthreads();
    }
    const int pre = blockOffsets[blockIdx.x] + ((t > 0) ? sdata[t - 1] : 0);
    if (idx + 3 < nN) {
        *(int4*)(rowptr + idx) = make_int4(pre, pre + v0, pre + v0 + v1, pre + v0 + v1 + v2);
    } else {
        if (idx     < nN) rowptr[idx]     = pre;
        if (idx + 1 < nN) rowptr[idx + 1] = pre + v0;
        if (idx + 2 < nN) rowptr[idx + 2] = pre + v0 + v1;
        if (idx + 3 < nN) rowptr[idx + 3] = pre + v0 + v1 + v2;
    }
    if (blockIdx.x == 0 && t == 0) rowptr[nN] = nE;
}

// scatter edge src ids into CSR order (cur must be zeroed)
__global__ __launch_bounds__(256) void scatter_kernel(const int* __restrict__ src,
                                                      const int* __restrict__ dst,
                                                      const int* __restrict__ rowptr,
                                                      int* __restrict__ cur,
                                                      int* __restrict__ ssrc, int nE) {
    int e = blockIdx.x * 256 + threadIdx.x;
    if (e < nE) {
        int d = dst[e];
        int pos = rowptr[d] + atomicAdd(&cur[d], 1);
        ssrc[pos] = src[e];
    }
}

// ---------------------------------------------------------------------------
// round-to-nearest-even fp32 -> bf16 bits
__device__ __forceinline__ unsigned int f2bf(float f) {
    union { float f; uint32_t i; } u; u.f = f;
    uint32_t r = u.i + 0x7fffu + ((u.i >> 16) & 1u);
    return r >> 16;
}

// P_bf16 = bf16(dinv ⊙ (X @ W)); 64-row tile per block, 256 threads = 4 rows x 8 cols each
__global__ __launch_bounds__(256) void gemm_scale_kernel(const float* __restrict__ X,
                                                         const float* __restrict__ W,
                                                         const float* __restrict__ dinv,
                                                         uint4* __restrict__ Pb, int nN) {
    __shared__ float Xs[128 * 65];  // transposed tile Xs[k][row], pad 65 -> conflict-free reads
    const int tid = threadIdx.x;
    const int rowBase = blockIdx.x * TILE_ROWS;
#pragma unroll
    for (int it = 0; it < 8; ++it) {
        int f4 = it * 256 + tid;
        int row = f4 >> 5;            // 0..63
        int kc = (f4 & 31) << 2;      // 0,4,...,124
        int grow = rowBase + row;
        float4 v = make_float4(0.f, 0.f, 0.f, 0.f);
        if (grow < nN) v = *(const float4*)(X + (size_t)grow * HID + kc);
        Xs[(kc + 0) * 65 + row] = v.x;
        Xs[(kc + 1) * 65 + row] = v.y;
        Xs[(kc + 2) * 65 + row] = v.z;
        Xs[(kc + 3) * 65 + row] = v.w;
    }
    __syncthreads();
    const int tx = tid & 15;   // col group: cols tx*8 .. tx*8+7
    const int ty = tid >> 4;   // row group: rows ty*4 .. ty*4+3
    float acc[4][8];
#pragma unroll
    for (int r = 0; r < 4; ++r)
#pragma unroll
        for (int c = 0; c < 8; ++c) acc[r][c] = 0.f;
    const float* Wp = W + tx * 8;
#pragma unroll 2
    for (int k = 0; k < 128; ++k) {
        float4 w0 = *(const float4*)(Wp + k * HID);
        float4 w1 = *(const float4*)(Wp + k * HID + 4);
        float xr[4];
#pragma unroll
        for (int r = 0; r < 4; ++r) xr[r] = Xs[k * 65 + ty * 4 + r];
#pragma unroll
        for (int r = 0; r < 4; ++r) {
            acc[r][0] = fmaf(xr[r], w0.x, acc[r][0]);
            acc[r][1] = fmaf(xr[r], w0.y, acc[r][1]);
            acc[r][2] = fmaf(xr[r], w0.z, acc[r][2]);
            acc[r][3] = fmaf(xr[r], w0.w, acc[r][3]);
            acc[r][4] = fmaf(xr[r], w1.x, acc[r][4]);
            acc[r][5] = fmaf(xr[r], w1.y, acc[r][5]);
            acc[r][6] = fmaf(xr[r], w1.z, acc[r][6]);
            acc[r][7] = fmaf(xr[r], w1.w, acc[r][7]);
        }
    }
#pragma unroll
    for (int r = 0; r < 4; ++r) {
        int grow = rowBase + ty * 4 + r;
        if (grow < nN) {
            float dv = dinv[grow];
            uint4 o;
            o.x = f2bf(dv * acc[r][0]) | (f2bf(dv * acc[r][1]) << 16);
            o.y = f2bf(dv * acc[r][2]) | (f2bf(dv * acc[r][3]) << 16);
            o.z = f2bf(dv * acc[r][4]) | (f2bf(dv * acc[r][5]) << 16);
            o.w = f2bf(dv * acc[r][6]) | (f2bf(dv * acc[r][7]) << 16);
            Pb[(size_t)grow * 16 + tx] = o;  // row = 16 uint4 = 128 bf16
        }
    }
}

// ---------------------------------------------------------------------------
// unpack 8 bf16 (uint4) and accumulate into 8 fp32
__device__ __forceinline__ void acc_bf8(const uint4 q, float* a) {
    union { uint32_t i; float f; } t;
    t.i = q.x << 16;          a[0] += t.f;
    t.i = q.x & 0xffff0000u;  a[1] += t.f;
    t.i = q.y << 16;          a[2] += t.f;
    t.i = q.y & 0xffff0000u;  a[3] += t.f;
    t.i = q.z << 16;          a[4] += t.f;
    t.i = q.z & 0xffff0000u;  a[5] += t.f;
    t.i = q.w << 16;          a[6] += t.f;
    t.i = q.w & 0xffff0000u;  a[7] += t.f;
}

// Xout[v] = relu(dinv[v]*(P[v] + sum_{in-edges} P[src]) + b)
// 16 lanes per node (uint4 = 8 bf16 each), 16 nodes per 256-thread block.
__global__ __launch_bounds__(256) void agg_kernel(const uint4* __restrict__ Pb,
                                                  const int* __restrict__ rowptr,
                                                  const int* __restrict__ ssrc,
                                                  const float* __restrict__ dinv,
                                                  const float* __restrict__ bias,
                                                  float* __restrict__ Xout, int nN) {
    const int lane = threadIdx.x & 15;
    const int grp = threadIdx.x >> 4;
    const int v = blockIdx.x * 16 + grp;
    if (v >= nN) return;
    float a0[8], a1[8], a2[8], a3[8];
#pragma unroll
    for (int i = 0; i < 8; ++i) { a0[i] = 0.f; a1[i] = 0.f; a2[i] = 0.f; a3[i] = 0.f; }
    acc_bf8(Pb[(size_t)v * 16 + lane], a0);  // self loop
    int e = rowptr[v];
    const int e1 = rowptr[v + 1];
    for (; e + 4 <= e1; e += 4) {
        const int u0 = ssrc[e + 0], u1 = ssrc[e + 1], u2 = ssrc[e + 2], u3 = ssrc[e + 3];
        uint4 q0 = Pb[(size_t)u0 * 16 + lane];
        uint4 q1 = Pb[(size_t)u1 * 16 + lane];
        uint4 q2 = Pb[(size_t)u2 * 16 + lane];
        uint4 q3 = Pb[(size_t)u3 * 16 + lane];
        acc_bf8(q0, a0); acc_bf8(q1, a1); acc_bf8(q2, a2); acc_bf8(q3, a3);
    }
    for (; e < e1; ++e) {
        uint4 q = Pb[(size_t)ssrc[e] * 16 + lane];
        acc_bf8(q, a1);
    }
    const float dv = dinv[v];
    const float4 bb0 = ((const float4*)bias)[lane * 2];
    const float4 bb1 = ((const float4*)bias)[lane * 2 + 1];
    float4 o0, o1;
    o0.x = fmaxf(fmaf(dv, (a0[0] + a1[0]) + (a2[0] + a3[0]), bb0.x), 0.f);
    o0.y = fmaxf(fmaf(dv, (a0[1] + a1[1]) + (a2[1] + a3[1]), bb0.y), 0.f);
    o0.z = fmaxf(fmaf(dv, (a0[2] + a1[2]) + (a2[2] + a3[2]), bb0.z), 0.f);
    o0.w = fmaxf(fmaf(dv, (a0[3] + a1[3]) + (a2[3] + a3[3]), bb0.w), 0.f);
    o1.x = fmaxf(fmaf(dv, (a0[4] + a1[4]) + (a2[4] + a3[4]), bb1.x), 0.f);
    o1.y = fmaxf(fmaf(dv, (a0[5] + a1[5]) + (a2[5] + a3[5]), bb1.y), 0.f);
    o1.z = fmaxf(fmaf(dv, (a0[6] + a1[6]) + (a2[6] + a3[6]), bb1.z), 0.f);
    o1.w = fmaxf(fmaf(dv, (a0[7] + a1[7]) + (a2[7] + a3[7]), bb1.w), 0.f);
    float4* X4 = (float4*)(Xout + (size_t)v * HID + lane * 8);
    X4[0] = o0;
    X4[1] = o1;
}

// ---------------------------------------------------------------------------
// global mean pool; one block per graph, batch ids are sorted
__global__ __launch_bounds__(128) void pool_kernel(const float* __restrict__ X,
                                                   const int* __restrict__ batch,
                                                   float* __restrict__ pooled, int nN) {
    const int g = blockIdx.x;
    int lo = 0, hi = nN;
    while (lo < hi) { int m = (lo + hi) >> 1; if (batch[m] < g) lo = m + 1; else hi = m; }
    const int start = lo;
    hi = nN;
    while (lo < hi) { int m = (lo + hi) >> 1; if (batch[m] < g + 1) lo = m + 1; else hi = m; }
    const int end = lo;
    float acc = 0.f;
    for (int n = start; n < end; ++n) acc += X[(size_t)n * HID + threadIdx.x];
    const float c = (float)max(end - start, 1);
    pooled[g * HID + threadIdx.x] = acc / c;
}

// ---------------------------------------------------------------------------
// single-step LSTM from zero state + FC(2); f-gate irrelevant (c0=0)
__device__ __forceinline__ float sigmoidf_(float x) { return 1.0f / (1.0f + expf(-x)); }

__global__ __launch_bounds__(128) void lstm_fc_kernel(const float* __restrict__ pooled,
                                                      const float* __restrict__ W_ih,
                                                      const float* __restrict__ b_ih,
                                                      const float* __restrict__ b_hh,
                                                      const float* __restrict__ W_fc,
                                                      const float* __restrict__ b_fc,
                                                      float* __restrict__ out) {
    __shared__ float pv[HID];
    __shared__ float r0[2], r1[2];
    const int g = blockIdx.x, j = threadIdx.x;
    pv[j] = pooled[g * HID + j];
    __syncthreads();
    float di = b_ih[j] + b_hh[j];                 // i gate, rows 0..127
    float dg = b_ih[256 + j] + b_hh[256 + j];     // g gate, rows 256..383
    float dO = b_ih[384 + j] + b_hh[384 + j];     // o gate, rows 384..511
    const float4* pv4 = (const float4*)pv;
#pragma unroll 4
    for (int k4 = 0; k4 < 32; ++k4) {
        float4 p = pv4[k4];
        float4 wi = *(const float4*)(W_ih + (size_t)j * HID + k4 * 4);
        float4 wg = *(const float4*)(W_ih + (size_t)(256 + j) * HID + k4 * 4);
        float4 wo = *(const float4*)(W_ih + (size_t)(384 + j) * HID + k4 * 4);
        di += p.x * wi.x + p.y * wi.y + p.z * wi.z + p.w * wi.w;
        dg += p.x * wg.x + p.y * wg.y + p.z * wg.z + p.w * wg.w;
        dO += p.x * wo.x + p.y * wo.y + p.z * wo.z + p.w * wo.w;
    }
    float c = sigmoidf_(di) * tanhf(dg);
    float hn = sigmoidf_(dO) * tanhf(c);
    float p0 = hn * W_fc[j];
    float p1 = hn * W_fc[HID + j];
#pragma unroll
    for (int off = 32; off > 0; off >>= 1) {
        p0 += __shfl_down(p0, off, 64);
        p1 += __shfl_down(p1, off, 64);
    }
    const int w = j >> 6, l = j & 63;
    if (l == 0) { r0[w] = p0; r1[w] = p1; }
    __syncthreads();
    if (j == 0) {
        out[g * 2 + 0] = r0[0] + r0[1] + b_fc[0];
        out[g * 2 + 1] = r1[0] + r1[1] + b_fc[1];
    }
}

// ---------------------------------------------------------------------------
extern "C" void kernel_launch(void* const* d_in, const int* in_sizes, int n_in,
                              void* d_out, int out_size, void* d_ws, size_t ws_size,
                              hipStream_t stream) {
    const float* x      = (const float*)d_in[0];
    const int*   eidx   = (const int*)d_in[1];
    const int*   batch  = (const int*)d_in[2];
    const float* W0     = (const float*)d_in[4];
    const float* b0     = (const float*)d_in[5];
    const float* W1     = (const float*)d_in[6];
    const float* b1     = (const float*)d_in[7];
    const float* W2     = (const float*)d_in[8];
    const float* b2     = (const float*)d_in[9];
    const float* W_ih   = (const float*)d_in[10];
    const float* b_ih   = (const float*)d_in[12];
    const float* b_hh   = (const float*)d_in[13];
    const float* W_fc   = (const float*)d_in[14];
    const float* b_fc   = (const float*)d_in[15];
    float* out = (float*)d_out;

    const int nN = in_sizes[0] / HID;     // 100000
    const int nE = in_sizes[1] / 2;       // 1600000
    const int nG = out_size / 2;          // 256
    const int* src = eidx;
    const int* dst = eidx + nE;

    // workspace layout
    size_t off = 0;
    auto alloc = [&](size_t bytes) -> void* {
        void* p = (char*)d_ws + off;
        off += (bytes + 255) & ~(size_t)255;
        return p;
    };
    uint4* Pb     = (uint4*)alloc((size_t)nN * 16 * sizeof(uint4));  // bf16 P, 256 B/row
    float* B0     = (float*)alloc((size_t)nN * HID * sizeof(float));
    float* dinv   = (float*)alloc((size_t)nN * sizeof(float));
    int*   cnt    = (int*)alloc((size_t)nN * sizeof(int));
    int*   rowptr = (int*)alloc((size_t)(nN + 1) * sizeof(int));
    int*   ssrc   = (int*)alloc((size_t)nE * sizeof(int));
    float* pooled = (float*)alloc((size_t)nG * HID * sizeof(float));
    int*   blockSums = (int*)alloc(1024 * sizeof(int));
    (void)ws_size;

    const int eBlocks = (nE + 255) / 256;
    const int scanBlocks = (nN + SCAN_CHUNK - 1) / SCAN_CHUNK;   // 98 for nN=100000

    // CSR build + dinv
    hipMemsetAsync(cnt, 0, (size_t)nN * sizeof(int), stream);
    count_kernel<<<eBlocks, 256, 0, stream>>>(dst, cnt, nE);
    scan_phase1<<<scanBlocks, 256, 0, stream>>>(cnt, blockSums, dinv, nN);
    scan_phase2<<<1, 256, 0, stream>>>(blockSums, scanBlocks);
    scan_phase3<<<scanBlocks, 256, 0, stream>>>(cnt, blockSums, rowptr, nN, nE);
    hipMemsetAsync(cnt, 0, (size_t)nN * sizeof(int), stream);
    scatter_kernel<<<eBlocks, 256, 0, stream>>>(src, dst, rowptr, cnt, ssrc, nE);

    const int gemmBlocks = (nN + TILE_ROWS - 1) / TILE_ROWS;
    const int aggBlocks = (nN + 15) / 16;

    // layer 0
    gemm_scale_kernel<<<gemmBlocks, 256, 0, stream>>>(x, W0, dinv, Pb, nN);
    agg_kernel<<<aggBlocks, 256, 0, stream>>>(Pb, rowptr, ssrc, dinv, b0, B0, nN);
    // layer 1
    gemm_scale_kernel<<<gemmBlocks, 256, 0, stream>>>(B0, W1, dinv, Pb, nN);
    agg_kernel<<<aggBlocks, 256, 0, stream>>>(Pb, rowptr, ssrc, dinv, b1, B0, nN);
    // layer 2
    gemm_scale_kernel<<<gemmBlocks, 256, 0, stream>>>(B0, W2, dinv, Pb, nN);
    agg_kernel<<<aggBlocks, 256, 0, stream>>>(Pb, rowptr, ssrc, dinv, b2, B0, nN);

    // pool + LSTM + FC
    pool_kernel<<<nG, 128, 0, stream>>>(B0, batch, pooled, nN);
    lstm_fc_kernel<<<nG, 128, 0, stream>>>(pooled, W_ih, b_ih, b_hh, W_fc, b_fc, out);
}

// Round 5
// 677.561 us; speedup vs baseline: 1.6926x; 1.1840x over previous
//
#include <hip/hip_runtime.h>
#include <math.h>
#include <stdint.h>

#define HID 128
#define TILE_ROWS 64
#define SCAN_CHUNK 1024   // elements per scan block (256 thr x 4)
#define NBUCK_MAX 512     // node buckets of 256 nodes each (nN<=131072)
#define EDGE_TILE 8192    // edges per block in bucket passes

// ---------------------------------------------------------------------------
// CSR build: count in-degrees
__global__ __launch_bounds__(256) void count_kernel(const int* __restrict__ dst,
                                                    int* __restrict__ cnt, int nE) {
    int e = blockIdx.x * 256 + threadIdx.x;
    if (e < nE) atomicAdd(&cnt[dst[e]], 1);
}

// ---------------------------------------------------------------------------
// Hierarchical scan, phase 1: per-block sums of cnt (1024 elems/block) + fused dinv
__global__ __launch_bounds__(256) void scan_phase1(const int* __restrict__ cnt,
                                                   int* __restrict__ blockSums,
                                                   float* __restrict__ dinv, int nN) {
    __shared__ int sdata[256];
    const int t = threadIdx.x;
    const int idx = blockIdx.x * SCAN_CHUNK + t * 4;
    int v0 = 0, v1 = 0, v2 = 0, v3 = 0;
    if (idx + 3 < nN) {
        int4 v = *(const int4*)(cnt + idx);
        v0 = v.x; v1 = v.y; v2 = v.z; v3 = v.w;
        float4 dv;
        dv.x = rsqrtf((float)v0 + 1.0f);
        dv.y = rsqrtf((float)v1 + 1.0f);
        dv.z = rsqrtf((float)v2 + 1.0f);
        dv.w = rsqrtf((float)v3 + 1.0f);
        *(float4*)(dinv + idx) = dv;
    } else {
        if (idx     < nN) { v0 = cnt[idx];     dinv[idx]     = rsqrtf((float)v0 + 1.0f); }
        if (idx + 1 < nN) { v1 = cnt[idx + 1]; dinv[idx + 1] = rsqrtf((float)v1 + 1.0f); }
        if (idx + 2 < nN) { v2 = cnt[idx + 2]; dinv[idx + 2] = rsqrtf((float)v2 + 1.0f); }
        if (idx + 3 < nN) { v3 = cnt[idx + 3]; dinv[idx + 3] = rsqrtf((float)v3 + 1.0f); }
    }
    sdata[t] = v0 + v1 + v2 + v3;
    __syncthreads();
#pragma unroll
    for (int off = 128; off > 0; off >>= 1) {
        if (t < off) sdata[t] += sdata[t + off];
        __syncthreads();
    }
    if (t == 0) blockSums[blockIdx.x] = sdata[0];
}

// phase 2: single small block converts blockSums -> exclusive offsets (nB <= 256)
__global__ __launch_bounds__(256) void scan_phase2(int* __restrict__ blockSums, int nB) {
    __shared__ int sd[256];
    const int t = threadIdx.x;
    sd[t] = (t < nB) ? blockSums[t] : 0;
    __syncthreads();
#pragma unroll
    for (int off = 1; off < 256; off <<= 1) {
        int v = sd[t];
        int add = (t >= off) ? sd[t - off] : 0;
        __syncthreads();
        sd[t] = v + add;
        __syncthreads();
    }
    if (t < nB) blockSums[t] = (t > 0) ? sd[t - 1] : 0;  // exclusive
}

// phase 3: per-block exclusive scan + global offset -> rowptr
__global__ __launch_bounds__(256) void scan_phase3(const int* __restrict__ cnt,
                                                   const int* __restrict__ blockOffsets,
                                                   int* __restrict__ rowptr, int nN, int nE) {
    __shared__ int sdata[256];
    const int t = threadIdx.x;
    const int idx = blockIdx.x * SCAN_CHUNK + t * 4;
    int v0 = 0, v1 = 0, v2 = 0, v3 = 0;
    if (idx + 3 < nN) {
        int4 v = *(const int4*)(cnt + idx);
        v0 = v.x; v1 = v.y; v2 = v.z; v3 = v.w;
    } else {
        if (idx     < nN) v0 = cnt[idx];
        if (idx + 1 < nN) v1 = cnt[idx + 1];
        if (idx + 2 < nN) v2 = cnt[idx + 2];
        if (idx + 3 < nN) v3 = cnt[idx + 3];
    }
    sdata[t] = v0 + v1 + v2 + v3;
    __syncthreads();
#pragma unroll
    for (int off = 1; off < 256; off <<= 1) {
        int v = sdata[t];
        int add = (t >= off) ? sdata[t - off] : 0;
        __syncthreads();
        sdata[t] = v + add;
        __syncthreads();
    }
    const int pre = blockOffsets[blockIdx.x] + ((t > 0) ? sdata[t - 1] : 0);
    if (idx + 3 < nN) {
        *(int4*)(rowptr + idx) = make_int4(pre, pre + v0, pre + v0 + v1, pre + v0 + v1 + v2);
    } else {
        if (idx     < nN) rowptr[idx]     = pre;
        if (idx + 1 < nN) rowptr[idx + 1] = pre + v0;
        if (idx + 2 < nN) rowptr[idx + 2] = pre + v0 + v1;
        if (idx + 3 < nN) rowptr[idx + 3] = pre + v0 + v1 + v2;
    }
    if (blockIdx.x == 0 && t == 0) rowptr[nN] = nE;
}

// ---------------------------------------------------------------------------
// Multisplit CSR build (replaces the 16x-write-amplified direct scatter).
// Bucket = dst >> 8 (256 nodes/bucket).

// Pass A: LDS-staged bucket histogram
__global__ __launch_bounds__(256) void bucket_count(const int* __restrict__ dst,
                                                    int* __restrict__ bcnt, int nE, int nB) {
    __shared__ int h[NBUCK_MAX];
    for (int i = threadIdx.x; i < nB; i += 256) h[i] = 0;
    __syncthreads();
    const int base = blockIdx.x * EDGE_TILE;
    const int end = min(base + EDGE_TILE, nE);
    for (int e = base + threadIdx.x; e < end; e += 256)
        atomicAdd(&h[dst[e] >> 8], 1);
    __syncthreads();
    for (int i = threadIdx.x; i < nB; i += 256)
        if (h[i]) atomicAdd(&bcnt[i], h[i]);
}

// Pass B: exclusive scan of bucket counts (nB <= 512), writes boff and bcur copies
__global__ __launch_bounds__(512) void bucket_scan(const int* __restrict__ bcnt,
                                                   int* __restrict__ boff,
                                                   int* __restrict__ bcur, int nB) {
    __shared__ int sd[512];
    const int t = threadIdx.x;
    sd[t] = (t < nB) ? bcnt[t] : 0;
    __syncthreads();
#pragma unroll
    for (int off = 1; off < 512; off <<= 1) {
        int v = sd[t];
        int add = (t >= off) ? sd[t - off] : 0;
        __syncthreads();
        sd[t] = v + add;
        __syncthreads();
    }
    if (t < nB) {
        int ex = (t > 0) ? sd[t - 1] : 0;
        boff[t] = ex;
        bcur[t] = ex;
    }
}

// Pass C: scatter (src,dst) pairs into bucket-contiguous ebuf; per-block range
// reservation makes each block's writes to a bucket dense.
__global__ __launch_bounds__(256) void bucket_scatter(const int* __restrict__ src,
                                                      const int* __restrict__ dst,
                                                      int* __restrict__ bcur,
                                                      uint2* __restrict__ ebuf, int nE, int nB) {
    __shared__ int h[NBUCK_MAX];
    __shared__ int basearr[NBUCK_MAX];
    const int base = blockIdx.x * EDGE_TILE;
    const int end = min(base + EDGE_TILE, nE);
    for (int i = threadIdx.x; i < nB; i += 256) h[i] = 0;
    __syncthreads();
    for (int e = base + threadIdx.x; e < end; e += 256)
        atomicAdd(&h[dst[e] >> 8], 1);
    __syncthreads();
    for (int i = threadIdx.x; i < nB; i += 256) {
        int c = h[i];
        basearr[i] = c ? atomicAdd(&bcur[i], c) : 0;
        h[i] = 0;   // reuse as local cursor
    }
    __syncthreads();
    for (int e = base + threadIdx.x; e < end; e += 256) {
        int d = dst[e];
        int b = d >> 8;
        int pos = basearr[b] + atomicAdd(&h[b], 1);
        ebuf[pos] = make_uint2((unsigned)src[e], (unsigned)d);
    }
}

// Pass D: per-bucket final CSR scatter. Destination window in ssrc is the
// contiguous rowptr range of 256 nodes (~16 KB) -> cache-resident, full lines.
__global__ __launch_bounds__(256) void csr_from_buckets(const uint2* __restrict__ ebuf,
                                                        const int* __restrict__ boff,
                                                        const int* __restrict__ rowptr,
                                                        int* __restrict__ ssrc, int nE, int nB) {
    __shared__ int cur[256];
    const int b = blockIdx.x;
    const int e0 = boff[b];
    const int e1 = (b + 1 < nB) ? boff[b + 1] : nE;
    cur[threadIdx.x] = 0;
    __syncthreads();
    for (int e = e0 + threadIdx.x; e < e1; e += 256) {
        uint2 ed = ebuf[e];
        int d = (int)ed.y;
        int pos = rowptr[d] + atomicAdd(&cur[d & 255], 1);
        ssrc[pos] = (int)ed.x;
    }
}

// ---------------------------------------------------------------------------
// round-to-nearest-even fp32 -> bf16 bits
__device__ __forceinline__ unsigned int f2bf(float f) {
    union { float f; uint32_t i; } u; u.f = f;
    uint32_t r = u.i + 0x7fffu + ((u.i >> 16) & 1u);
    return r >> 16;
}

// P_bf16 = bf16(dinv ⊙ (X @ W)); 64-row tile per block, 256 threads = 4 rows x 8 cols each
__global__ __launch_bounds__(256) void gemm_scale_kernel(const float* __restrict__ X,
                                                         const float* __restrict__ W,
                                                         const float* __restrict__ dinv,
                                                         uint4* __restrict__ Pb, int nN) {
    __shared__ float Xs[128 * 65];  // transposed tile Xs[k][row], pad 65 -> conflict-free reads
    const int tid = threadIdx.x;
    const int rowBase = blockIdx.x * TILE_ROWS;
#pragma unroll
    for (int it = 0; it < 8; ++it) {
        int f4 = it * 256 + tid;
        int row = f4 >> 5;            // 0..63
        int kc = (f4 & 31) << 2;      // 0,4,...,124
        int grow = rowBase + row;
        float4 v = make_float4(0.f, 0.f, 0.f, 0.f);
        if (grow < nN) v = *(const float4*)(X + (size_t)grow * HID + kc);
        Xs[(kc + 0) * 65 + row] = v.x;
        Xs[(kc + 1) * 65 + row] = v.y;
        Xs[(kc + 2) * 65 + row] = v.z;
        Xs[(kc + 3) * 65 + row] = v.w;
    }
    __syncthreads();
    const int tx = tid & 15;   // col group: cols tx*8 .. tx*8+7
    const int ty = tid >> 4;   // row group: rows ty*4 .. ty*4+3
    float acc[4][8];
#pragma unroll
    for (int r = 0; r < 4; ++r)
#pragma unroll
        for (int c = 0; c < 8; ++c) acc[r][c] = 0.f;
    const float* Wp = W + tx * 8;
#pragma unroll 2
    for (int k = 0; k < 128; ++k) {
        float4 w0 = *(const float4*)(Wp + k * HID);
        float4 w1 = *(const float4*)(Wp + k * HID + 4);
        float xr[4];
#pragma unroll
        for (int r = 0; r < 4; ++r) xr[r] = Xs[k * 65 + ty * 4 + r];
#pragma unroll
        for (int r = 0; r < 4; ++r) {
            acc[r][0] = fmaf(xr[r], w0.x, acc[r][0]);
            acc[r][1] = fmaf(xr[r], w0.y, acc[r][1]);
            acc[r][2] = fmaf(xr[r], w0.z, acc[r][2]);
            acc[r][3] = fmaf(xr[r], w0.w, acc[r][3]);
            acc[r][4] = fmaf(xr[r], w1.x, acc[r][4]);
            acc[r][5] = fmaf(xr[r], w1.y, acc[r][5]);
            acc[r][6] = fmaf(xr[r], w1.z, acc[r][6]);
            acc[r][7] = fmaf(xr[r], w1.w, acc[r][7]);
        }
    }
#pragma unroll
    for (int r = 0; r < 4; ++r) {
        int grow = rowBase + ty * 4 + r;
        if (grow < nN) {
            float dv = dinv[grow];
            uint4 o;
            o.x = f2bf(dv * acc[r][0]) | (f2bf(dv * acc[r][1]) << 16);
            o.y = f2bf(dv * acc[r][2]) | (f2bf(dv * acc[r][3]) << 16);
            o.z = f2bf(dv * acc[r][4]) | (f2bf(dv * acc[r][5]) << 16);
            o.w = f2bf(dv * acc[r][6]) | (f2bf(dv * acc[r][7]) << 16);
            Pb[(size_t)grow * 16 + tx] = o;  // row = 16 uint4 = 128 bf16
        }
    }
}

// ---------------------------------------------------------------------------
// unpack 8 bf16 (uint4) and accumulate into 8 fp32
__device__ __forceinline__ void acc_bf8(const uint4 q, float* a) {
    union { uint32_t i; float f; } t;
    t.i = q.x << 16;          a[0] += t.f;
    t.i = q.x & 0xffff0000u;  a[1] += t.f;
    t.i = q.y << 16;          a[2] += t.f;
    t.i = q.y & 0xffff0000u;  a[3] += t.f;
    t.i = q.z << 16;          a[4] += t.f;
    t.i = q.z & 0xffff0000u;  a[5] += t.f;
    t.i = q.w << 16;          a[6] += t.f;
    t.i = q.w & 0xffff0000u;  a[7] += t.f;
}

// Xout[v] = relu(dinv[v]*(P[v] + sum_{in-edges} P[src]) + b)
// 16 lanes per node (uint4 = 8 bf16 each), 16 nodes per 256-thread block.
__global__ __launch_bounds__(256) void agg_kernel(const uint4* __restrict__ Pb,
                                                  const int* __restrict__ rowptr,
                                                  const int* __restrict__ ssrc,
                                                  const float* __restrict__ dinv,
                                                  const float* __restrict__ bias,
                                                  float* __restrict__ Xout, int nN) {
    const int lane = threadIdx.x & 15;
    const int grp = threadIdx.x >> 4;
    const int v = blockIdx.x * 16 + grp;
    if (v >= nN) return;
    float a0[8], a1[8], a2[8], a3[8];
#pragma unroll
    for (int i = 0; i < 8; ++i) { a0[i] = 0.f; a1[i] = 0.f; a2[i] = 0.f; a3[i] = 0.f; }
    acc_bf8(Pb[(size_t)v * 16 + lane], a0);  // self loop
    int e = rowptr[v];
    const int e1 = rowptr[v + 1];
    for (; e + 4 <= e1; e += 4) {
        const int u0 = ssrc[e + 0], u1 = ssrc[e + 1], u2 = ssrc[e + 2], u3 = ssrc[e + 3];
        uint4 q0 = Pb[(size_t)u0 * 16 + lane];
        uint4 q1 = Pb[(size_t)u1 * 16 + lane];
        uint4 q2 = Pb[(size_t)u2 * 16 + lane];
        uint4 q3 = Pb[(size_t)u3 * 16 + lane];
        acc_bf8(q0, a0); acc_bf8(q1, a1); acc_bf8(q2, a2); acc_bf8(q3, a3);
    }
    for (; e < e1; ++e) {
        uint4 q = Pb[(size_t)ssrc[e] * 16 + lane];
        acc_bf8(q, a1);
    }
    const float dv = dinv[v];
    const float4 bb0 = ((const float4*)bias)[lane * 2];
    const float4 bb1 = ((const float4*)bias)[lane * 2 + 1];
    float4 o0, o1;
    o0.x = fmaxf(fmaf(dv, (a0[0] + a1[0]) + (a2[0] + a3[0]), bb0.x), 0.f);
    o0.y = fmaxf(fmaf(dv, (a0[1] + a1[1]) + (a2[1] + a3[1]), bb0.y), 0.f);
    o0.z = fmaxf(fmaf(dv, (a0[2] + a1[2]) + (a2[2] + a3[2]), bb0.z), 0.f);
    o0.w = fmaxf(fmaf(dv, (a0[3] + a1[3]) + (a2[3] + a3[3]), bb0.w), 0.f);
    o1.x = fmaxf(fmaf(dv, (a0[4] + a1[4]) + (a2[4] + a3[4]), bb1.x), 0.f);
    o1.y = fmaxf(fmaf(dv, (a0[5] + a1[5]) + (a2[5] + a3[5]), bb1.y), 0.f);
    o1.z = fmaxf(fmaf(dv, (a0[6] + a1[6]) + (a2[6] + a3[6]), bb1.z), 0.f);
    o1.w = fmaxf(fmaf(dv, (a0[7] + a1[7]) + (a2[7] + a3[7]), bb1.w), 0.f);
    float4* X4 = (float4*)(Xout + (size_t)v * HID + lane * 8);
    X4[0] = o0;
    X4[1] = o1;
}

// ---------------------------------------------------------------------------
// global mean pool, phase 1: coalesced partial sums, flush per graph boundary.
// block = 256 threads covers 64 nodes; thread t: col = t&127, rows t>>7, step 2.
__global__ __launch_bounds__(256) void pool_partial(const float* __restrict__ X,
                                                    const int* __restrict__ batch,
                                                    float* __restrict__ psum, int nN) {
    const int c = threadIdx.x & 127;
    int n = blockIdx.x * 64 + (threadIdx.x >> 7);
    const int nEnd = min(blockIdx.x * 64 + 64, nN);
    float acc = 0.f;
    int g = -1;
    for (; n < nEnd; n += 2) {
        int gn = batch[n];
        float v = X[(size_t)n * HID + c];
        if (gn != g) {
            if (g >= 0) atomicAdd(&psum[g * HID + c], acc);
            g = gn;
            acc = v;
        } else {
            acc += v;
        }
    }
    if (g >= 0) atomicAdd(&psum[g * HID + c], acc);
}

// phase 2: divide by per-graph count (binary search over sorted batch)
__global__ __launch_bounds__(128) void pool_finalize(const float* __restrict__ psum,
                                                     const int* __restrict__ batch,
                                                     float* __restrict__ pooled, int nN) {
    const int g = blockIdx.x;
    int lo = 0, hi = nN;
    while (lo < hi) { int m = (lo + hi) >> 1; if (batch[m] < g) lo = m + 1; else hi = m; }
    const int start = lo;
    hi = nN;
    while (lo < hi) { int m = (lo + hi) >> 1; if (batch[m] < g + 1) lo = m + 1; else hi = m; }
    const float c = (float)max(lo - start, 1);
    pooled[g * HID + threadIdx.x] = psum[g * HID + threadIdx.x] / c;
}

// ---------------------------------------------------------------------------
// single-step LSTM from zero state + FC(2); f-gate irrelevant (c0=0)
__device__ __forceinline__ float sigmoidf_(float x) { return 1.0f / (1.0f + expf(-x)); }

__global__ __launch_bounds__(128) void lstm_fc_kernel(const float* __restrict__ pooled,
                                                      const float* __restrict__ W_ih,
                                                      const float* __restrict__ b_ih,
                                                      const float* __restrict__ b_hh,
                                                      const float* __restrict__ W_fc,
                                                      const float* __restrict__ b_fc,
                                                      float* __restrict__ out) {
    __shared__ float pv[HID];
    __shared__ float r0[2], r1[2];
    const int g = blockIdx.x, j = threadIdx.x;
    pv[j] = pooled[g * HID + j];
    __syncthreads();
    float di = b_ih[j] + b_hh[j];                 // i gate, rows 0..127
    float dg = b_ih[256 + j] + b_hh[256 + j];     // g gate, rows 256..383
    float dO = b_ih[384 + j] + b_hh[384 + j];     // o gate, rows 384..511
    const float4* pv4 = (const float4*)pv;
#pragma unroll 4
    for (int k4 = 0; k4 < 32; ++k4) {
        float4 p = pv4[k4];
        float4 wi = *(const float4*)(W_ih + (size_t)j * HID + k4 * 4);
        float4 wg = *(const float4*)(W_ih + (size_t)(256 + j) * HID + k4 * 4);
        float4 wo = *(const float4*)(W_ih + (size_t)(384 + j) * HID + k4 * 4);
        di += p.x * wi.x + p.y * wi.y + p.z * wi.z + p.w * wi.w;
        dg += p.x * wg.x + p.y * wg.y + p.z * wg.z + p.w * wg.w;
        dO += p.x * wo.x + p.y * wo.y + p.z * wo.z + p.w * wo.w;
    }
    float c = sigmoidf_(di) * tanhf(dg);
    float hn = sigmoidf_(dO) * tanhf(c);
    float p0 = hn * W_fc[j];
    float p1 = hn * W_fc[HID + j];
#pragma unroll
    for (int off = 32; off > 0; off >>= 1) {
        p0 += __shfl_down(p0, off, 64);
        p1 += __shfl_down(p1, off, 64);
    }
    const int w = j >> 6, l = j & 63;
    if (l == 0) { r0[w] = p0; r1[w] = p1; }
    __syncthreads();
    if (j == 0) {
        out[g * 2 + 0] = r0[0] + r0[1] + b_fc[0];
        out[g * 2 + 1] = r1[0] + r1[1] + b_fc[1];
    }
}

// ---------------------------------------------------------------------------
extern "C" void kernel_launch(void* const* d_in, const int* in_sizes, int n_in,
                              void* d_out, int out_size, void* d_ws, size_t ws_size,
                              hipStream_t stream) {
    const float* x      = (const float*)d_in[0];
    const int*   eidx   = (const int*)d_in[1];
    const int*   batch  = (const int*)d_in[2];
    const float* W0     = (const float*)d_in[4];
    const float* b0     = (const float*)d_in[5];
    const float* W1     = (const float*)d_in[6];
    const float* b1     = (const float*)d_in[7];
    const float* W2     = (const float*)d_in[8];
    const float* b2     = (const float*)d_in[9];
    const float* W_ih   = (const float*)d_in[10];
    const float* b_ih   = (const float*)d_in[12];
    const float* b_hh   = (const float*)d_in[13];
    const float* W_fc   = (const float*)d_in[14];
    const float* b_fc   = (const float*)d_in[15];
    float* out = (float*)d_out;

    const int nN = in_sizes[0] / HID;     // 100000
    const int nE = in_sizes[1] / 2;       // 1600000
    const int nG = out_size / 2;          // 256
    const int* src = eidx;
    const int* dst = eidx + nE;

    // workspace layout
    size_t off = 0;
    auto alloc = [&](size_t bytes) -> void* {
        void* p = (char*)d_ws + off;
        off += (bytes + 255) & ~(size_t)255;
        return p;
    };
    uint4* Pb     = (uint4*)alloc((size_t)nN * 16 * sizeof(uint4));  // bf16 P, 256 B/row
    float* B0     = (float*)alloc((size_t)nN * HID * sizeof(float));
    float* dinv   = (float*)alloc((size_t)nN * sizeof(float));
    int*   cnt    = (int*)alloc((size_t)nN * sizeof(int));
    int*   rowptr = (int*)alloc((size_t)(nN + 1) * sizeof(int));
    int*   ssrc   = (int*)alloc((size_t)nE * sizeof(int));
    uint2* ebuf   = (uint2*)alloc((size_t)nE * sizeof(uint2));       // bucket-sorted (src,dst)
    float* pooled = (float*)alloc((size_t)nG * HID * sizeof(float));
    float* psum   = (float*)alloc((size_t)nG * HID * sizeof(float));
    int*   blockSums = (int*)alloc(1024 * sizeof(int));
    int*   bcnt   = (int*)alloc(NBUCK_MAX * sizeof(int));
    int*   boff   = (int*)alloc(NBUCK_MAX * sizeof(int));
    int*   bcur   = (int*)alloc(NBUCK_MAX * sizeof(int));
    (void)ws_size;

    const int eBlocks = (nE + 255) / 256;
    const int scanBlocks = (nN + SCAN_CHUNK - 1) / SCAN_CHUNK;      // 98 for nN=100000
    const int nB = (nN + 255) >> 8;                                 // 391 buckets
    const int tileBlocks = (nE + EDGE_TILE - 1) / EDGE_TILE;        // 196

    // degrees + dinv + rowptr
    hipMemsetAsync(cnt, 0, (size_t)nN * sizeof(int), stream);
    count_kernel<<<eBlocks, 256, 0, stream>>>(dst, cnt, nE);
    scan_phase1<<<scanBlocks, 256, 0, stream>>>(cnt, blockSums, dinv, nN);
    scan_phase2<<<1, 256, 0, stream>>>(blockSums, scanBlocks);
    scan_phase3<<<scanBlocks, 256, 0, stream>>>(cnt, blockSums, rowptr, nN, nE);

    // multisplit CSR
    hipMemsetAsync(bcnt, 0, NBUCK_MAX * sizeof(int), stream);
    bucket_count<<<tileBlocks, 256, 0, stream>>>(dst, bcnt, nE, nB);
    bucket_scan<<<1, 512, 0, stream>>>(bcnt, boff, bcur, nB);
    bucket_scatter<<<tileBlocks, 256, 0, stream>>>(src, dst, bcur, ebuf, nE, nB);
    csr_from_buckets<<<nB, 256, 0, stream>>>(ebuf, boff, rowptr, ssrc, nE, nB);

    const int gemmBlocks = (nN + TILE_ROWS - 1) / TILE_ROWS;
    const int aggBlocks = (nN + 15) / 16;

    // layer 0
    gemm_scale_kernel<<<gemmBlocks, 256, 0, stream>>>(x, W0, dinv, Pb, nN);
    agg_kernel<<<aggBlocks, 256, 0, stream>>>(Pb, rowptr, ssrc, dinv, b0, B0, nN);
    // layer 1
    gemm_scale_kernel<<<gemmBlocks, 256, 0, stream>>>(B0, W1, dinv, Pb, nN);
    agg_kernel<<<aggBlocks, 256, 0, stream>>>(Pb, rowptr, ssrc, dinv, b1, B0, nN);
    // layer 2
    gemm_scale_kernel<<<gemmBlocks, 256, 0, stream>>>(B0, W2, dinv, Pb, nN);
    agg_kernel<<<aggBlocks, 256, 0, stream>>>(Pb, rowptr, ssrc, dinv, b2, B0, nN);

    // pool + LSTM + FC
    hipMemsetAsync(psum, 0, (size_t)nG * HID * sizeof(float), stream);
    pool_partial<<<(nN + 63) / 64, 256, 0, stream>>>(B0, batch, psum, nN);
    pool_finalize<<<nG, 128, 0, stream>>>(psum, batch, pooled, nN);
    lstm_fc_kernel<<<nG, 128, 0, stream>>>(pooled, W_ih, b_ih, b_hh, W_fc, b_fc, out);
}

// Round 6
// 537.647 us; speedup vs baseline: 2.1330x; 1.2602x over previous
//
#include <hip/hip_runtime.h>
#include <math.h>
#include <stdint.h>

#define HID 128
#define SCAN_CHUNK 1024   // elements per scan block (256 thr x 4)
#define NBUCK_MAX 512     // node buckets of 256 nodes each (nN<=131072)
#define EDGE_TILE 8192    // edges per block in bucket passes
#define GEMM_ROWS 128     // M-tile per block
#define XS_STRIDE 136     // bf16 elems per LDS row (128 + 8 pad -> 2-way max bank alias)

typedef short bf16x8 __attribute__((ext_vector_type(8)));
typedef float f32x4 __attribute__((ext_vector_type(4)));

// ---------------------------------------------------------------------------
// round-to-nearest-even fp32 -> bf16 bits
__device__ __forceinline__ unsigned int f2bf(float f) {
    union { float f; uint32_t i; } u; u.f = f;
    uint32_t r = u.i + 0x7fffu + ((u.i >> 16) & 1u);
    return r >> 16;
}

// ---------------------------------------------------------------------------
// CSR build: count in-degrees
__global__ __launch_bounds__(256) void count_kernel(const int* __restrict__ dst,
                                                    int* __restrict__ cnt, int nE) {
    int e = blockIdx.x * 256 + threadIdx.x;
    if (e < nE) atomicAdd(&cnt[dst[e]], 1);
}

// ---------------------------------------------------------------------------
// Hierarchical scan, phase 1: per-block sums of cnt (1024 elems/block) + fused dinv
__global__ __launch_bounds__(256) void scan_phase1(const int* __restrict__ cnt,
                                                   int* __restrict__ blockSums,
                                                   float* __restrict__ dinv, int nN) {
    __shared__ int sdata[256];
    const int t = threadIdx.x;
    const int idx = blockIdx.x * SCAN_CHUNK + t * 4;
    int v0 = 0, v1 = 0, v2 = 0, v3 = 0;
    if (idx + 3 < nN) {
        int4 v = *(const int4*)(cnt + idx);
        v0 = v.x; v1 = v.y; v2 = v.z; v3 = v.w;
        float4 dv;
        dv.x = rsqrtf((float)v0 + 1.0f);
        dv.y = rsqrtf((float)v1 + 1.0f);
        dv.z = rsqrtf((float)v2 + 1.0f);
        dv.w = rsqrtf((float)v3 + 1.0f);
        *(float4*)(dinv + idx) = dv;
    } else {
        if (idx     < nN) { v0 = cnt[idx];     dinv[idx]     = rsqrtf((float)v0 + 1.0f); }
        if (idx + 1 < nN) { v1 = cnt[idx + 1]; dinv[idx + 1] = rsqrtf((float)v1 + 1.0f); }
        if (idx + 2 < nN) { v2 = cnt[idx + 2]; dinv[idx + 2] = rsqrtf((float)v2 + 1.0f); }
        if (idx + 3 < nN) { v3 = cnt[idx + 3]; dinv[idx + 3] = rsqrtf((float)v3 + 1.0f); }
    }
    sdata[t] = v0 + v1 + v2 + v3;
    __syncthreads();
#pragma unroll
    for (int off = 128; off > 0; off >>= 1) {
        if (t < off) sdata[t] += sdata[t + off];
        __syncthreads();
    }
    if (t == 0) blockSums[blockIdx.x] = sdata[0];
}

// phase 2: single small block converts blockSums -> exclusive offsets (nB <= 256)
__global__ __launch_bounds__(256) void scan_phase2(int* __restrict__ blockSums, int nB) {
    __shared__ int sd[256];
    const int t = threadIdx.x;
    sd[t] = (t < nB) ? blockSums[t] : 0;
    __syncthreads();
#pragma unroll
    for (int off = 1; off < 256; off <<= 1) {
        int v = sd[t];
        int add = (t >= off) ? sd[t - off] : 0;
        __syncthreads();
        sd[t] = v + add;
        __syncthreads();
    }
    if (t < nB) blockSums[t] = (t > 0) ? sd[t - 1] : 0;  // exclusive
}

// phase 3: per-block exclusive scan + global offset -> rowptr
__global__ __launch_bounds__(256) void scan_phase3(const int* __restrict__ cnt,
                                                   const int* __restrict__ blockOffsets,
                                                   int* __restrict__ rowptr, int nN, int nE) {
    __shared__ int sdata[256];
    const int t = threadIdx.x;
    const int idx = blockIdx.x * SCAN_CHUNK + t * 4;
    int v0 = 0, v1 = 0, v2 = 0, v3 = 0;
    if (idx + 3 < nN) {
        int4 v = *(const int4*)(cnt + idx);
        v0 = v.x; v1 = v.y; v2 = v.z; v3 = v.w;
    } else {
        if (idx     < nN) v0 = cnt[idx];
        if (idx + 1 < nN) v1 = cnt[idx + 1];
        if (idx + 2 < nN) v2 = cnt[idx + 2];
        if (idx + 3 < nN) v3 = cnt[idx + 3];
    }
    sdata[t] = v0 + v1 + v2 + v3;
    __syncthreads();
#pragma unroll
    for (int off = 1; off < 256; off <<= 1) {
        int v = sdata[t];
        int add = (t >= off) ? sdata[t - off] : 0;
        __syncthreads();
        sdata[t] = v + add;
        __syncthreads();
    }
    const int pre = blockOffsets[blockIdx.x] + ((t > 0) ? sdata[t - 1] : 0);
    if (idx + 3 < nN) {
        *(int4*)(rowptr + idx) = make_int4(pre, pre + v0, pre + v0 + v1, pre + v0 + v1 + v2);
    } else {
        if (idx     < nN) rowptr[idx]     = pre;
        if (idx + 1 < nN) rowptr[idx + 1] = pre + v0;
        if (idx + 2 < nN) rowptr[idx + 2] = pre + v0 + v1;
        if (idx + 3 < nN) rowptr[idx + 3] = pre + v0 + v1 + v2;
    }
    if (blockIdx.x == 0 && t == 0) rowptr[nN] = nE;
}

// ---------------------------------------------------------------------------
// Multisplit CSR build. Bucket = dst >> 8 (256 nodes/bucket).
__global__ __launch_bounds__(256) void bucket_count(const int* __restrict__ dst,
                                                    int* __restrict__ bcnt, int nE, int nB) {
    __shared__ int h[NBUCK_MAX];
    for (int i = threadIdx.x; i < nB; i += 256) h[i] = 0;
    __syncthreads();
    const int base = blockIdx.x * EDGE_TILE;
    const int end = min(base + EDGE_TILE, nE);
    for (int e = base + threadIdx.x; e < end; e += 256)
        atomicAdd(&h[dst[e] >> 8], 1);
    __syncthreads();
    for (int i = threadIdx.x; i < nB; i += 256)
        if (h[i]) atomicAdd(&bcnt[i], h[i]);
}

__global__ __launch_bounds__(512) void bucket_scan(const int* __restrict__ bcnt,
                                                   int* __restrict__ boff,
                                                   int* __restrict__ bcur, int nB) {
    __shared__ int sd[512];
    const int t = threadIdx.x;
    sd[t] = (t < nB) ? bcnt[t] : 0;
    __syncthreads();
#pragma unroll
    for (int off = 1; off < 512; off <<= 1) {
        int v = sd[t];
        int add = (t >= off) ? sd[t - off] : 0;
        __syncthreads();
        sd[t] = v + add;
        __syncthreads();
    }
    if (t < nB) {
        int ex = (t > 0) ? sd[t - 1] : 0;
        boff[t] = ex;
        bcur[t] = ex;
    }
}

__global__ __launch_bounds__(256) void bucket_scatter(const int* __restrict__ src,
                                                      const int* __restrict__ dst,
                                                      int* __restrict__ bcur,
                                                      uint2* __restrict__ ebuf, int nE, int nB) {
    __shared__ int h[NBUCK_MAX];
    __shared__ int basearr[NBUCK_MAX];
    const int base = blockIdx.x * EDGE_TILE;
    const int end = min(base + EDGE_TILE, nE);
    for (int i = threadIdx.x; i < nB; i += 256) h[i] = 0;
    __syncthreads();
    for (int e = base + threadIdx.x; e < end; e += 256)
        atomicAdd(&h[dst[e] >> 8], 1);
    __syncthreads();
    for (int i = threadIdx.x; i < nB; i += 256) {
        int c = h[i];
        basearr[i] = c ? atomicAdd(&bcur[i], c) : 0;
        h[i] = 0;   // reuse as local cursor
    }
    __syncthreads();
    for (int e = base + threadIdx.x; e < end; e += 256) {
        int d = dst[e];
        int b = d >> 8;
        int pos = basearr[b] + atomicAdd(&h[b], 1);
        ebuf[pos] = make_uint2((unsigned)src[e], (unsigned)d);
    }
}

__global__ __launch_bounds__(256) void csr_from_buckets(const uint2* __restrict__ ebuf,
                                                        const int* __restrict__ boff,
                                                        const int* __restrict__ rowptr,
                                                        int* __restrict__ ssrc, int nE, int nB) {
    __shared__ int cur[256];
    const int b = blockIdx.x;
    const int e0 = boff[b];
    const int e1 = (b + 1 < nB) ? boff[b + 1] : nE;
    cur[threadIdx.x] = 0;
    __syncthreads();
    for (int e = e0 + threadIdx.x; e < e1; e += 256) {
        uint2 ed = ebuf[e];
        int d = (int)ed.y;
        int pos = rowptr[d] + atomicAdd(&cur[d & 255], 1);
        ssrc[pos] = (int)ed.x;
    }
}

// ---------------------------------------------------------------------------
// fp32 x -> bf16 Xb (row = 16 uint4 = 128 bf16)
__global__ __launch_bounds__(256) void xcvt_kernel(const float* __restrict__ x,
                                                   uint4* __restrict__ Xb, int total) {
    int i = blockIdx.x * 256 + threadIdx.x;   // one uint4 out = 8 floats in
    if (i < total) {
        const float4* xp = (const float4*)x + (size_t)i * 2;
        float4 u = xp[0], v = xp[1];
        uint4 o;
        o.x = f2bf(u.x) | (f2bf(u.y) << 16);
        o.y = f2bf(u.z) | (f2bf(u.w) << 16);
        o.z = f2bf(v.x) | (f2bf(v.y) << 16);
        o.w = f2bf(v.z) | (f2bf(v.w) << 16);
        Xb[i] = o;
    }
}

// transpose+convert 3 weight matrices: Wt[n][k] = bf16(W[k][n]); 3 x 128 x 128
__global__ __launch_bounds__(256) void wt_kernel(const float* __restrict__ W0,
                                                 const float* __restrict__ W1,
                                                 const float* __restrict__ W2,
                                                 unsigned short* __restrict__ Wtb) {
    int i = blockIdx.x * 256 + threadIdx.x;   // 0..49151
    if (i < 3 * HID * HID) {
        int w = i >> 14, r = i & 16383;
        int n = r >> 7, k = r & 127;
        const float* W = (w == 0) ? W0 : (w == 1) ? W1 : W2;
        Wtb[i] = (unsigned short)f2bf(W[k * HID + n]);
    }
}

// ---------------------------------------------------------------------------
// MFMA GEMM: Pb = bf16(dinv ⊙ (Xb @ W)), Xb/Wt bf16 in, fp32 accumulate.
// Block: 128 rows x 128 cols, 4 waves; wave = 32 rows (2 m-tiles) x 8 n-tiles.
// mfma_f32_16x16x32_bf16: A/B frag [m|n=lane&15][k=quad*8+j]; C/D col=lane&15,row=quad*4+reg.
__global__ __launch_bounds__(256) void gemm_mfma_kernel(const uint4* __restrict__ Xb,
                                                        const uint4* __restrict__ Wtb,
                                                        const float* __restrict__ dinv,
                                                        unsigned int* __restrict__ Pb32,
                                                        int nN) {
    __shared__ short Xs[GEMM_ROWS * XS_STRIDE];
    __shared__ short Ws[HID * XS_STRIDE];
    const int tid = threadIdx.x;
    const int rowBase = blockIdx.x * GEMM_ROWS;
#pragma unroll
    for (int it = 0; it < 8; ++it) {   // 2048 uint4 X-tile
        int f = it * 256 + tid;
        int row = f >> 4, c = f & 15;
        uint4 v = Xb[(size_t)(rowBase + row) * 16 + c];
        *(uint4*)(&Xs[row * XS_STRIDE + c * 8]) = v;
    }
#pragma unroll
    for (int it = 0; it < 8; ++it) {   // 2048 uint4 W-tile
        int f = it * 256 + tid;
        int n = f >> 4, c = f & 15;
        *(uint4*)(&Ws[n * XS_STRIDE + c * 8]) = Wtb[f];
    }
    __syncthreads();
    const int wave = tid >> 6, lane = tid & 63;
    const int quad = lane >> 4, l16 = lane & 15;
    f32x4 acc[2][8] = {};
    const int kq = quad * 8;
#pragma unroll
    for (int ks = 0; ks < 4; ++ks) {
        const int k0 = ks * 32 + kq;
        bf16x8 a0 = *(const bf16x8*)(&Xs[(wave * 32 + l16) * XS_STRIDE + k0]);
        bf16x8 a1 = *(const bf16x8*)(&Xs[(wave * 32 + 16 + l16) * XS_STRIDE + k0]);
#pragma unroll
        for (int nt = 0; nt < 8; ++nt) {
            bf16x8 b = *(const bf16x8*)(&Ws[(nt * 16 + l16) * XS_STRIDE + k0]);
            acc[0][nt] = __builtin_amdgcn_mfma_f32_16x16x32_bf16(a0, b, acc[0][nt], 0, 0, 0);
            acc[1][nt] = __builtin_amdgcn_mfma_f32_16x16x32_bf16(a1, b, acc[1][nt], 0, 0, 0);
        }
    }
    // epilogue: scale by dinv[row], pack col pairs via shfl, store uint (2 bf16)
#pragma unroll
    for (int mt = 0; mt < 2; ++mt) {
        const int gr0 = rowBase + wave * 32 + mt * 16 + quad * 4;
#pragma unroll
        for (int r = 0; r < 4; ++r) {
            const int gr = gr0 + r;
            const bool ok = gr < nN;
            const float d = ok ? dinv[gr] : 0.f;
#pragma unroll
            for (int nt = 0; nt < 8; ++nt) {
                float v = d * acc[mt][nt][r];
                float vo = __shfl_xor(v, 1, 64);
                if (ok && !(l16 & 1)) {
                    Pb32[(size_t)gr * 64 + nt * 8 + (l16 >> 1)] = f2bf(v) | (f2bf(vo) << 16);
                }
            }
        }
    }
}

// ---------------------------------------------------------------------------
// unpack 8 bf16 (uint4) and accumulate into 8 fp32
__device__ __forceinline__ void acc_bf8(const uint4 q, float* a) {
    union { uint32_t i; float f; } t;
    t.i = q.x << 16;          a[0] += t.f;
    t.i = q.x & 0xffff0000u;  a[1] += t.f;
    t.i = q.y << 16;          a[2] += t.f;
    t.i = q.y & 0xffff0000u;  a[3] += t.f;
    t.i = q.z << 16;          a[4] += t.f;
    t.i = q.z & 0xffff0000u;  a[5] += t.f;
    t.i = q.w << 16;          a[6] += t.f;
    t.i = q.w & 0xffff0000u;  a[7] += t.f;
}

// Xout[v] = relu(dinv[v]*(P[v] + sum_in P[src]) + b); 16 lanes/node.
// Outputs: bf16 (Xb_out, for next gemm) and/or fp32 (Xf_out, for pool).
__global__ __launch_bounds__(256) void agg_kernel(const uint4* __restrict__ Pb,
                                                  const int* __restrict__ rowptr,
                                                  const int* __restrict__ ssrc,
                                                  const float* __restrict__ dinv,
                                                  const float* __restrict__ bias,
                                                  uint4* __restrict__ Xb_out,
                                                  float* __restrict__ Xf_out, int nN) {
    const int lane = threadIdx.x & 15;
    const int grp = threadIdx.x >> 4;
    const int v = blockIdx.x * 16 + grp;
    if (v >= nN) return;
    float a0[8], a1[8], a2[8], a3[8];
#pragma unroll
    for (int i = 0; i < 8; ++i) { a0[i] = 0.f; a1[i] = 0.f; a2[i] = 0.f; a3[i] = 0.f; }
    acc_bf8(Pb[(size_t)v * 16 + lane], a0);  // self loop
    int e = rowptr[v];
    const int e1 = rowptr[v + 1];
    for (; e + 4 <= e1; e += 4) {
        const int u0 = ssrc[e + 0], u1 = ssrc[e + 1], u2 = ssrc[e + 2], u3 = ssrc[e + 3];
        uint4 q0 = Pb[(size_t)u0 * 16 + lane];
        uint4 q1 = Pb[(size_t)u1 * 16 + lane];
        uint4 q2 = Pb[(size_t)u2 * 16 + lane];
        uint4 q3 = Pb[(size_t)u3 * 16 + lane];
        acc_bf8(q0, a0); acc_bf8(q1, a1); acc_bf8(q2, a2); acc_bf8(q3, a3);
    }
    for (; e < e1; ++e) {
        uint4 q = Pb[(size_t)ssrc[e] * 16 + lane];
        acc_bf8(q, a1);
    }
    const float dv = dinv[v];
    const float4 bb0 = ((const float4*)bias)[lane * 2];
    const float4 bb1 = ((const float4*)bias)[lane * 2 + 1];
    float4 o0, o1;
    o0.x = fmaxf(fmaf(dv, (a0[0] + a1[0]) + (a2[0] + a3[0]), bb0.x), 0.f);
    o0.y = fmaxf(fmaf(dv, (a0[1] + a1[1]) + (a2[1] + a3[1]), bb0.y), 0.f);
    o0.z = fmaxf(fmaf(dv, (a0[2] + a1[2]) + (a2[2] + a3[2]), bb0.z), 0.f);
    o0.w = fmaxf(fmaf(dv, (a0[3] + a1[3]) + (a2[3] + a3[3]), bb0.w), 0.f);
    o1.x = fmaxf(fmaf(dv, (a0[4] + a1[4]) + (a2[4] + a3[4]), bb1.x), 0.f);
    o1.y = fmaxf(fmaf(dv, (a0[5] + a1[5]) + (a2[5] + a3[5]), bb1.y), 0.f);
    o1.z = fmaxf(fmaf(dv, (a0[6] + a1[6]) + (a2[6] + a3[6]), bb1.z), 0.f);
    o1.w = fmaxf(fmaf(dv, (a0[7] + a1[7]) + (a2[7] + a3[7]), bb1.w), 0.f);
    if (Xb_out) {
        uint4 q;
        q.x = f2bf(o0.x) | (f2bf(o0.y) << 16);
        q.y = f2bf(o0.z) | (f2bf(o0.w) << 16);
        q.z = f2bf(o1.x) | (f2bf(o1.y) << 16);
        q.w = f2bf(o1.z) | (f2bf(o1.w) << 16);
        Xb_out[(size_t)v * 16 + lane] = q;
    }
    if (Xf_out) {
        float4* X4 = (float4*)(Xf_out + (size_t)v * HID + lane * 8);
        X4[0] = o0;
        X4[1] = o1;
    }
}

// ---------------------------------------------------------------------------
// global mean pool, phase 1: coalesced partial sums, flush per graph boundary.
__global__ __launch_bounds__(256) void pool_partial(const float* __restrict__ X,
                                                    const int* __restrict__ batch,
                                                    float* __restrict__ psum, int nN) {
    const int c = threadIdx.x & 127;
    int n = blockIdx.x * 64 + (threadIdx.x >> 7);
    const int nEnd = min(blockIdx.x * 64 + 64, nN);
    float acc = 0.f;
    int g = -1;
    for (; n < nEnd; n += 2) {
        int gn = batch[n];
        float v = X[(size_t)n * HID + c];
        if (gn != g) {
            if (g >= 0) atomicAdd(&psum[g * HID + c], acc);
            g = gn;
            acc = v;
        } else {
            acc += v;
        }
    }
    if (g >= 0) atomicAdd(&psum[g * HID + c], acc);
}

// phase 2: divide by per-graph count (binary search over sorted batch)
__global__ __launch_bounds__(128) void pool_finalize(const float* __restrict__ psum,
                                                     const int* __restrict__ batch,
                                                     float* __restrict__ pooled, int nN) {
    const int g = blockIdx.x;
    int lo = 0, hi = nN;
    while (lo < hi) { int m = (lo + hi) >> 1; if (batch[m] < g) lo = m + 1; else hi = m; }
    const int start = lo;
    hi = nN;
    while (lo < hi) { int m = (lo + hi) >> 1; if (batch[m] < g + 1) lo = m + 1; else hi = m; }
    const float c = (float)max(lo - start, 1);
    pooled[g * HID + threadIdx.x] = psum[g * HID + threadIdx.x] / c;
}

// ---------------------------------------------------------------------------
// single-step LSTM from zero state + FC(2); f-gate irrelevant (c0=0)
__device__ __forceinline__ float sigmoidf_(float x) { return 1.0f / (1.0f + expf(-x)); }

__global__ __launch_bounds__(128) void lstm_fc_kernel(const float* __restrict__ pooled,
                                                      const float* __restrict__ W_ih,
                                                      const float* __restrict__ b_ih,
                                                      const float* __restrict__ b_hh,
                                                      const float* __restrict__ W_fc,
                                                      const float* __restrict__ b_fc,
                                                      float* __restrict__ out) {
    __shared__ float pv[HID];
    __shared__ float r0[2], r1[2];
    const int g = blockIdx.x, j = threadIdx.x;
    pv[j] = pooled[g * HID + j];
    __syncthreads();
    float di = b_ih[j] + b_hh[j];
    float dg = b_ih[256 + j] + b_hh[256 + j];
    float dO = b_ih[384 + j] + b_hh[384 + j];
    const float4* pv4 = (const float4*)pv;
#pragma unroll 4
    for (int k4 = 0; k4 < 32; ++k4) {
        float4 p = pv4[k4];
        float4 wi = *(const float4*)(W_ih + (size_t)j * HID + k4 * 4);
        float4 wg = *(const float4*)(W_ih + (size_t)(256 + j) * HID + k4 * 4);
        float4 wo = *(const float4*)(W_ih + (size_t)(384 + j) * HID + k4 * 4);
        di += p.x * wi.x + p.y * wi.y + p.z * wi.z + p.w * wi.w;
        dg += p.x * wg.x + p.y * wg.y + p.z * wg.z + p.w * wg.w;
        dO += p.x * wo.x + p.y * wo.y + p.z * wo.z + p.w * wo.w;
    }
    float c = sigmoidf_(di) * tanhf(dg);
    float hn = sigmoidf_(dO) * tanhf(c);
    float p0 = hn * W_fc[j];
    float p1 = hn * W_fc[HID + j];
#pragma unroll
    for (int off = 32; off > 0; off >>= 1) {
        p0 += __shfl_down(p0, off, 64);
        p1 += __shfl_down(p1, off, 64);
    }
    const int w = j >> 6, l = j & 63;
    if (l == 0) { r0[w] = p0; r1[w] = p1; }
    __syncthreads();
    if (j == 0) {
        out[g * 2 + 0] = r0[0] + r0[1] + b_fc[0];
        out[g * 2 + 1] = r1[0] + r1[1] + b_fc[1];
    }
}

// ---------------------------------------------------------------------------
extern "C" void kernel_launch(void* const* d_in, const int* in_sizes, int n_in,
                              void* d_out, int out_size, void* d_ws, size_t ws_size,
                              hipStream_t stream) {
    const float* x      = (const float*)d_in[0];
    const int*   eidx   = (const int*)d_in[1];
    const int*   batch  = (const int*)d_in[2];
    const float* W0     = (const float*)d_in[4];
    const float* b0     = (const float*)d_in[5];
    const float* W1     = (const float*)d_in[6];
    const float* b1     = (const float*)d_in[7];
    const float* W2     = (const float*)d_in[8];
    const float* b2     = (const float*)d_in[9];
    const float* W_ih   = (const float*)d_in[10];
    const float* b_ih   = (const float*)d_in[12];
    const float* b_hh   = (const float*)d_in[13];
    const float* W_fc   = (const float*)d_in[14];
    const float* b_fc   = (const float*)d_in[15];
    float* out = (float*)d_out;

    const int nN = in_sizes[0] / HID;     // 100000
    const int nE = in_sizes[1] / 2;       // 1600000
    const int nG = out_size / 2;          // 256
    const int* src = eidx;
    const int* dst = eidx + nE;
    const int rowsPad = (nN + GEMM_ROWS - 1) & ~(GEMM_ROWS - 1);  // 100096

    // workspace layout
    size_t off = 0;
    auto alloc = [&](size_t bytes) -> void* {
        void* p = (char*)d_ws + off;
        off += (bytes + 255) & ~(size_t)255;
        return p;
    };
    uint4* Pb     = (uint4*)alloc((size_t)rowsPad * 16 * sizeof(uint4));  // bf16 P
    // Xb (bf16 activations) and B0 (fp32, pool input) never live simultaneously:
    char*  xbB0   = (char*)alloc((size_t)nN * HID * sizeof(float));
    uint4* Xb     = (uint4*)xbB0;
    float* B0     = (float*)xbB0;
    float* dinv   = (float*)alloc((size_t)nN * sizeof(float));
    int*   cnt    = (int*)alloc((size_t)nN * sizeof(int));
    int*   rowptr = (int*)alloc((size_t)(nN + 1) * sizeof(int));
    int*   ssrc   = (int*)alloc((size_t)nE * sizeof(int));
    uint2* ebuf   = (uint2*)alloc((size_t)nE * sizeof(uint2));
    float* pooled = (float*)alloc((size_t)nG * HID * sizeof(float));
    float* psum   = (float*)alloc((size_t)nG * HID * sizeof(float));
    int*   blockSums = (int*)alloc(1024 * sizeof(int));
    int*   bcnt   = (int*)alloc(NBUCK_MAX * sizeof(int));
    int*   boff   = (int*)alloc(NBUCK_MAX * sizeof(int));
    int*   bcur   = (int*)alloc(NBUCK_MAX * sizeof(int));
    unsigned short* Wtb = (unsigned short*)alloc(3 * HID * HID * sizeof(unsigned short));
    (void)ws_size;

    const int eBlocks = (nE + 255) / 256;
    const int scanBlocks = (nN + SCAN_CHUNK - 1) / SCAN_CHUNK;
    const int nB = (nN + 255) >> 8;
    const int tileBlocks = (nE + EDGE_TILE - 1) / EDGE_TILE;

    // degrees + dinv + rowptr
    hipMemsetAsync(cnt, 0, (size_t)nN * sizeof(int), stream);
    count_kernel<<<eBlocks, 256, 0, stream>>>(dst, cnt, nE);
    scan_phase1<<<scanBlocks, 256, 0, stream>>>(cnt, blockSums, dinv, nN);
    scan_phase2<<<1, 256, 0, stream>>>(blockSums, scanBlocks);
    scan_phase3<<<scanBlocks, 256, 0, stream>>>(cnt, blockSums, rowptr, nN, nE);

    // multisplit CSR
    hipMemsetAsync(bcnt, 0, NBUCK_MAX * sizeof(int), stream);
    bucket_count<<<tileBlocks, 256, 0, stream>>>(dst, bcnt, nE, nB);
    bucket_scan<<<1, 512, 0, stream>>>(bcnt, boff, bcur, nB);
    bucket_scatter<<<tileBlocks, 256, 0, stream>>>(src, dst, bcur, ebuf, nE, nB);
    csr_from_buckets<<<nB, 256, 0, stream>>>(ebuf, boff, rowptr, ssrc, nE, nB);

    // bf16 conversions
    const int xTotal = nN * 16;  // uint4 units
    xcvt_kernel<<<(xTotal + 255) / 256, 256, 0, stream>>>(x, Xb, xTotal);
    wt_kernel<<<(3 * HID * HID + 255) / 256, 256, 0, stream>>>(W0, W1, W2, Wtb);

    const int gemmBlocks = rowsPad / GEMM_ROWS;
    const int aggBlocks = (nN + 15) / 16;
    const uint4* Wt0 = (const uint4*)Wtb;
    const uint4* Wt1 = (const uint4*)(Wtb + HID * HID);
    const uint4* Wt2 = (const uint4*)(Wtb + 2 * HID * HID);

    // layer 0
    gemm_mfma_kernel<<<gemmBlocks, 256, 0, stream>>>(Xb, Wt0, dinv, (unsigned int*)Pb, nN);
    agg_kernel<<<aggBlocks, 256, 0, stream>>>(Pb, rowptr, ssrc, dinv, b0, Xb, nullptr, nN);
    // layer 1
    gemm_mfma_kernel<<<gemmBlocks, 256, 0, stream>>>(Xb, Wt1, dinv, (unsigned int*)Pb, nN);
    agg_kernel<<<aggBlocks, 256, 0, stream>>>(Pb, rowptr, ssrc, dinv, b1, Xb, nullptr, nN);
    // layer 2
    gemm_mfma_kernel<<<gemmBlocks, 256, 0, stream>>>(Xb, Wt2, dinv, (unsigned int*)Pb, nN);
    agg_kernel<<<aggBlocks, 256, 0, stream>>>(Pb, rowptr, ssrc, dinv, b2, nullptr, B0, nN);

    // pool + LSTM + FC
    hipMemsetAsync(psum, 0, (size_t)nG * HID * sizeof(float), stream);
    pool_partial<<<(nN + 63) / 64, 256, 0, stream>>>(B0, batch, psum, nN);
    pool_finalize<<<nG, 128, 0, stream>>>(psum, batch, pooled, nN);
    lstm_fc_kernel<<<nG, 128, 0, stream>>>(pooled, W_ih, b_ih, b_hh, W_fc, b_fc, out);
}

// Round 7
// 480.277 us; speedup vs baseline: 2.3878x; 1.1195x over previous
//
#include <hip/hip_runtime.h>
#include <math.h>
#include <stdint.h>

#define HID 128
#define SCAN_CHUNK 1024   // elements per scan block (256 thr x 4)
#define NBUCK_MAX 512     // node buckets of 256 nodes each (nN<=131072)
#define EDGE_TILE 8192    // edges per block in bucket passes
#define GEMM_ROWS 128     // M-tile per block
#define XS_STRIDE 136     // bf16 elems per LDS row (128 + 8 pad -> 2-way max bank alias)

typedef short bf16x8 __attribute__((ext_vector_type(8)));
typedef float f32x4 __attribute__((ext_vector_type(4)));

// ---------------------------------------------------------------------------
// round-to-nearest-even fp32 -> bf16 bits
__device__ __forceinline__ unsigned int f2bf(float f) {
    union { float f; uint32_t i; } u; u.f = f;
    uint32_t r = u.i + 0x7fffu + ((u.i >> 16) & 1u);
    return r >> 16;
}

// ---------------------------------------------------------------------------
// Hierarchical scan, phase 1: per-block sums of cnt (1024 elems/block) + fused dinv
__global__ __launch_bounds__(256) void scan_phase1(const int* __restrict__ cnt,
                                                   int* __restrict__ blockSums,
                                                   float* __restrict__ dinv, int nN) {
    __shared__ int sdata[256];
    const int t = threadIdx.x;
    const int idx = blockIdx.x * SCAN_CHUNK + t * 4;
    int v0 = 0, v1 = 0, v2 = 0, v3 = 0;
    if (idx + 3 < nN) {
        int4 v = *(const int4*)(cnt + idx);
        v0 = v.x; v1 = v.y; v2 = v.z; v3 = v.w;
        float4 dv;
        dv.x = rsqrtf((float)v0 + 1.0f);
        dv.y = rsqrtf((float)v1 + 1.0f);
        dv.z = rsqrtf((float)v2 + 1.0f);
        dv.w = rsqrtf((float)v3 + 1.0f);
        *(float4*)(dinv + idx) = dv;
    } else {
        if (idx     < nN) { v0 = cnt[idx];     dinv[idx]     = rsqrtf((float)v0 + 1.0f); }
        if (idx + 1 < nN) { v1 = cnt[idx + 1]; dinv[idx + 1] = rsqrtf((float)v1 + 1.0f); }
        if (idx + 2 < nN) { v2 = cnt[idx + 2]; dinv[idx + 2] = rsqrtf((float)v2 + 1.0f); }
        if (idx + 3 < nN) { v3 = cnt[idx + 3]; dinv[idx + 3] = rsqrtf((float)v3 + 1.0f); }
    }
    sdata[t] = v0 + v1 + v2 + v3;
    __syncthreads();
#pragma unroll
    for (int off = 128; off > 0; off >>= 1) {
        if (t < off) sdata[t] += sdata[t + off];
        __syncthreads();
    }
    if (t == 0) blockSums[blockIdx.x] = sdata[0];
}

// phase 2: single small block converts blockSums -> exclusive offsets (nB <= 256)
__global__ __launch_bounds__(256) void scan_phase2(int* __restrict__ blockSums, int nB) {
    __shared__ int sd[256];
    const int t = threadIdx.x;
    sd[t] = (t < nB) ? blockSums[t] : 0;
    __syncthreads();
#pragma unroll
    for (int off = 1; off < 256; off <<= 1) {
        int v = sd[t];
        int add = (t >= off) ? sd[t - off] : 0;
        __syncthreads();
        sd[t] = v + add;
        __syncthreads();
    }
    if (t < nB) blockSums[t] = (t > 0) ? sd[t - 1] : 0;  // exclusive
}

// phase 3: per-block exclusive scan + global offset -> rowptr
__global__ __launch_bounds__(256) void scan_phase3(const int* __restrict__ cnt,
                                                   const int* __restrict__ blockOffsets,
                                                   int* __restrict__ rowptr, int nN, int nE) {
    __shared__ int sdata[256];
    const int t = threadIdx.x;
    const int idx = blockIdx.x * SCAN_CHUNK + t * 4;
    int v0 = 0, v1 = 0, v2 = 0, v3 = 0;
    if (idx + 3 < nN) {
        int4 v = *(const int4*)(cnt + idx);
        v0 = v.x; v1 = v.y; v2 = v.z; v3 = v.w;
    } else {
        if (idx     < nN) v0 = cnt[idx];
        if (idx + 1 < nN) v1 = cnt[idx + 1];
        if (idx + 2 < nN) v2 = cnt[idx + 2];
        if (idx + 3 < nN) v3 = cnt[idx + 3];
    }
    sdata[t] = v0 + v1 + v2 + v3;
    __syncthreads();
#pragma unroll
    for (int off = 1; off < 256; off <<= 1) {
        int v = sdata[t];
        int add = (t >= off) ? sdata[t - off] : 0;
        __syncthreads();
        sdata[t] = v + add;
        __syncthreads();
    }
    const int pre = blockOffsets[blockIdx.x] + ((t > 0) ? sdata[t - 1] : 0);
    if (idx + 3 < nN) {
        *(int4*)(rowptr + idx) = make_int4(pre, pre + v0, pre + v0 + v1, pre + v0 + v1 + v2);
    } else {
        if (idx     < nN) rowptr[idx]     = pre;
        if (idx + 1 < nN) rowptr[idx + 1] = pre + v0;
        if (idx + 2 < nN) rowptr[idx + 2] = pre + v0 + v1;
        if (idx + 3 < nN) rowptr[idx + 3] = pre + v0 + v1 + v2;
    }
    if (blockIdx.x == 0 && t == 0) rowptr[nN] = nE;
}

// ---------------------------------------------------------------------------
// Multisplit CSR build. Bucket = dst >> 8 (256 nodes/bucket).
__global__ __launch_bounds__(256) void bucket_count(const int* __restrict__ dst,
                                                    int* __restrict__ bcnt, int nE, int nB) {
    __shared__ int h[NBUCK_MAX];
    for (int i = threadIdx.x; i < nB; i += 256) h[i] = 0;
    __syncthreads();
    const int base = blockIdx.x * EDGE_TILE;
    const int end = min(base + EDGE_TILE, nE);
    for (int e = base + threadIdx.x; e < end; e += 256)
        atomicAdd(&h[dst[e] >> 8], 1);
    __syncthreads();
    for (int i = threadIdx.x; i < nB; i += 256)
        if (h[i]) atomicAdd(&bcnt[i], h[i]);
}

__global__ __launch_bounds__(512) void bucket_scan(const int* __restrict__ bcnt,
                                                   int* __restrict__ boff,
                                                   int* __restrict__ bcur, int nB) {
    __shared__ int sd[512];
    const int t = threadIdx.x;
    sd[t] = (t < nB) ? bcnt[t] : 0;
    __syncthreads();
#pragma unroll
    for (int off = 1; off < 512; off <<= 1) {
        int v = sd[t];
        int add = (t >= off) ? sd[t - off] : 0;
        __syncthreads();
        sd[t] = v + add;
        __syncthreads();
    }
    if (t < nB) {
        int ex = (t > 0) ? sd[t - 1] : 0;
        boff[t] = ex;
        bcur[t] = ex;
    }
}

__global__ __launch_bounds__(256) void bucket_scatter(const int* __restrict__ src,
                                                      const int* __restrict__ dst,
                                                      int* __restrict__ bcur,
                                                      uint2* __restrict__ ebuf, int nE, int nB) {
    __shared__ int h[NBUCK_MAX];
    __shared__ int basearr[NBUCK_MAX];
    const int base = blockIdx.x * EDGE_TILE;
    const int end = min(base + EDGE_TILE, nE);
    for (int i = threadIdx.x; i < nB; i += 256) h[i] = 0;
    __syncthreads();
    for (int e = base + threadIdx.x; e < end; e += 256)
        atomicAdd(&h[dst[e] >> 8], 1);
    __syncthreads();
    for (int i = threadIdx.x; i < nB; i += 256) {
        int c = h[i];
        basearr[i] = c ? atomicAdd(&bcur[i], c) : 0;
        h[i] = 0;   // reuse as local cursor
    }
    __syncthreads();
    for (int e = base + threadIdx.x; e < end; e += 256) {
        int d = dst[e];
        int b = d >> 8;
        int pos = basearr[b] + atomicAdd(&h[b], 1);
        ebuf[pos] = make_uint2((unsigned)src[e], (unsigned)d);
    }
}

// per-bucket node-degree histogram from bucket-sorted ebuf (replaces global-atomic count)
__global__ __launch_bounds__(256) void node_count(const uint2* __restrict__ ebuf,
                                                  const int* __restrict__ boff,
                                                  int* __restrict__ cnt, int nE, int nB, int nN) {
    __shared__ int h[256];
    h[threadIdx.x] = 0;
    __syncthreads();
    const int b = blockIdx.x;
    const int e0 = boff[b];
    const int e1 = (b + 1 < nB) ? boff[b + 1] : nE;
    for (int e = e0 + threadIdx.x; e < e1; e += 256)
        atomicAdd(&h[ebuf[e].y & 255], 1);
    __syncthreads();
    const int v = b * 256 + threadIdx.x;
    if (v < nN) cnt[v] = h[threadIdx.x];
}

__global__ __launch_bounds__(256) void csr_from_buckets(const uint2* __restrict__ ebuf,
                                                        const int* __restrict__ boff,
                                                        const int* __restrict__ rowptr,
                                                        int* __restrict__ ssrc, int nE, int nB) {
    __shared__ int cur[256];
    const int b = blockIdx.x;
    const int e0 = boff[b];
    const int e1 = (b + 1 < nB) ? boff[b + 1] : nE;
    cur[threadIdx.x] = 0;
    __syncthreads();
    for (int e = e0 + threadIdx.x; e < e1; e += 256) {
        uint2 ed = ebuf[e];
        int d = (int)ed.y;
        int pos = rowptr[d] + atomicAdd(&cur[d & 255], 1);
        ssrc[pos] = (int)ed.x;
    }
}

// ---------------------------------------------------------------------------
// fp32 x -> bf16 Xb (row = 16 uint4 = 128 bf16)
__global__ __launch_bounds__(256) void xcvt_kernel(const float* __restrict__ x,
                                                   uint4* __restrict__ Xb, int total) {
    int i = blockIdx.x * 256 + threadIdx.x;   // one uint4 out = 8 floats in
    if (i < total) {
        const float4* xp = (const float4*)x + (size_t)i * 2;
        float4 u = xp[0], v = xp[1];
        uint4 o;
        o.x = f2bf(u.x) | (f2bf(u.y) << 16);
        o.y = f2bf(u.z) | (f2bf(u.w) << 16);
        o.z = f2bf(v.x) | (f2bf(v.y) << 16);
        o.w = f2bf(v.z) | (f2bf(v.w) << 16);
        Xb[i] = o;
    }
}

// transpose+convert 3 weight matrices: Wt[n][k] = bf16(W[k][n]); 3 x 128 x 128
__global__ __launch_bounds__(256) void wt_kernel(const float* __restrict__ W0,
                                                 const float* __restrict__ W1,
                                                 const float* __restrict__ W2,
                                                 unsigned short* __restrict__ Wtb) {
    int i = blockIdx.x * 256 + threadIdx.x;   // 0..49151
    if (i < 3 * HID * HID) {
        int w = i >> 14, r = i & 16383;
        int n = r >> 7, k = r & 127;
        const float* W = (w == 0) ? W0 : (w == 1) ? W1 : W2;
        Wtb[i] = (unsigned short)f2bf(W[k * HID + n]);
    }
}

// ---------------------------------------------------------------------------
// MFMA GEMM: Pb = bf16(dinv ⊙ (Xb @ W)), Xb/Wt bf16 in, fp32 accumulate.
__global__ __launch_bounds__(256) void gemm_mfma_kernel(const uint4* __restrict__ Xb,
                                                        const uint4* __restrict__ Wtb,
                                                        const float* __restrict__ dinv,
                                                        unsigned int* __restrict__ Pb32,
                                                        int nN) {
    __shared__ short Xs[GEMM_ROWS * XS_STRIDE];
    __shared__ short Ws[HID * XS_STRIDE];
    const int tid = threadIdx.x;
    const int rowBase = blockIdx.x * GEMM_ROWS;
#pragma unroll
    for (int it = 0; it < 8; ++it) {   // 2048 uint4 X-tile
        int f = it * 256 + tid;
        int row = f >> 4, c = f & 15;
        uint4 v = Xb[(size_t)(rowBase + row) * 16 + c];
        *(uint4*)(&Xs[row * XS_STRIDE + c * 8]) = v;
    }
#pragma unroll
    for (int it = 0; it < 8; ++it) {   // 2048 uint4 W-tile
        int f = it * 256 + tid;
        int n = f >> 4, c = f & 15;
        *(uint4*)(&Ws[n * XS_STRIDE + c * 8]) = Wtb[f];
    }
    __syncthreads();
    const int wave = tid >> 6, lane = tid & 63;
    const int quad = lane >> 4, l16 = lane & 15;
    f32x4 acc[2][8] = {};
    const int kq = quad * 8;
#pragma unroll
    for (int ks = 0; ks < 4; ++ks) {
        const int k0 = ks * 32 + kq;
        bf16x8 a0 = *(const bf16x8*)(&Xs[(wave * 32 + l16) * XS_STRIDE + k0]);
        bf16x8 a1 = *(const bf16x8*)(&Xs[(wave * 32 + 16 + l16) * XS_STRIDE + k0]);
#pragma unroll
        for (int nt = 0; nt < 8; ++nt) {
            bf16x8 b = *(const bf16x8*)(&Ws[(nt * 16 + l16) * XS_STRIDE + k0]);
            acc[0][nt] = __builtin_amdgcn_mfma_f32_16x16x32_bf16(a0, b, acc[0][nt], 0, 0, 0);
            acc[1][nt] = __builtin_amdgcn_mfma_f32_16x16x32_bf16(a1, b, acc[1][nt], 0, 0, 0);
        }
    }
#pragma unroll
    for (int mt = 0; mt < 2; ++mt) {
        const int gr0 = rowBase + wave * 32 + mt * 16 + quad * 4;
#pragma unroll
        for (int r = 0; r < 4; ++r) {
            const int gr = gr0 + r;
            const bool ok = gr < nN;
            const float d = ok ? dinv[gr] : 0.f;
#pragma unroll
            for (int nt = 0; nt < 8; ++nt) {
                float v = d * acc[mt][nt][r];
                float vo = __shfl_xor(v, 1, 64);
                if (ok && !(l16 & 1)) {
                    Pb32[(size_t)gr * 64 + nt * 8 + (l16 >> 1)] = f2bf(v) | (f2bf(vo) << 16);
                }
            }
        }
    }
}

// ---------------------------------------------------------------------------
// unpack 8 bf16 (uint4) and accumulate into 8 fp32
__device__ __forceinline__ void acc_bf8(const uint4 q, float* a) {
    union { uint32_t i; float f; } t;
    t.i = q.x << 16;          a[0] += t.f;
    t.i = q.x & 0xffff0000u;  a[1] += t.f;
    t.i = q.y << 16;          a[2] += t.f;
    t.i = q.y & 0xffff0000u;  a[3] += t.f;
    t.i = q.z << 16;          a[4] += t.f;
    t.i = q.z & 0xffff0000u;  a[5] += t.f;
    t.i = q.w << 16;          a[6] += t.f;
    t.i = q.w & 0xffff0000u;  a[7] += t.f;
}

// Xout[v] = relu(dinv[v]*(P[v] + sum_in P[src]) + b); 16 lanes/node; bf16 out.
__global__ __launch_bounds__(256) void agg_kernel(const uint4* __restrict__ Pb,
                                                  const int* __restrict__ rowptr,
                                                  const int* __restrict__ ssrc,
                                                  const float* __restrict__ dinv,
                                                  const float* __restrict__ bias,
                                                  uint4* __restrict__ Xb_out, int nN) {
    const int lane = threadIdx.x & 15;
    const int grp = threadIdx.x >> 4;
    const int v = blockIdx.x * 16 + grp;
    if (v >= nN) return;
    float a0[8], a1[8], a2[8], a3[8];
#pragma unroll
    for (int i = 0; i < 8; ++i) { a0[i] = 0.f; a1[i] = 0.f; a2[i] = 0.f; a3[i] = 0.f; }
    acc_bf8(Pb[(size_t)v * 16 + lane], a0);  // self loop
    int e = rowptr[v];
    const int e1 = rowptr[v + 1];
    for (; e + 4 <= e1; e += 4) {
        const int u0 = ssrc[e + 0], u1 = ssrc[e + 1], u2 = ssrc[e + 2], u3 = ssrc[e + 3];
        uint4 q0 = Pb[(size_t)u0 * 16 + lane];
        uint4 q1 = Pb[(size_t)u1 * 16 + lane];
        uint4 q2 = Pb[(size_t)u2 * 16 + lane];
        uint4 q3 = Pb[(size_t)u3 * 16 + lane];
        acc_bf8(q0, a0); acc_bf8(q1, a1); acc_bf8(q2, a2); acc_bf8(q3, a3);
    }
    for (; e < e1; ++e) {
        uint4 q = Pb[(size_t)ssrc[e] * 16 + lane];
        acc_bf8(q, a1);
    }
    const float dv = dinv[v];
    const float4 bb0 = ((const float4*)bias)[lane * 2];
    const float4 bb1 = ((const float4*)bias)[lane * 2 + 1];
    float4 o0, o1;
    o0.x = fmaxf(fmaf(dv, (a0[0] + a1[0]) + (a2[0] + a3[0]), bb0.x), 0.f);
    o0.y = fmaxf(fmaf(dv, (a0[1] + a1[1]) + (a2[1] + a3[1]), bb0.y), 0.f);
    o0.z = fmaxf(fmaf(dv, (a0[2] + a1[2]) + (a2[2] + a3[2]), bb0.z), 0.f);
    o0.w = fmaxf(fmaf(dv, (a0[3] + a1[3]) + (a2[3] + a3[3]), bb0.w), 0.f);
    o1.x = fmaxf(fmaf(dv, (a0[4] + a1[4]) + (a2[4] + a3[4]), bb1.x), 0.f);
    o1.y = fmaxf(fmaf(dv, (a0[5] + a1[5]) + (a2[5] + a3[5]), bb1.y), 0.f);
    o1.z = fmaxf(fmaf(dv, (a0[6] + a1[6]) + (a2[6] + a3[6]), bb1.z), 0.f);
    o1.w = fmaxf(fmaf(dv, (a0[7] + a1[7]) + (a2[7] + a3[7]), bb1.w), 0.f);
    uint4 q;
    q.x = f2bf(o0.x) | (f2bf(o0.y) << 16);
    q.y = f2bf(o0.z) | (f2bf(o0.w) << 16);
    q.z = f2bf(o1.x) | (f2bf(o1.y) << 16);
    q.w = f2bf(o1.z) | (f2bf(o1.w) << 16);
    Xb_out[(size_t)v * 16 + lane] = q;
}

// ---------------------------------------------------------------------------
// global mean pool over bf16 rows, phase 1: coalesced partial sums.
// thread t: uint index c2 = t&63 (cols 2*c2, 2*c2+1), rows (t>>6) step 4.
__global__ __launch_bounds__(256) void pool_partial(const unsigned int* __restrict__ Xb32,
                                                    const int* __restrict__ batch,
                                                    float* __restrict__ psum, int nN) {
    const int c2 = threadIdx.x & 63;
    int n = blockIdx.x * 64 + (threadIdx.x >> 6);
    const int nEnd = min(blockIdx.x * 64 + 64, nN);
    float acc0 = 0.f, acc1 = 0.f;
    int g = -1;
    for (; n < nEnd; n += 4) {
        int gn = batch[n];
        unsigned int q = Xb32[(size_t)n * 64 + c2];
        union { uint32_t i; float f; } lo, hi;
        lo.i = q << 16; hi.i = q & 0xffff0000u;
        if (gn != g) {
            if (g >= 0) {
                atomicAdd(&psum[g * HID + c2 * 2], acc0);
                atomicAdd(&psum[g * HID + c2 * 2 + 1], acc1);
            }
            g = gn;
            acc0 = lo.f; acc1 = hi.f;
        } else {
            acc0 += lo.f; acc1 += hi.f;
        }
    }
    if (g >= 0) {
        atomicAdd(&psum[g * HID + c2 * 2], acc0);
        atomicAdd(&psum[g * HID + c2 * 2 + 1], acc1);
    }
}

// phase 2: divide by per-graph count (binary search over sorted batch)
__global__ __launch_bounds__(128) void pool_finalize(const float* __restrict__ psum,
                                                     const int* __restrict__ batch,
                                                     float* __restrict__ pooled, int nN) {
    const int g = blockIdx.x;
    int lo = 0, hi = nN;
    while (lo < hi) { int m = (lo + hi) >> 1; if (batch[m] < g) lo = m + 1; else hi = m; }
    const int start = lo;
    hi = nN;
    while (lo < hi) { int m = (lo + hi) >> 1; if (batch[m] < g + 1) lo = m + 1; else hi = m; }
    const float c = (float)max(lo - start, 1);
    pooled[g * HID + threadIdx.x] = psum[g * HID + threadIdx.x] / c;
}

// ---------------------------------------------------------------------------
// single-step LSTM from zero state + FC(2); f-gate irrelevant (c0=0)
__device__ __forceinline__ float sigmoidf_(float x) { return 1.0f / (1.0f + expf(-x)); }

__global__ __launch_bounds__(128) void lstm_fc_kernel(const float* __restrict__ pooled,
                                                      const float* __restrict__ W_ih,
                                                      const float* __restrict__ b_ih,
                                                      const float* __restrict__ b_hh,
                                                      const float* __restrict__ W_fc,
                                                      const float* __restrict__ b_fc,
                                                      float* __restrict__ out) {
    __shared__ float pv[HID];
    __shared__ float r0[2], r1[2];
    const int g = blockIdx.x, j = threadIdx.x;
    pv[j] = pooled[g * HID + j];
    __syncthreads();
    float di = b_ih[j] + b_hh[j];
    float dg = b_ih[256 + j] + b_hh[256 + j];
    float dO = b_ih[384 + j] + b_hh[384 + j];
    const float4* pv4 = (const float4*)pv;
#pragma unroll 4
    for (int k4 = 0; k4 < 32; ++k4) {
        float4 p = pv4[k4];
        float4 wi = *(const float4*)(W_ih + (size_t)j * HID + k4 * 4);
        float4 wg = *(const float4*)(W_ih + (size_t)(256 + j) * HID + k4 * 4);
        float4 wo = *(const float4*)(W_ih + (size_t)(384 + j) * HID + k4 * 4);
        di += p.x * wi.x + p.y * wi.y + p.z * wi.z + p.w * wi.w;
        dg += p.x * wg.x + p.y * wg.y + p.z * wg.z + p.w * wg.w;
        dO += p.x * wo.x + p.y * wo.y + p.z * wo.z + p.w * wo.w;
    }
    float c = sigmoidf_(di) * tanhf(dg);
    float hn = sigmoidf_(dO) * tanhf(c);
    float p0 = hn * W_fc[j];
    float p1 = hn * W_fc[HID + j];
#pragma unroll
    for (int off = 32; off > 0; off >>= 1) {
        p0 += __shfl_down(p0, off, 64);
        p1 += __shfl_down(p1, off, 64);
    }
    const int w = j >> 6, l = j & 63;
    if (l == 0) { r0[w] = p0; r1[w] = p1; }
    __syncthreads();
    if (j == 0) {
        out[g * 2 + 0] = r0[0] + r0[1] + b_fc[0];
        out[g * 2 + 1] = r1[0] + r1[1] + b_fc[1];
    }
}

// ---------------------------------------------------------------------------
extern "C" void kernel_launch(void* const* d_in, const int* in_sizes, int n_in,
                              void* d_out, int out_size, void* d_ws, size_t ws_size,
                              hipStream_t stream) {
    const float* x      = (const float*)d_in[0];
    const int*   eidx   = (const int*)d_in[1];
    const int*   batch  = (const int*)d_in[2];
    const float* W0     = (const float*)d_in[4];
    const float* b0     = (const float*)d_in[5];
    const float* W1     = (const float*)d_in[6];
    const float* b1     = (const float*)d_in[7];
    const float* W2     = (const float*)d_in[8];
    const float* b2     = (const float*)d_in[9];
    const float* W_ih   = (const float*)d_in[10];
    const float* b_ih   = (const float*)d_in[12];
    const float* b_hh   = (const float*)d_in[13];
    const float* W_fc   = (const float*)d_in[14];
    const float* b_fc   = (const float*)d_in[15];
    float* out = (float*)d_out;

    const int nN = in_sizes[0] / HID;     // 100000
    const int nE = in_sizes[1] / 2;       // 1600000
    const int nG = out_size / 2;          // 256
    const int* src = eidx;
    const int* dst = eidx + nE;
    const int rowsPad = (nN + GEMM_ROWS - 1) & ~(GEMM_ROWS - 1);  // 100096

    // workspace layout
    size_t off = 0;
    auto alloc = [&](size_t bytes) -> void* {
        void* p = (char*)d_ws + off;
        off += (bytes + 255) & ~(size_t)255;
        return p;
    };
    uint4* Pb     = (uint4*)alloc((size_t)rowsPad * 16 * sizeof(uint4));  // bf16 P
    uint4* Xb     = (uint4*)alloc((size_t)nN * 16 * sizeof(uint4));       // bf16 activations
    float* dinv   = (float*)alloc((size_t)nN * sizeof(float));
    int*   cnt    = (int*)alloc((size_t)nN * sizeof(int));
    int*   rowptr = (int*)alloc((size_t)(nN + 1) * sizeof(int));
    int*   ssrc   = (int*)alloc((size_t)nE * sizeof(int));
    uint2* ebuf   = (uint2*)alloc((size_t)nE * sizeof(uint2));
    float* pooled = (float*)alloc((size_t)nG * HID * sizeof(float));
    float* psum   = (float*)alloc((size_t)nG * HID * sizeof(float));
    int*   blockSums = (int*)alloc(1024 * sizeof(int));
    int*   bcnt   = (int*)alloc(NBUCK_MAX * sizeof(int));
    int*   boff   = (int*)alloc(NBUCK_MAX * sizeof(int));
    int*   bcur   = (int*)alloc(NBUCK_MAX * sizeof(int));
    unsigned short* Wtb = (unsigned short*)alloc(3 * HID * HID * sizeof(unsigned short));
    (void)ws_size;

    const int scanBlocks = (nN + SCAN_CHUNK - 1) / SCAN_CHUNK;
    const int nB = (nN + 255) >> 8;
    const int tileBlocks = (nE + EDGE_TILE - 1) / EDGE_TILE;

    // multisplit: bucket-sort edges by dst bucket
    hipMemsetAsync(bcnt, 0, NBUCK_MAX * sizeof(int), stream);
    bucket_count<<<tileBlocks, 256, 0, stream>>>(dst, bcnt, nE, nB);
    bucket_scan<<<1, 512, 0, stream>>>(bcnt, boff, bcur, nB);
    bucket_scatter<<<tileBlocks, 256, 0, stream>>>(src, dst, bcur, ebuf, nE, nB);

    // degrees from buckets (LDS histogram, no global atomics) + dinv + rowptr
    node_count<<<nB, 256, 0, stream>>>(ebuf, boff, cnt, nE, nB, nN);
    scan_phase1<<<scanBlocks, 256, 0, stream>>>(cnt, blockSums, dinv, nN);
    scan_phase2<<<1, 256, 0, stream>>>(blockSums, scanBlocks);
    scan_phase3<<<scanBlocks, 256, 0, stream>>>(cnt, blockSums, rowptr, nN, nE);
    csr_from_buckets<<<nB, 256, 0, stream>>>(ebuf, boff, rowptr, ssrc, nE, nB);

    // bf16 conversions
    const int xTotal = nN * 16;  // uint4 units
    xcvt_kernel<<<(xTotal + 255) / 256, 256, 0, stream>>>(x, Xb, xTotal);
    wt_kernel<<<(3 * HID * HID + 255) / 256, 256, 0, stream>>>(W0, W1, W2, Wtb);

    const int gemmBlocks = rowsPad / GEMM_ROWS;
    const int aggBlocks = (nN + 15) / 16;
    const uint4* Wt0 = (const uint4*)Wtb;
    const uint4* Wt1 = (const uint4*)(Wtb + HID * HID);
    const uint4* Wt2 = (const uint4*)(Wtb + 2 * HID * HID);

    // layer 0
    gemm_mfma_kernel<<<gemmBlocks, 256, 0, stream>>>(Xb, Wt0, dinv, (unsigned int*)Pb, nN);
    agg_kernel<<<aggBlocks, 256, 0, stream>>>(Pb, rowptr, ssrc, dinv, b0, Xb, nN);
    // layer 1
    gemm_mfma_kernel<<<gemmBlocks, 256, 0, stream>>>(Xb, Wt1, dinv, (unsigned int*)Pb, nN);
    agg_kernel<<<aggBlocks, 256, 0, stream>>>(Pb, rowptr, ssrc, dinv, b1, Xb, nN);
    // layer 2
    gemm_mfma_kernel<<<gemmBlocks, 256, 0, stream>>>(Xb, Wt2, dinv, (unsigned int*)Pb, nN);
    agg_kernel<<<aggBlocks, 256, 0, stream>>>(Pb, rowptr, ssrc, dinv, b2, Xb, nN);

    // pool + LSTM + FC
    hipMemsetAsync(psum, 0, (size_t)nG * HID * sizeof(float), stream);
    pool_partial<<<(nN + 63) / 64, 256, 0, stream>>>((const unsigned int*)Xb, batch, psum, nN);
    pool_finalize<<<nG, 128, 0, stream>>>(psum, batch, pooled, nN);
    lstm_fc_kernel<<<nG, 128, 0, stream>>>(pooled, W_ih, b_ih, b_hh, W_fc, b_fc, out);
}

// Round 8
// 478.555 us; speedup vs baseline: 2.3964x; 1.0036x over previous
//
#include <hip/hip_runtime.h>
#include <math.h>
#include <stdint.h>

#define HID 128
#define SCAN_CHUNK 1024   // elements per scan block (256 thr x 4)
#define NBUCK_MAX 512     // node buckets of 256 nodes each (nN<=131072)
#define EDGE_TILE 8192    // edges per block in bucket passes
#define GEMM_ROWS 128     // M-tile per block
#define XS_STRIDE 136     // bf16 elems per LDS row (128 + 8 pad -> 2-way max bank alias)

typedef short bf16x8 __attribute__((ext_vector_type(8)));
typedef float f32x4 __attribute__((ext_vector_type(4)));

// ---------------------------------------------------------------------------
// round-to-nearest-even fp32 -> bf16 bits
__device__ __forceinline__ unsigned int f2bf(float f) {
    union { float f; uint32_t i; } u; u.f = f;
    uint32_t r = u.i + 0x7fffu + ((u.i >> 16) & 1u);
    return r >> 16;
}

// ---------------------------------------------------------------------------
// Hierarchical scan, phase 1: per-block sums of cnt (1024 elems/block) + fused dinv
__global__ __launch_bounds__(256) void scan_phase1(const int* __restrict__ cnt,
                                                   int* __restrict__ blockSums,
                                                   float* __restrict__ dinv, int nN) {
    __shared__ int sdata[256];
    const int t = threadIdx.x;
    const int idx = blockIdx.x * SCAN_CHUNK + t * 4;
    int v0 = 0, v1 = 0, v2 = 0, v3 = 0;
    if (idx + 3 < nN) {
        int4 v = *(const int4*)(cnt + idx);
        v0 = v.x; v1 = v.y; v2 = v.z; v3 = v.w;
        float4 dv;
        dv.x = rsqrtf((float)v0 + 1.0f);
        dv.y = rsqrtf((float)v1 + 1.0f);
        dv.z = rsqrtf((float)v2 + 1.0f);
        dv.w = rsqrtf((float)v3 + 1.0f);
        *(float4*)(dinv + idx) = dv;
    } else {
        if (idx     < nN) { v0 = cnt[idx];     dinv[idx]     = rsqrtf((float)v0 + 1.0f); }
        if (idx + 1 < nN) { v1 = cnt[idx + 1]; dinv[idx + 1] = rsqrtf((float)v1 + 1.0f); }
        if (idx + 2 < nN) { v2 = cnt[idx + 2]; dinv[idx + 2] = rsqrtf((float)v2 + 1.0f); }
        if (idx + 3 < nN) { v3 = cnt[idx + 3]; dinv[idx + 3] = rsqrtf((float)v3 + 1.0f); }
    }
    sdata[t] = v0 + v1 + v2 + v3;
    __syncthreads();
#pragma unroll
    for (int off = 128; off > 0; off >>= 1) {
        if (t < off) sdata[t] += sdata[t + off];
        __syncthreads();
    }
    if (t == 0) blockSums[blockIdx.x] = sdata[0];
}

// phase 2: single small block converts blockSums -> exclusive offsets (nB <= 256)
__global__ __launch_bounds__(256) void scan_phase2(int* __restrict__ blockSums, int nB) {
    __shared__ int sd[256];
    const int t = threadIdx.x;
    sd[t] = (t < nB) ? blockSums[t] : 0;
    __syncthreads();
#pragma unroll
    for (int off = 1; off < 256; off <<= 1) {
        int v = sd[t];
        int add = (t >= off) ? sd[t - off] : 0;
        __syncthreads();
        sd[t] = v + add;
        __syncthreads();
    }
    if (t < nB) blockSums[t] = (t > 0) ? sd[t - 1] : 0;  // exclusive
}

// phase 3: per-block exclusive scan + global offset -> rowptr
__global__ __launch_bounds__(256) void scan_phase3(const int* __restrict__ cnt,
                                                   const int* __restrict__ blockOffsets,
                                                   int* __restrict__ rowptr, int nN, int nE) {
    __shared__ int sdata[256];
    const int t = threadIdx.x;
    const int idx = blockIdx.x * SCAN_CHUNK + t * 4;
    int v0 = 0, v1 = 0, v2 = 0, v3 = 0;
    if (idx + 3 < nN) {
        int4 v = *(const int4*)(cnt + idx);
        v0 = v.x; v1 = v.y; v2 = v.z; v3 = v.w;
    } else {
        if (idx     < nN) v0 = cnt[idx];
        if (idx + 1 < nN) v1 = cnt[idx + 1];
        if (idx + 2 < nN) v2 = cnt[idx + 2];
        if (idx + 3 < nN) v3 = cnt[idx + 3];
    }
    sdata[t] = v0 + v1 + v2 + v3;
    __syncthreads();
#pragma unroll
    for (int off = 1; off < 256; off <<= 1) {
        int v = sdata[t];
        int add = (t >= off) ? sdata[t - off] : 0;
        __syncthreads();
        sdata[t] = v + add;
        __syncthreads();
    }
    const int pre = blockOffsets[blockIdx.x] + ((t > 0) ? sdata[t - 1] : 0);
    if (idx + 3 < nN) {
        *(int4*)(rowptr + idx) = make_int4(pre, pre + v0, pre + v0 + v1, pre + v0 + v1 + v2);
    } else {
        if (idx     < nN) rowptr[idx]     = pre;
        if (idx + 1 < nN) rowptr[idx + 1] = pre + v0;
        if (idx + 2 < nN) rowptr[idx + 2] = pre + v0 + v1;
        if (idx + 3 < nN) rowptr[idx + 3] = pre + v0 + v1 + v2;
    }
    if (blockIdx.x == 0 && t == 0) rowptr[nN] = nE;
}

// ---------------------------------------------------------------------------
// Multisplit CSR build. Bucket = dst >> 8 (256 nodes/bucket).
__global__ __launch_bounds__(256) void bucket_count(const int* __restrict__ dst,
                                                    int* __restrict__ bcnt, int nE, int nB) {
    __shared__ int h[NBUCK_MAX];
    for (int i = threadIdx.x; i < nB; i += 256) h[i] = 0;
    __syncthreads();
    const int base = blockIdx.x * EDGE_TILE;
    const int end = min(base + EDGE_TILE, nE);
    for (int e = base + threadIdx.x; e < end; e += 256)
        atomicAdd(&h[dst[e] >> 8], 1);
    __syncthreads();
    for (int i = threadIdx.x; i < nB; i += 256)
        if (h[i]) atomicAdd(&bcnt[i], h[i]);
}

__global__ __launch_bounds__(512) void bucket_scan(const int* __restrict__ bcnt,
                                                   int* __restrict__ boff,
                                                   int* __restrict__ bcur, int nB) {
    __shared__ int sd[512];
    const int t = threadIdx.x;
    sd[t] = (t < nB) ? bcnt[t] : 0;
    __syncthreads();
#pragma unroll
    for (int off = 1; off < 512; off <<= 1) {
        int v = sd[t];
        int add = (t >= off) ? sd[t - off] : 0;
        __syncthreads();
        sd[t] = v + add;
        __syncthreads();
    }
    if (t < nB) {
        int ex = (t > 0) ? sd[t - 1] : 0;
        boff[t] = ex;
        bcur[t] = ex;
    }
}

__global__ __launch_bounds__(256) void bucket_scatter(const int* __restrict__ src,
                                                      const int* __restrict__ dst,
                                                      int* __restrict__ bcur,
                                                      uint2* __restrict__ ebuf, int nE, int nB) {
    __shared__ int h[NBUCK_MAX];
    __shared__ int basearr[NBUCK_MAX];
    const int base = blockIdx.x * EDGE_TILE;
    const int end = min(base + EDGE_TILE, nE);
    for (int i = threadIdx.x; i < nB; i += 256) h[i] = 0;
    __syncthreads();
    for (int e = base + threadIdx.x; e < end; e += 256)
        atomicAdd(&h[dst[e] >> 8], 1);
    __syncthreads();
    for (int i = threadIdx.x; i < nB; i += 256) {
        int c = h[i];
        basearr[i] = c ? atomicAdd(&bcur[i], c) : 0;
        h[i] = 0;   // reuse as local cursor
    }
    __syncthreads();
    for (int e = base + threadIdx.x; e < end; e += 256) {
        int d = dst[e];
        int b = d >> 8;
        int pos = basearr[b] + atomicAdd(&h[b], 1);
        ebuf[pos] = make_uint2((unsigned)src[e], (unsigned)d);
    }
}

// per-bucket node-degree histogram from bucket-sorted ebuf (no global atomics)
__global__ __launch_bounds__(256) void node_count(const uint2* __restrict__ ebuf,
                                                  const int* __restrict__ boff,
                                                  int* __restrict__ cnt, int nE, int nB, int nN) {
    __shared__ int h[256];
    h[threadIdx.x] = 0;
    __syncthreads();
    const int b = blockIdx.x;
    const int e0 = boff[b];
    const int e1 = (b + 1 < nB) ? boff[b + 1] : nE;
    for (int e = e0 + threadIdx.x; e < e1; e += 256)
        atomicAdd(&h[ebuf[e].y & 255], 1);
    __syncthreads();
    const int v = b * 256 + threadIdx.x;
    if (v < nN) cnt[v] = h[threadIdx.x];
}

// Final CSR scatter with per-row src-half partition: row edges are
// [rowptr[v], rowmid[v]) src<nHalf, [rowmid[v], rowptr[v+1]) src>=nHalf.
__global__ __launch_bounds__(256) void csr_from_buckets(const uint2* __restrict__ ebuf,
                                                        const int* __restrict__ boff,
                                                        const int* __restrict__ rowptr,
                                                        int* __restrict__ rowmid,
                                                        int* __restrict__ ssrc,
                                                        int nE, int nB, int nN, int nHalf) {
    __shared__ int rbase[256];  // rowptr cache
    __shared__ int rmid[256];   // rowmid (LDS authoritative copy)
    __shared__ int cLow[256], cHigh[256];
    const int t = threadIdx.x;
    const int b = blockIdx.x;
    const int e0 = boff[b];
    const int e1 = (b + 1 < nB) ? boff[b + 1] : nE;
    const int v = b * 256 + t;
    rbase[t] = (v <= nN) ? rowptr[v] : 0;
    cLow[t] = 0;
    __syncthreads();
    // pass 1: count low-src edges per node
    for (int e = e0 + t; e < e1; e += 256) {
        uint2 ed = ebuf[e];
        if ((int)ed.x < nHalf) atomicAdd(&cLow[ed.y & 255], 1);
    }
    __syncthreads();
    rmid[t] = rbase[t] + cLow[t];
    if (v < nN) rowmid[v] = rmid[t];
    cLow[t] = 0;
    cHigh[t] = 0;
    __syncthreads();
    // pass 2: scatter into the two partitions
    for (int e = e0 + t; e < e1; e += 256) {
        uint2 ed = ebuf[e];
        int li = (int)ed.y & 255;
        int u = (int)ed.x;
        int pos;
        if (u < nHalf) pos = rbase[li] + atomicAdd(&cLow[li], 1);
        else           pos = rmid[li] + atomicAdd(&cHigh[li], 1);
        ssrc[pos] = u;
    }
}

// ---------------------------------------------------------------------------
// transpose+convert 3 weight matrices: Wt[n][k] = bf16(W[k][n]); 3 x 128 x 128
__global__ __launch_bounds__(256) void wt_kernel(const float* __restrict__ W0,
                                                 const float* __restrict__ W1,
                                                 const float* __restrict__ W2,
                                                 unsigned short* __restrict__ Wtb) {
    int i = blockIdx.x * 256 + threadIdx.x;   // 0..49151
    if (i < 3 * HID * HID) {
        int w = i >> 14, r = i & 16383;
        int n = r >> 7, k = r & 127;
        const float* W = (w == 0) ? W0 : (w == 1) ? W1 : W2;
        Wtb[i] = (unsigned short)f2bf(W[k * HID + n]);
    }
}

// ---------------------------------------------------------------------------
// MFMA GEMM (bf16 input): Pb = bf16(dinv ⊙ (Xb @ W)), fp32 accumulate.
__global__ __launch_bounds__(256) void gemm_mfma_kernel(const uint4* __restrict__ Xb,
                                                        const uint4* __restrict__ Wtb,
                                                        const float* __restrict__ dinv,
                                                        unsigned int* __restrict__ Pb32,
                                                        int nN) {
    __shared__ short Xs[GEMM_ROWS * XS_STRIDE];
    __shared__ short Ws[HID * XS_STRIDE];
    const int tid = threadIdx.x;
    const int rowBase = blockIdx.x * GEMM_ROWS;
#pragma unroll
    for (int it = 0; it < 8; ++it) {   // 2048 uint4 X-tile
        int f = it * 256 + tid;
        int row = f >> 4, c = f & 15;
        int grow = rowBase + row;
        uint4 v = make_uint4(0u, 0u, 0u, 0u);
        if (grow < nN) v = Xb[(size_t)grow * 16 + c];
        *(uint4*)(&Xs[row * XS_STRIDE + c * 8]) = v;
    }
#pragma unroll
    for (int it = 0; it < 8; ++it) {   // 2048 uint4 W-tile
        int f = it * 256 + tid;
        int n = f >> 4, c = f & 15;
        *(uint4*)(&Ws[n * XS_STRIDE + c * 8]) = Wtb[f];
    }
    __syncthreads();
    const int wave = tid >> 6, lane = tid & 63;
    const int quad = lane >> 4, l16 = lane & 15;
    f32x4 acc[2][8] = {};
    const int kq = quad * 8;
#pragma unroll
    for (int ks = 0; ks < 4; ++ks) {
        const int k0 = ks * 32 + kq;
        bf16x8 a0 = *(const bf16x8*)(&Xs[(wave * 32 + l16) * XS_STRIDE + k0]);
        bf16x8 a1 = *(const bf16x8*)(&Xs[(wave * 32 + 16 + l16) * XS_STRIDE + k0]);
#pragma unroll
        for (int nt = 0; nt < 8; ++nt) {
            bf16x8 b = *(const bf16x8*)(&Ws[(nt * 16 + l16) * XS_STRIDE + k0]);
            acc[0][nt] = __builtin_amdgcn_mfma_f32_16x16x32_bf16(a0, b, acc[0][nt], 0, 0, 0);
            acc[1][nt] = __builtin_amdgcn_mfma_f32_16x16x32_bf16(a1, b, acc[1][nt], 0, 0, 0);
        }
    }
#pragma unroll
    for (int mt = 0; mt < 2; ++mt) {
        const int gr0 = rowBase + wave * 32 + mt * 16 + quad * 4;
#pragma unroll
        for (int r = 0; r < 4; ++r) {
            const int gr = gr0 + r;
            const bool ok = gr < nN;
            const float d = ok ? dinv[gr] : 0.f;
#pragma unroll
            for (int nt = 0; nt < 8; ++nt) {
                float v = d * acc[mt][nt][r];
                float vo = __shfl_xor(v, 1, 64);
                if (ok && !(l16 & 1)) {
                    Pb32[(size_t)gr * 64 + nt * 8 + (l16 >> 1)] = f2bf(v) | (f2bf(vo) << 16);
                }
            }
        }
    }
}

// MFMA GEMM variant with fused fp32->bf16 input conversion (layer 0).
__global__ __launch_bounds__(256) void gemm_mfma_f32in(const float* __restrict__ X,
                                                       const uint4* __restrict__ Wtb,
                                                       const float* __restrict__ dinv,
                                                       unsigned int* __restrict__ Pb32,
                                                       int nN) {
    __shared__ short Xs[GEMM_ROWS * XS_STRIDE];
    __shared__ short Ws[HID * XS_STRIDE];
    const int tid = threadIdx.x;
    const int rowBase = blockIdx.x * GEMM_ROWS;
#pragma unroll
    for (int it = 0; it < 16; ++it) {  // 4096 float4 X-tile, convert to bf16
        int f = it * 256 + tid;
        int row = f >> 5, c = f & 31;
        int grow = rowBase + row;
        float4 v = make_float4(0.f, 0.f, 0.f, 0.f);
        if (grow < nN) v = *(const float4*)(X + (size_t)grow * HID + c * 4);
        uint2 o;
        o.x = f2bf(v.x) | (f2bf(v.y) << 16);
        o.y = f2bf(v.z) | (f2bf(v.w) << 16);
        *(uint2*)(&Xs[row * XS_STRIDE + c * 4]) = o;
    }
#pragma unroll
    for (int it = 0; it < 8; ++it) {   // 2048 uint4 W-tile
        int f = it * 256 + tid;
        int n = f >> 4, c = f & 15;
        *(uint4*)(&Ws[n * XS_STRIDE + c * 8]) = Wtb[f];
    }
    __syncthreads();
    const int wave = tid >> 6, lane = tid & 63;
    const int quad = lane >> 4, l16 = lane & 15;
    f32x4 acc[2][8] = {};
    const int kq = quad * 8;
#pragma unroll
    for (int ks = 0; ks < 4; ++ks) {
        const int k0 = ks * 32 + kq;
        bf16x8 a0 = *(const bf16x8*)(&Xs[(wave * 32 + l16) * XS_STRIDE + k0]);
        bf16x8 a1 = *(const bf16x8*)(&Xs[(wave * 32 + 16 + l16) * XS_STRIDE + k0]);
#pragma unroll
        for (int nt = 0; nt < 8; ++nt) {
            bf16x8 b = *(const bf16x8*)(&Ws[(nt * 16 + l16) * XS_STRIDE + k0]);
            acc[0][nt] = __builtin_amdgcn_mfma_f32_16x16x32_bf16(a0, b, acc[0][nt], 0, 0, 0);
            acc[1][nt] = __builtin_amdgcn_mfma_f32_16x16x32_bf16(a1, b, acc[1][nt], 0, 0, 0);
        }
    }
#pragma unroll
    for (int mt = 0; mt < 2; ++mt) {
        const int gr0 = rowBase + wave * 32 + mt * 16 + quad * 4;
#pragma unroll
        for (int r = 0; r < 4; ++r) {
            const int gr = gr0 + r;
            const bool ok = gr < nN;
            const float d = ok ? dinv[gr] : 0.f;
#pragma unroll
            for (int nt = 0; nt < 8; ++nt) {
                float v = d * acc[mt][nt][r];
                float vo = __shfl_xor(v, 1, 64);
                if (ok && !(l16 & 1)) {
                    Pb32[(size_t)gr * 64 + nt * 8 + (l16 >> 1)] = f2bf(v) | (f2bf(vo) << 16);
                }
            }
        }
    }
}

// ---------------------------------------------------------------------------
// unpack 8 bf16 (uint4) and accumulate into 8 fp32
__device__ __forceinline__ void acc_bf8(const uint4 q, float* a) {
    union { uint32_t i; float f; } t;
    t.i = q.x << 16;          a[0] += t.f;
    t.i = q.x & 0xffff0000u;  a[1] += t.f;
    t.i = q.y << 16;          a[2] += t.f;
    t.i = q.y & 0xffff0000u;  a[3] += t.f;
    t.i = q.z << 16;          a[4] += t.f;
    t.i = q.z & 0xffff0000u;  a[5] += t.f;
    t.i = q.w << 16;          a[6] += t.f;
    t.i = q.w & 0xffff0000u;  a[7] += t.f;
}

// Xout[v] = relu(dinv[v]*(P[v] + sum_in P[src]) + b); 16 lanes/node; bf16 out.
// Two src-half phases (via rowmid) shrink the concurrent gather working set.
__global__ __launch_bounds__(256) void agg_kernel(const uint4* __restrict__ Pb,
                                                  const int* __restrict__ rowptr,
                                                  const int* __restrict__ rowmid,
                                                  const int* __restrict__ ssrc,
                                                  const float* __restrict__ dinv,
                                                  const float* __restrict__ bias,
                                                  uint4* __restrict__ Xb_out, int nN) {
    const int lane = threadIdx.x & 15;
    const int grp = threadIdx.x >> 4;
    const int v = blockIdx.x * 16 + grp;
    if (v >= nN) return;
    float a0[8], a1[8], a2[8], a3[8];
#pragma unroll
    for (int i = 0; i < 8; ++i) { a0[i] = 0.f; a1[i] = 0.f; a2[i] = 0.f; a3[i] = 0.f; }
    acc_bf8(Pb[(size_t)v * 16 + lane], a0);  // self loop
    const int ee0 = rowptr[v], em = rowmid[v], ee1 = rowptr[v + 1];
#pragma unroll 1
    for (int ph = 0; ph < 2; ++ph) {
        int e = ph ? em : ee0;
        const int eE = ph ? ee1 : em;
        for (; e + 4 <= eE; e += 4) {
            const int u0 = ssrc[e + 0], u1 = ssrc[e + 1], u2 = ssrc[e + 2], u3 = ssrc[e + 3];
            uint4 q0 = Pb[(size_t)u0 * 16 + lane];
            uint4 q1 = Pb[(size_t)u1 * 16 + lane];
            uint4 q2 = Pb[(size_t)u2 * 16 + lane];
            uint4 q3 = Pb[(size_t)u3 * 16 + lane];
            acc_bf8(q0, a0); acc_bf8(q1, a1); acc_bf8(q2, a2); acc_bf8(q3, a3);
        }
        for (; e < eE; ++e) {
            uint4 q = Pb[(size_t)ssrc[e] * 16 + lane];
            acc_bf8(q, a1);
        }
    }
    const float dv = dinv[v];
    const float4 bb0 = ((const float4*)bias)[lane * 2];
    const float4 bb1 = ((const float4*)bias)[lane * 2 + 1];
    float4 o0, o1;
    o0.x = fmaxf(fmaf(dv, (a0[0] + a1[0]) + (a2[0] + a3[0]), bb0.x), 0.f);
    o0.y = fmaxf(fmaf(dv, (a0[1] + a1[1]) + (a2[1] + a3[1]), bb0.y), 0.f);
    o0.z = fmaxf(fmaf(dv, (a0[2] + a1[2]) + (a2[2] + a3[2]), bb0.z), 0.f);
    o0.w = fmaxf(fmaf(dv, (a0[3] + a1[3]) + (a2[3] + a3[3]), bb0.w), 0.f);
    o1.x = fmaxf(fmaf(dv, (a0[4] + a1[4]) + (a2[4] + a3[4]), bb1.x), 0.f);
    o1.y = fmaxf(fmaf(dv, (a0[5] + a1[5]) + (a2[5] + a3[5]), bb1.y), 0.f);
    o1.z = fmaxf(fmaf(dv, (a0[6] + a1[6]) + (a2[6] + a3[6]), bb1.z), 0.f);
    o1.w = fmaxf(fmaf(dv, (a0[7] + a1[7]) + (a2[7] + a3[7]), bb1.w), 0.f);
    uint4 q;
    q.x = f2bf(o0.x) | (f2bf(o0.y) << 16);
    q.y = f2bf(o0.z) | (f2bf(o0.w) << 16);
    q.z = f2bf(o1.x) | (f2bf(o1.y) << 16);
    q.w = f2bf(o1.z) | (f2bf(o1.w) << 16);
    Xb_out[(size_t)v * 16 + lane] = q;
}

// ---------------------------------------------------------------------------
// global mean pool over bf16 rows, phase 1: coalesced partial sums.
__global__ __launch_bounds__(256) void pool_partial(const unsigned int* __restrict__ Xb32,
                                                    const int* __restrict__ batch,
                                                    float* __restrict__ psum, int nN) {
    const int c2 = threadIdx.x & 63;
    int n = blockIdx.x * 64 + (threadIdx.x >> 6);
    const int nEnd = min(blockIdx.x * 64 + 64, nN);
    float acc0 = 0.f, acc1 = 0.f;
    int g = -1;
    for (; n < nEnd; n += 4) {
        int gn = batch[n];
        unsigned int q = Xb32[(size_t)n * 64 + c2];
        union { uint32_t i; float f; } lo, hi;
        lo.i = q << 16; hi.i = q & 0xffff0000u;
        if (gn != g) {
            if (g >= 0) {
                atomicAdd(&psum[g * HID + c2 * 2], acc0);
                atomicAdd(&psum[g * HID + c2 * 2 + 1], acc1);
            }
            g = gn;
            acc0 = lo.f; acc1 = hi.f;
        } else {
            acc0 += lo.f; acc1 += hi.f;
        }
    }
    if (g >= 0) {
        atomicAdd(&psum[g * HID + c2 * 2], acc0);
        atomicAdd(&psum[g * HID + c2 * 2 + 1], acc1);
    }
}

// phase 2: divide by per-graph count (binary search over sorted batch)
__global__ __launch_bounds__(128) void pool_finalize(const float* __restrict__ psum,
                                                     const int* __restrict__ batch,
                                                     float* __restrict__ pooled, int nN) {
    const int g = blockIdx.x;
    int lo = 0, hi = nN;
    while (lo < hi) { int m = (lo + hi) >> 1; if (batch[m] < g) lo = m + 1; else hi = m; }
    const int start = lo;
    hi = nN;
    while (lo < hi) { int m = (lo + hi) >> 1; if (batch[m] < g + 1) lo = m + 1; else hi = m; }
    const float c = (float)max(lo - start, 1);
    pooled[g * HID + threadIdx.x] = psum[g * HID + threadIdx.x] / c;
}

// ---------------------------------------------------------------------------
// single-step LSTM from zero state + FC(2); f-gate irrelevant (c0=0)
__device__ __forceinline__ float sigmoidf_(float x) { return 1.0f / (1.0f + expf(-x)); }

__global__ __launch_bounds__(128) void lstm_fc_kernel(const float* __restrict__ pooled,
                                                      const float* __restrict__ W_ih,
                                                      const float* __restrict__ b_ih,
                                                      const float* __restrict__ b_hh,
                                                      const float* __restrict__ W_fc,
                                                      const float* __restrict__ b_fc,
                                                      float* __restrict__ out) {
    __shared__ float pv[HID];
    __shared__ float r0[2], r1[2];
    const int g = blockIdx.x, j = threadIdx.x;
    pv[j] = pooled[g * HID + j];
    __syncthreads();
    float di = b_ih[j] + b_hh[j];
    float dg = b_ih[256 + j] + b_hh[256 + j];
    float dO = b_ih[384 + j] + b_hh[384 + j];
    const float4* pv4 = (const float4*)pv;
#pragma unroll 4
    for (int k4 = 0; k4 < 32; ++k4) {
        float4 p = pv4[k4];
        float4 wi = *(const float4*)(W_ih + (size_t)j * HID + k4 * 4);
        float4 wg = *(const float4*)(W_ih + (size_t)(256 + j) * HID + k4 * 4);
        float4 wo = *(const float4*)(W_ih + (size_t)(384 + j) * HID + k4 * 4);
        di += p.x * wi.x + p.y * wi.y + p.z * wi.z + p.w * wi.w;
        dg += p.x * wg.x + p.y * wg.y + p.z * wg.z + p.w * wg.w;
        dO += p.x * wo.x + p.y * wo.y + p.z * wo.z + p.w * wo.w;
    }
    float c = sigmoidf_(di) * tanhf(dg);
    float hn = sigmoidf_(dO) * tanhf(c);
    float p0 = hn * W_fc[j];
    float p1 = hn * W_fc[HID + j];
#pragma unroll
    for (int off = 32; off > 0; off >>= 1) {
        p0 += __shfl_down(p0, off, 64);
        p1 += __shfl_down(p1, off, 64);
    }
    const int w = j >> 6, l = j & 63;
    if (l == 0) { r0[w] = p0; r1[w] = p1; }
    __syncthreads();
    if (j == 0) {
        out[g * 2 + 0] = r0[0] + r0[1] + b_fc[0];
        out[g * 2 + 1] = r1[0] + r1[1] + b_fc[1];
    }
}

// ---------------------------------------------------------------------------
extern "C" void kernel_launch(void* const* d_in, const int* in_sizes, int n_in,
                              void* d_out, int out_size, void* d_ws, size_t ws_size,
                              hipStream_t stream) {
    const float* x      = (const float*)d_in[0];
    const int*   eidx   = (const int*)d_in[1];
    const int*   batch  = (const int*)d_in[2];
    const float* W0     = (const float*)d_in[4];
    const float* b0     = (const float*)d_in[5];
    const float* W1     = (const float*)d_in[6];
    const float* b1     = (const float*)d_in[7];
    const float* W2     = (const float*)d_in[8];
    const float* b2     = (const float*)d_in[9];
    const float* W_ih   = (const float*)d_in[10];
    const float* b_ih   = (const float*)d_in[12];
    const float* b_hh   = (const float*)d_in[13];
    const float* W_fc   = (const float*)d_in[14];
    const float* b_fc   = (const float*)d_in[15];
    float* out = (float*)d_out;

    const int nN = in_sizes[0] / HID;     // 100000
    const int nE = in_sizes[1] / 2;       // 1600000
    const int nG = out_size / 2;          // 256
    const int* src = eidx;
    const int* dst = eidx + nE;
    const int rowsPad = (nN + GEMM_ROWS - 1) & ~(GEMM_ROWS - 1);  // 100096
    const int nHalf = nN >> 1;

    // workspace layout
    size_t off = 0;
    auto alloc = [&](size_t bytes) -> void* {
        void* p = (char*)d_ws + off;
        off += (bytes + 255) & ~(size_t)255;
        return p;
    };
    uint4* Pb     = (uint4*)alloc((size_t)rowsPad * 16 * sizeof(uint4));  // bf16 P
    uint4* Xb     = (uint4*)alloc((size_t)nN * 16 * sizeof(uint4));       // bf16 activations
    float* dinv   = (float*)alloc((size_t)nN * sizeof(float));
    int*   cnt    = (int*)alloc((size_t)nN * sizeof(int));
    int*   rowptr = (int*)alloc((size_t)(nN + 1) * sizeof(int));
    int*   rowmid = (int*)alloc((size_t)nN * sizeof(int));
    int*   ssrc   = (int*)alloc((size_t)nE * sizeof(int));
    uint2* ebuf   = (uint2*)alloc((size_t)nE * sizeof(uint2));
    float* pooled = (float*)alloc((size_t)nG * HID * sizeof(float));
    float* psum   = (float*)alloc((size_t)nG * HID * sizeof(float));
    int*   blockSums = (int*)alloc(1024 * sizeof(int));
    int*   bcnt   = (int*)alloc(NBUCK_MAX * sizeof(int));
    int*   boff   = (int*)alloc(NBUCK_MAX * sizeof(int));
    int*   bcur   = (int*)alloc(NBUCK_MAX * sizeof(int));
    unsigned short* Wtb = (unsigned short*)alloc(3 * HID * HID * sizeof(unsigned short));
    (void)ws_size;

    const int scanBlocks = (nN + SCAN_CHUNK - 1) / SCAN_CHUNK;
    const int nB = (nN + 255) >> 8;
    const int tileBlocks = (nE + EDGE_TILE - 1) / EDGE_TILE;

    // multisplit: bucket-sort edges by dst bucket
    hipMemsetAsync(bcnt, 0, NBUCK_MAX * sizeof(int), stream);
    bucket_count<<<tileBlocks, 256, 0, stream>>>(dst, bcnt, nE, nB);
    bucket_scan<<<1, 512, 0, stream>>>(bcnt, boff, bcur, nB);
    bucket_scatter<<<tileBlocks, 256, 0, stream>>>(src, dst, bcur, ebuf, nE, nB);

    // degrees from buckets + dinv + rowptr + partitioned CSR
    node_count<<<nB, 256, 0, stream>>>(ebuf, boff, cnt, nE, nB, nN);
    scan_phase1<<<scanBlocks, 256, 0, stream>>>(cnt, blockSums, dinv, nN);
    scan_phase2<<<1, 256, 0, stream>>>(blockSums, scanBlocks);
    scan_phase3<<<scanBlocks, 256, 0, stream>>>(cnt, blockSums, rowptr, nN, nE);
    csr_from_buckets<<<nB, 256, 0, stream>>>(ebuf, boff, rowptr, rowmid, ssrc, nE, nB, nN, nHalf);

    // weights -> bf16 transposed
    wt_kernel<<<(3 * HID * HID + 255) / 256, 256, 0, stream>>>(W0, W1, W2, Wtb);

    const int gemmBlocks = rowsPad / GEMM_ROWS;
    const int aggBlocks = (nN + 15) / 16;
    const uint4* Wt0 = (const uint4*)Wtb;
    const uint4* Wt1 = (const uint4*)(Wtb + HID * HID);
    const uint4* Wt2 = (const uint4*)(Wtb + 2 * HID * HID);

    // layer 0 (fused fp32->bf16 input conversion)
    gemm_mfma_f32in<<<gemmBlocks, 256, 0, stream>>>(x, Wt0, dinv, (unsigned int*)Pb, nN);
    agg_kernel<<<aggBlocks, 256, 0, stream>>>(Pb, rowptr, rowmid, ssrc, dinv, b0, Xb, nN);
    // layer 1
    gemm_mfma_kernel<<<gemmBlocks, 256, 0, stream>>>(Xb, Wt1, dinv, (unsigned int*)Pb, nN);
    agg_kernel<<<aggBlocks, 256, 0, stream>>>(Pb, rowptr, rowmid, ssrc, dinv, b1, Xb, nN);
    // layer 2
    gemm_mfma_kernel<<<gemmBlocks, 256, 0, stream>>>(Xb, Wt2, dinv, (unsigned int*)Pb, nN);
    agg_kernel<<<aggBlocks, 256, 0, stream>>>(Pb, rowptr, rowmid, ssrc, dinv, b2, Xb, nN);

    // pool + LSTM + FC
    hipMemsetAsync(psum, 0, (size_t)nG * HID * sizeof(float), stream);
    pool_partial<<<(nN + 63) / 64, 256, 0, stream>>>((const unsigned int*)Xb, batch, psum, nN);
    pool_finalize<<<nG, 128, 0, stream>>>(psum, batch, pooled, nN);
    lstm_fc_kernel<<<nG, 128, 0, stream>>>(pooled, W_ih, b_ih, b_hh, W_fc, b_fc, out);
}

// Round 9
// 466.213 us; speedup vs baseline: 2.4598x; 1.0265x over previous
//
#include <hip/hip_runtime.h>
#include <math.h>
#include <stdint.h>

#define HID 128
#define SCAN_CHUNK 1024   // elements per scan block (256 thr x 4)
#define NBUCK_MAX 512     // node buckets of 256 nodes each (nN<=131072)
#define EDGE_TILE 8192    // edges per block in bucket passes
#define GEMM_ROWS 128     // M-tile per block (layer-0 gemm)
#define XS_STRIDE 136     // bf16 elems per LDS row (128 + 8 pad)

typedef short bf16x8 __attribute__((ext_vector_type(8)));
typedef float f32x4 __attribute__((ext_vector_type(4)));

// ---------------------------------------------------------------------------
// round-to-nearest-even fp32 -> bf16 bits
__device__ __forceinline__ unsigned int f2bf(float f) {
    union { float f; uint32_t i; } u; u.f = f;
    uint32_t r = u.i + 0x7fffu + ((u.i >> 16) & 1u);
    return r >> 16;
}

// ---------------------------------------------------------------------------
// Hierarchical scan, phase 1: per-block sums of cnt + fused dinv
__global__ __launch_bounds__(256) void scan_phase1(const int* __restrict__ cnt,
                                                   int* __restrict__ blockSums,
                                                   float* __restrict__ dinv, int nN) {
    __shared__ int sdata[256];
    const int t = threadIdx.x;
    const int idx = blockIdx.x * SCAN_CHUNK + t * 4;
    int v0 = 0, v1 = 0, v2 = 0, v3 = 0;
    if (idx + 3 < nN) {
        int4 v = *(const int4*)(cnt + idx);
        v0 = v.x; v1 = v.y; v2 = v.z; v3 = v.w;
        float4 dv;
        dv.x = rsqrtf((float)v0 + 1.0f);
        dv.y = rsqrtf((float)v1 + 1.0f);
        dv.z = rsqrtf((float)v2 + 1.0f);
        dv.w = rsqrtf((float)v3 + 1.0f);
        *(float4*)(dinv + idx) = dv;
    } else {
        if (idx     < nN) { v0 = cnt[idx];     dinv[idx]     = rsqrtf((float)v0 + 1.0f); }
        if (idx + 1 < nN) { v1 = cnt[idx + 1]; dinv[idx + 1] = rsqrtf((float)v1 + 1.0f); }
        if (idx + 2 < nN) { v2 = cnt[idx + 2]; dinv[idx + 2] = rsqrtf((float)v2 + 1.0f); }
        if (idx + 3 < nN) { v3 = cnt[idx + 3]; dinv[idx + 3] = rsqrtf((float)v3 + 1.0f); }
    }
    sdata[t] = v0 + v1 + v2 + v3;
    __syncthreads();
#pragma unroll
    for (int off = 128; off > 0; off >>= 1) {
        if (t < off) sdata[t] += sdata[t + off];
        __syncthreads();
    }
    if (t == 0) blockSums[blockIdx.x] = sdata[0];
}

__global__ __launch_bounds__(256) void scan_phase2(int* __restrict__ blockSums, int nB) {
    __shared__ int sd[256];
    const int t = threadIdx.x;
    sd[t] = (t < nB) ? blockSums[t] : 0;
    __syncthreads();
#pragma unroll
    for (int off = 1; off < 256; off <<= 1) {
        int v = sd[t];
        int add = (t >= off) ? sd[t - off] : 0;
        __syncthreads();
        sd[t] = v + add;
        __syncthreads();
    }
    if (t < nB) blockSums[t] = (t > 0) ? sd[t - 1] : 0;  // exclusive
}

__global__ __launch_bounds__(256) void scan_phase3(const int* __restrict__ cnt,
                                                   const int* __restrict__ blockOffsets,
                                                   int* __restrict__ rowptr, int nN, int nE) {
    __shared__ int sdata[256];
    const int t = threadIdx.x;
    const int idx = blockIdx.x * SCAN_CHUNK + t * 4;
    int v0 = 0, v1 = 0, v2 = 0, v3 = 0;
    if (idx + 3 < nN) {
        int4 v = *(const int4*)(cnt + idx);
        v0 = v.x; v1 = v.y; v2 = v.z; v3 = v.w;
    } else {
        if (idx     < nN) v0 = cnt[idx];
        if (idx + 1 < nN) v1 = cnt[idx + 1];
        if (idx + 2 < nN) v2 = cnt[idx + 2];
        if (idx + 3 < nN) v3 = cnt[idx + 3];
    }
    sdata[t] = v0 + v1 + v2 + v3;
    __syncthreads();
#pragma unroll
    for (int off = 1; off < 256; off <<= 1) {
        int v = sdata[t];
        int add = (t >= off) ? sdata[t - off] : 0;
        __syncthreads();
        sdata[t] = v + add;
        __syncthreads();
    }
    const int pre = blockOffsets[blockIdx.x] + ((t > 0) ? sdata[t - 1] : 0);
    if (idx + 3 < nN) {
        *(int4*)(rowptr + idx) = make_int4(pre, pre + v0, pre + v0 + v1, pre + v0 + v1 + v2);
    } else {
        if (idx     < nN) rowptr[idx]     = pre;
        if (idx + 1 < nN) rowptr[idx + 1] = pre + v0;
        if (idx + 2 < nN) rowptr[idx + 2] = pre + v0 + v1;
        if (idx + 3 < nN) rowptr[idx + 3] = pre + v0 + v1 + v2;
    }
    if (blockIdx.x == 0 && t == 0) rowptr[nN] = nE;
}

// ---------------------------------------------------------------------------
// Multisplit CSR build. Bucket = dst >> 8. ebuf entry = (src<<8)|(dst&255).
__global__ __launch_bounds__(256) void bucket_count(const int* __restrict__ dst,
                                                    int* __restrict__ bcnt, int nE, int nB) {
    __shared__ int h[NBUCK_MAX];
    for (int i = threadIdx.x; i < nB; i += 256) h[i] = 0;
    __syncthreads();
    const int base = blockIdx.x * EDGE_TILE;
    const int end = min(base + EDGE_TILE, nE);
    for (int e = base + threadIdx.x; e < end; e += 256)
        atomicAdd(&h[dst[e] >> 8], 1);
    __syncthreads();
    for (int i = threadIdx.x; i < nB; i += 256)
        if (h[i]) atomicAdd(&bcnt[i], h[i]);
}

__global__ __launch_bounds__(512) void bucket_scan(const int* __restrict__ bcnt,
                                                   int* __restrict__ boff,
                                                   int* __restrict__ bcur, int nB) {
    __shared__ int sd[512];
    const int t = threadIdx.x;
    sd[t] = (t < nB) ? bcnt[t] : 0;
    __syncthreads();
#pragma unroll
    for (int off = 1; off < 512; off <<= 1) {
        int v = sd[t];
        int add = (t >= off) ? sd[t - off] : 0;
        __syncthreads();
        sd[t] = v + add;
        __syncthreads();
    }
    if (t < nB) {
        int ex = (t > 0) ? sd[t - 1] : 0;
        boff[t] = ex;
        bcur[t] = ex;
    }
}

__global__ __launch_bounds__(256) void bucket_scatter(const int* __restrict__ src,
                                                      const int* __restrict__ dst,
                                                      int* __restrict__ bcur,
                                                      unsigned int* __restrict__ ebuf,
                                                      int nE, int nB) {
    __shared__ int h[NBUCK_MAX];
    __shared__ int basearr[NBUCK_MAX];
    const int base = blockIdx.x * EDGE_TILE;
    const int end = min(base + EDGE_TILE, nE);
    for (int i = threadIdx.x; i < nB; i += 256) h[i] = 0;
    __syncthreads();
    for (int e = base + threadIdx.x; e < end; e += 256)
        atomicAdd(&h[dst[e] >> 8], 1);
    __syncthreads();
    for (int i = threadIdx.x; i < nB; i += 256) {
        int c = h[i];
        basearr[i] = c ? atomicAdd(&bcur[i], c) : 0;
        h[i] = 0;   // reuse as local cursor
    }
    __syncthreads();
    for (int e = base + threadIdx.x; e < end; e += 256) {
        int d = dst[e];
        int b = d >> 8;
        int pos = basearr[b] + atomicAdd(&h[b], 1);
        ebuf[pos] = ((unsigned)src[e] << 8) | ((unsigned)d & 255u);
    }
}

// per-bucket node-degree histogram from bucket-sorted ebuf
__global__ __launch_bounds__(256) void node_count(const unsigned int* __restrict__ ebuf,
                                                  const int* __restrict__ boff,
                                                  int* __restrict__ cnt, int nE, int nB, int nN) {
    __shared__ int h[256];
    h[threadIdx.x] = 0;
    __syncthreads();
    const int b = blockIdx.x;
    const int e0 = boff[b];
    const int e1 = (b + 1 < nB) ? boff[b + 1] : nE;
    for (int e = e0 + threadIdx.x; e < e1; e += 256)
        atomicAdd(&h[ebuf[e] & 255u], 1);
    __syncthreads();
    const int v = b * 256 + threadIdx.x;
    if (v < nN) cnt[v] = h[threadIdx.x];
}

// single-pass final CSR scatter; dst window per bucket is ~16 KB (cache-resident)
__global__ __launch_bounds__(256) void csr_from_buckets(const unsigned int* __restrict__ ebuf,
                                                        const int* __restrict__ boff,
                                                        const int* __restrict__ rowptr,
                                                        int* __restrict__ ssrc, int nE, int nB) {
    __shared__ int cur[256];
    const int b = blockIdx.x;
    const int e0 = boff[b];
    const int e1 = (b + 1 < nB) ? boff[b + 1] : nE;
    const int nodeBase = b * 256;
    cur[threadIdx.x] = 0;
    __syncthreads();
    for (int e = e0 + threadIdx.x; e < e1; e += 256) {
        unsigned int ed = ebuf[e];
        int li = (int)(ed & 255u);
        int pos = rowptr[nodeBase + li] + atomicAdd(&cur[li], 1);
        ssrc[pos] = (int)(ed >> 8);
    }
}

// ---------------------------------------------------------------------------
// transpose+convert 3 weight matrices: Wt[n][k] = bf16(W[k][n]); 3 x 128 x 128
__global__ __launch_bounds__(256) void wt_kernel(const float* __restrict__ W0,
                                                 const float* __restrict__ W1,
                                                 const float* __restrict__ W2,
                                                 unsigned short* __restrict__ Wtb) {
    int i = blockIdx.x * 256 + threadIdx.x;   // 0..49151
    if (i < 3 * HID * HID) {
        int w = i >> 14, r = i & 16383;
        int n = r >> 7, k = r & 127;
        const float* W = (w == 0) ? W0 : (w == 1) ? W1 : W2;
        Wtb[i] = (unsigned short)f2bf(W[k * HID + n]);
    }
}

// ---------------------------------------------------------------------------
// Layer-0 MFMA GEMM with fused fp32->bf16 input conversion.
// Pb = bf16(dinv ⊙ (bf16(X) @ W)), fp32 accumulate.
__global__ __launch_bounds__(256) void gemm_mfma_f32in(const float* __restrict__ X,
                                                       const uint4* __restrict__ Wtb,
                                                       const float* __restrict__ dinv,
                                                       unsigned int* __restrict__ Pb32,
                                                       int nN) {
    __shared__ short Xs[GEMM_ROWS * XS_STRIDE];
    __shared__ short Ws[HID * XS_STRIDE];
    const int tid = threadIdx.x;
    const int rowBase = blockIdx.x * GEMM_ROWS;
#pragma unroll
    for (int it = 0; it < 16; ++it) {  // 4096 float4 X-tile, convert to bf16
        int f = it * 256 + tid;
        int row = f >> 5, c = f & 31;
        int grow = rowBase + row;
        float4 v = make_float4(0.f, 0.f, 0.f, 0.f);
        if (grow < nN) v = *(const float4*)(X + (size_t)grow * HID + c * 4);
        uint2 o;
        o.x = f2bf(v.x) | (f2bf(v.y) << 16);
        o.y = f2bf(v.z) | (f2bf(v.w) << 16);
        *(uint2*)(&Xs[row * XS_STRIDE + c * 4]) = o;
    }
#pragma unroll
    for (int it = 0; it < 8; ++it) {   // 2048 uint4 W-tile
        int f = it * 256 + tid;
        int n = f >> 4, c = f & 15;
        *(uint4*)(&Ws[n * XS_STRIDE + c * 8]) = Wtb[f];
    }
    __syncthreads();
    const int wave = tid >> 6, lane = tid & 63;
    const int quad = lane >> 4, l16 = lane & 15;
    f32x4 acc[2][8] = {};
    const int kq = quad * 8;
#pragma unroll
    for (int ks = 0; ks < 4; ++ks) {
        const int k0 = ks * 32 + kq;
        bf16x8 a0 = *(const bf16x8*)(&Xs[(wave * 32 + l16) * XS_STRIDE + k0]);
        bf16x8 a1 = *(const bf16x8*)(&Xs[(wave * 32 + 16 + l16) * XS_STRIDE + k0]);
#pragma unroll
        for (int nt = 0; nt < 8; ++nt) {
            bf16x8 b = *(const bf16x8*)(&Ws[(nt * 16 + l16) * XS_STRIDE + k0]);
            acc[0][nt] = __builtin_amdgcn_mfma_f32_16x16x32_bf16(a0, b, acc[0][nt], 0, 0, 0);
            acc[1][nt] = __builtin_amdgcn_mfma_f32_16x16x32_bf16(a1, b, acc[1][nt], 0, 0, 0);
        }
    }
#pragma unroll
    for (int mt = 0; mt < 2; ++mt) {
        const int gr0 = rowBase + wave * 32 + mt * 16 + quad * 4;
#pragma unroll
        for (int r = 0; r < 4; ++r) {
            const int gr = gr0 + r;
            const bool ok = gr < nN;
            const float d = ok ? dinv[gr] : 0.f;
#pragma unroll
            for (int nt = 0; nt < 8; ++nt) {
                float v = d * acc[mt][nt][r];
                float vo = __shfl_xor(v, 1, 64);
                if (ok && !(l16 & 1)) {
                    Pb32[(size_t)gr * 64 + nt * 8 + (l16 >> 1)] = f2bf(v) | (f2bf(vo) << 16);
                }
            }
        }
    }
}

// ---------------------------------------------------------------------------
// unpack 8 bf16 (uint4) and accumulate into 8 fp32
__device__ __forceinline__ void acc_bf8(const uint4 q, float* a) {
    union { uint32_t i; float f; } t;
    t.i = q.x << 16;          a[0] += t.f;
    t.i = q.x & 0xffff0000u;  a[1] += t.f;
    t.i = q.y << 16;          a[2] += t.f;
    t.i = q.y & 0xffff0000u;  a[3] += t.f;
    t.i = q.z << 16;          a[4] += t.f;
    t.i = q.z & 0xffff0000u;  a[5] += t.f;
    t.i = q.w << 16;          a[6] += t.f;
    t.i = q.w & 0xffff0000u;  a[7] += t.f;
}

// Fused agg + next-layer GEMM:
// h[v] = relu(dinv[v]*(P[v] + sum_in P[src]) + b)   (gather phase, registers)
// Pout[v] = bf16(dinv[v] * (h @ Wnext)[v])          (LDS h-tile + MFMA)
// Block = 256 threads = 16 nodes (16 lanes each); 4 waves each do m16 x n32.
__global__ __launch_bounds__(256) void fused_agg_gemm(const uint4* __restrict__ Pb,
                                                      const int* __restrict__ rowptr,
                                                      const int* __restrict__ ssrc,
                                                      const float* __restrict__ dinv,
                                                      const float* __restrict__ bias,
                                                      const uint4* __restrict__ Wtb,
                                                      unsigned int* __restrict__ Pout32,
                                                      int nN) {
    __shared__ short Ws[HID * XS_STRIDE];  // 34816 B
    __shared__ short Hs[16 * XS_STRIDE];   //  4352 B
    const int tid = threadIdx.x;
#pragma unroll
    for (int it = 0; it < 8; ++it) {       // stage W (2048 uint4)
        int f = it * 256 + tid;
        int n = f >> 4, c = f & 15;
        *(uint4*)(&Ws[n * XS_STRIDE + c * 8]) = Wtb[f];
    }
    const int lane16 = tid & 15;
    const int grp = tid >> 4;
    const int v = blockIdx.x * 16 + grp;
    const bool ok = v < nN;
    float a0[8], a1[8], a2[8], a3[8];
#pragma unroll
    for (int i = 0; i < 8; ++i) { a0[i] = 0.f; a1[i] = 0.f; a2[i] = 0.f; a3[i] = 0.f; }
    uint4 q = make_uint4(0u, 0u, 0u, 0u);
    if (ok) {
        acc_bf8(Pb[(size_t)v * 16 + lane16], a0);  // self loop
        int e = rowptr[v];
        const int e1 = rowptr[v + 1];
        for (; e + 4 <= e1; e += 4) {
            const int u0 = ssrc[e + 0], u1 = ssrc[e + 1], u2 = ssrc[e + 2], u3 = ssrc[e + 3];
            uint4 q0 = Pb[(size_t)u0 * 16 + lane16];
            uint4 q1 = Pb[(size_t)u1 * 16 + lane16];
            uint4 q2 = Pb[(size_t)u2 * 16 + lane16];
            uint4 q3 = Pb[(size_t)u3 * 16 + lane16];
            acc_bf8(q0, a0); acc_bf8(q1, a1); acc_bf8(q2, a2); acc_bf8(q3, a3);
        }
        for (; e < e1; ++e) {
            uint4 qe = Pb[(size_t)ssrc[e] * 16 + lane16];
            acc_bf8(qe, a1);
        }
        const float dv = dinv[v];
        const float4 bb0 = ((const float4*)bias)[lane16 * 2];
        const float4 bb1 = ((const float4*)bias)[lane16 * 2 + 1];
        float4 o0, o1;
        o0.x = fmaxf(fmaf(dv, (a0[0] + a1[0]) + (a2[0] + a3[0]), bb0.x), 0.f);
        o0.y = fmaxf(fmaf(dv, (a0[1] + a1[1]) + (a2[1] + a3[1]), bb0.y), 0.f);
        o0.z = fmaxf(fmaf(dv, (a0[2] + a1[2]) + (a2[2] + a3[2]), bb0.z), 0.f);
        o0.w = fmaxf(fmaf(dv, (a0[3] + a1[3]) + (a2[3] + a3[3]), bb0.w), 0.f);
        o1.x = fmaxf(fmaf(dv, (a0[4] + a1[4]) + (a2[4] + a3[4]), bb1.x), 0.f);
        o1.y = fmaxf(fmaf(dv, (a0[5] + a1[5]) + (a2[5] + a3[5]), bb1.y), 0.f);
        o1.z = fmaxf(fmaf(dv, (a0[6] + a1[6]) + (a2[6] + a3[6]), bb1.z), 0.f);
        o1.w = fmaxf(fmaf(dv, (a0[7] + a1[7]) + (a2[7] + a3[7]), bb1.w), 0.f);
        q.x = f2bf(o0.x) | (f2bf(o0.y) << 16);
        q.y = f2bf(o0.z) | (f2bf(o0.w) << 16);
        q.z = f2bf(o1.x) | (f2bf(o1.y) << 16);
        q.w = f2bf(o1.z) | (f2bf(o1.w) << 16);
    }
    *(uint4*)(&Hs[grp * XS_STRIDE + lane16 * 8]) = q;  // bf16 h row tile
    __syncthreads();
    // MFMA: each wave computes the 16-row tile x its 32 cols
    const int wave = tid >> 6, lane = tid & 63;
    const int quad = lane >> 4, l16 = lane & 15;
    f32x4 acc[2] = {};
#pragma unroll
    for (int ks = 0; ks < 4; ++ks) {
        const int k0 = ks * 32 + quad * 8;
        bf16x8 a = *(const bf16x8*)(&Hs[l16 * XS_STRIDE + k0]);
#pragma unroll
        for (int nt = 0; nt < 2; ++nt) {
            bf16x8 b = *(const bf16x8*)(&Ws[((wave * 2 + nt) * 16 + l16) * XS_STRIDE + k0]);
            acc[nt] = __builtin_amdgcn_mfma_f32_16x16x32_bf16(a, b, acc[nt], 0, 0, 0);
        }
    }
#pragma unroll
    for (int r = 0; r < 4; ++r) {
        const int gr = blockIdx.x * 16 + quad * 4 + r;
        const bool okr = gr < nN;
        const float d = okr ? dinv[gr] : 0.f;
#pragma unroll
        for (int nt = 0; nt < 2; ++nt) {
            float val = d * acc[nt][r];
            float vo = __shfl_xor(val, 1, 64);
            if (okr && !(l16 & 1)) {
                Pout32[(size_t)gr * 64 + (wave * 2 + nt) * 8 + (l16 >> 1)] =
                    f2bf(val) | (f2bf(vo) << 16);
            }
        }
    }
}

// Plain agg (final layer): h -> bf16 Xb for pooling.
__global__ __launch_bounds__(256) void agg_kernel(const uint4* __restrict__ Pb,
                                                  const int* __restrict__ rowptr,
                                                  const int* __restrict__ ssrc,
                                                  const float* __restrict__ dinv,
                                                  const float* __restrict__ bias,
                                                  uint4* __restrict__ Xb_out, int nN) {
    const int lane = threadIdx.x & 15;
    const int grp = threadIdx.x >> 4;
    const int v = blockIdx.x * 16 + grp;
    if (v >= nN) return;
    float a0[8], a1[8], a2[8], a3[8];
#pragma unroll
    for (int i = 0; i < 8; ++i) { a0[i] = 0.f; a1[i] = 0.f; a2[i] = 0.f; a3[i] = 0.f; }
    acc_bf8(Pb[(size_t)v * 16 + lane], a0);  // self loop
    int e = rowptr[v];
    const int e1 = rowptr[v + 1];
    for (; e + 4 <= e1; e += 4) {
        const int u0 = ssrc[e + 0], u1 = ssrc[e + 1], u2 = ssrc[e + 2], u3 = ssrc[e + 3];
        uint4 q0 = Pb[(size_t)u0 * 16 + lane];
        uint4 q1 = Pb[(size_t)u1 * 16 + lane];
        uint4 q2 = Pb[(size_t)u2 * 16 + lane];
        uint4 q3 = Pb[(size_t)u3 * 16 + lane];
        acc_bf8(q0, a0); acc_bf8(q1, a1); acc_bf8(q2, a2); acc_bf8(q3, a3);
    }
    for (; e < e1; ++e) {
        uint4 q = Pb[(size_t)ssrc[e] * 16 + lane];
        acc_bf8(q, a1);
    }
    const float dv = dinv[v];
    const float4 bb0 = ((const float4*)bias)[lane * 2];
    const float4 bb1 = ((const float4*)bias)[lane * 2 + 1];
    float4 o0, o1;
    o0.x = fmaxf(fmaf(dv, (a0[0] + a1[0]) + (a2[0] + a3[0]), bb0.x), 0.f);
    o0.y = fmaxf(fmaf(dv, (a0[1] + a1[1]) + (a2[1] + a3[1]), bb0.y), 0.f);
    o0.z = fmaxf(fmaf(dv, (a0[2] + a1[2]) + (a2[2] + a3[2]), bb0.z), 0.f);
    o0.w = fmaxf(fmaf(dv, (a0[3] + a1[3]) + (a2[3] + a3[3]), bb0.w), 0.f);
    o1.x = fmaxf(fmaf(dv, (a0[4] + a1[4]) + (a2[4] + a3[4]), bb1.x), 0.f);
    o1.y = fmaxf(fmaf(dv, (a0[5] + a1[5]) + (a2[5] + a3[5]), bb1.y), 0.f);
    o1.z = fmaxf(fmaf(dv, (a0[6] + a1[6]) + (a2[6] + a3[6]), bb1.z), 0.f);
    o1.w = fmaxf(fmaf(dv, (a0[7] + a1[7]) + (a2[7] + a3[7]), bb1.w), 0.f);
    uint4 q;
    q.x = f2bf(o0.x) | (f2bf(o0.y) << 16);
    q.y = f2bf(o0.z) | (f2bf(o0.w) << 16);
    q.z = f2bf(o1.x) | (f2bf(o1.y) << 16);
    q.w = f2bf(o1.z) | (f2bf(o1.w) << 16);
    Xb_out[(size_t)v * 16 + lane] = q;
}

// ---------------------------------------------------------------------------
// global mean pool over bf16 rows, phase 1: coalesced partial sums.
__global__ __launch_bounds__(256) void pool_partial(const unsigned int* __restrict__ Xb32,
                                                    const int* __restrict__ batch,
                                                    float* __restrict__ psum, int nN) {
    const int c2 = threadIdx.x & 63;
    int n = blockIdx.x * 64 + (threadIdx.x >> 6);
    const int nEnd = min(blockIdx.x * 64 + 64, nN);
    float acc0 = 0.f, acc1 = 0.f;
    int g = -1;
    for (; n < nEnd; n += 4) {
        int gn = batch[n];
        unsigned int q = Xb32[(size_t)n * 64 + c2];
        union { uint32_t i; float f; } lo, hi;
        lo.i = q << 16; hi.i = q & 0xffff0000u;
        if (gn != g) {
            if (g >= 0) {
                atomicAdd(&psum[g * HID + c2 * 2], acc0);
                atomicAdd(&psum[g * HID + c2 * 2 + 1], acc1);
            }
            g = gn;
            acc0 = lo.f; acc1 = hi.f;
        } else {
            acc0 += lo.f; acc1 += hi.f;
        }
    }
    if (g >= 0) {
        atomicAdd(&psum[g * HID + c2 * 2], acc0);
        atomicAdd(&psum[g * HID + c2 * 2 + 1], acc1);
    }
}

__global__ __launch_bounds__(128) void pool_finalize(const float* __restrict__ psum,
                                                     const int* __restrict__ batch,
                                                     float* __restrict__ pooled, int nN) {
    const int g = blockIdx.x;
    int lo = 0, hi = nN;
    while (lo < hi) { int m = (lo + hi) >> 1; if (batch[m] < g) lo = m + 1; else hi = m; }
    const int start = lo;
    hi = nN;
    while (lo < hi) { int m = (lo + hi) >> 1; if (batch[m] < g + 1) lo = m + 1; else hi = m; }
    const float c = (float)max(lo - start, 1);
    pooled[g * HID + threadIdx.x] = psum[g * HID + threadIdx.x] / c;
}

// ---------------------------------------------------------------------------
// single-step LSTM from zero state + FC(2); f-gate irrelevant (c0=0)
__device__ __forceinline__ float sigmoidf_(float x) { return 1.0f / (1.0f + expf(-x)); }

__global__ __launch_bounds__(128) void lstm_fc_kernel(const float* __restrict__ pooled,
                                                      const float* __restrict__ W_ih,
                                                      const float* __restrict__ b_ih,
                                                      const float* __restrict__ b_hh,
                                                      const float* __restrict__ W_fc,
                                                      const float* __restrict__ b_fc,
                                                      float* __restrict__ out) {
    __shared__ float pv[HID];
    __shared__ float r0[2], r1[2];
    const int g = blockIdx.x, j = threadIdx.x;
    pv[j] = pooled[g * HID + j];
    __syncthreads();
    float di = b_ih[j] + b_hh[j];
    float dg = b_ih[256 + j] + b_hh[256 + j];
    float dO = b_ih[384 + j] + b_hh[384 + j];
    const float4* pv4 = (const float4*)pv;
#pragma unroll 4
    for (int k4 = 0; k4 < 32; ++k4) {
        float4 p = pv4[k4];
        float4 wi = *(const float4*)(W_ih + (size_t)j * HID + k4 * 4);
        float4 wg = *(const float4*)(W_ih + (size_t)(256 + j) * HID + k4 * 4);
        float4 wo = *(const float4*)(W_ih + (size_t)(384 + j) * HID + k4 * 4);
        di += p.x * wi.x + p.y * wi.y + p.z * wi.z + p.w * wi.w;
        dg += p.x * wg.x + p.y * wg.y + p.z * wg.z + p.w * wg.w;
        dO += p.x * wo.x + p.y * wo.y + p.z * wo.z + p.w * wo.w;
    }
    float c = sigmoidf_(di) * tanhf(dg);
    float hn = sigmoidf_(dO) * tanhf(c);
    float p0 = hn * W_fc[j];
    float p1 = hn * W_fc[HID + j];
#pragma unroll
    for (int off = 32; off > 0; off >>= 1) {
        p0 += __shfl_down(p0, off, 64);
        p1 += __shfl_down(p1, off, 64);
    }
    const int w = j >> 6, l = j & 63;
    if (l == 0) { r0[w] = p0; r1[w] = p1; }
    __syncthreads();
    if (j == 0) {
        out[g * 2 + 0] = r0[0] + r0[1] + b_fc[0];
        out[g * 2 + 1] = r1[0] + r1[1] + b_fc[1];
    }
}

// ---------------------------------------------------------------------------
extern "C" void kernel_launch(void* const* d_in, const int* in_sizes, int n_in,
                              void* d_out, int out_size, void* d_ws, size_t ws_size,
                              hipStream_t stream) {
    const float* x      = (const float*)d_in[0];
    const int*   eidx   = (const int*)d_in[1];
    const int*   batch  = (const int*)d_in[2];
    const float* W0     = (const float*)d_in[4];
    const float* b0     = (const float*)d_in[5];
    const float* W1     = (const float*)d_in[6];
    const float* b1     = (const float*)d_in[7];
    const float* W2     = (const float*)d_in[8];
    const float* b2     = (const float*)d_in[9];
    const float* W_ih   = (const float*)d_in[10];
    const float* b_ih   = (const float*)d_in[12];
    const float* b_hh   = (const float*)d_in[13];
    const float* W_fc   = (const float*)d_in[14];
    const float* b_fc   = (const float*)d_in[15];
    float* out = (float*)d_out;

    const int nN = in_sizes[0] / HID;     // 100000
    const int nE = in_sizes[1] / 2;       // 1600000
    const int nG = out_size / 2;          // 256
    const int* src = eidx;
    const int* dst = eidx + nE;
    const int rowsPad = (nN + GEMM_ROWS - 1) & ~(GEMM_ROWS - 1);

    // workspace layout
    size_t off = 0;
    auto alloc = [&](size_t bytes) -> void* {
        void* p = (char*)d_ws + off;
        off += (bytes + 255) & ~(size_t)255;
        return p;
    };
    uint4* Pb     = (uint4*)alloc((size_t)nN * 16 * sizeof(uint4));   // bf16 P (ping)
    uint4* Pb2    = (uint4*)alloc((size_t)nN * 16 * sizeof(uint4));   // bf16 P (pong)
    uint4* Xb     = (uint4*)alloc((size_t)nN * 16 * sizeof(uint4));   // bf16 final h
    float* dinv   = (float*)alloc((size_t)nN * sizeof(float));
    int*   cnt    = (int*)alloc((size_t)nN * sizeof(int));
    int*   rowptr = (int*)alloc((size_t)(nN + 1) * sizeof(int));
    int*   ssrc   = (int*)alloc((size_t)nE * sizeof(int));
    unsigned int* ebuf = (unsigned int*)alloc((size_t)nE * sizeof(unsigned int));
    float* pooled = (float*)alloc((size_t)nG * HID * sizeof(float));
    float* psum   = (float*)alloc((size_t)nG * HID * sizeof(float));
    int*   blockSums = (int*)alloc(1024 * sizeof(int));
    int*   bcnt   = (int*)alloc(NBUCK_MAX * sizeof(int));
    int*   boff   = (int*)alloc(NBUCK_MAX * sizeof(int));
    int*   bcur   = (int*)alloc(NBUCK_MAX * sizeof(int));
    unsigned short* Wtb = (unsigned short*)alloc(3 * HID * HID * sizeof(unsigned short));
    (void)ws_size;

    const int scanBlocks = (nN + SCAN_CHUNK - 1) / SCAN_CHUNK;
    const int nB = (nN + 255) >> 8;
    const int tileBlocks = (nE + EDGE_TILE - 1) / EDGE_TILE;

    // multisplit: bucket-sort edges (packed 4B) by dst bucket
    hipMemsetAsync(bcnt, 0, NBUCK_MAX * sizeof(int), stream);
    bucket_count<<<tileBlocks, 256, 0, stream>>>(dst, bcnt, nE, nB);
    bucket_scan<<<1, 512, 0, stream>>>(bcnt, boff, bcur, nB);
    bucket_scatter<<<tileBlocks, 256, 0, stream>>>(src, dst, bcur, ebuf, nE, nB);

    // degrees + dinv + rowptr + CSR
    node_count<<<nB, 256, 0, stream>>>(ebuf, boff, cnt, nE, nB, nN);
    scan_phase1<<<scanBlocks, 256, 0, stream>>>(cnt, blockSums, dinv, nN);
    scan_phase2<<<1, 256, 0, stream>>>(blockSums, scanBlocks);
    scan_phase3<<<scanBlocks, 256, 0, stream>>>(cnt, blockSums, rowptr, nN, nE);
    csr_from_buckets<<<nB, 256, 0, stream>>>(ebuf, boff, rowptr, ssrc, nE, nB);

    // weights -> bf16 transposed
    wt_kernel<<<(3 * HID * HID + 255) / 256, 256, 0, stream>>>(W0, W1, W2, Wtb);

    const int gemmBlocks = rowsPad / GEMM_ROWS;
    const int aggBlocks = (nN + 15) / 16;
    const uint4* Wt1 = (const uint4*)(Wtb + HID * HID);
    const uint4* Wt2 = (const uint4*)(Wtb + 2 * HID * HID);

    // layer 0 GEMM (fp32 in), then fused agg0+gemm1, fused agg1+gemm2, plain agg2
    gemm_mfma_f32in<<<gemmBlocks, 256, 0, stream>>>(x, (const uint4*)Wtb, dinv,
                                                    (unsigned int*)Pb, nN);
    fused_agg_gemm<<<aggBlocks, 256, 0, stream>>>(Pb, rowptr, ssrc, dinv, b0, Wt1,
                                                  (unsigned int*)Pb2, nN);
    fused_agg_gemm<<<aggBlocks, 256, 0, stream>>>(Pb2, rowptr, ssrc, dinv, b1, Wt2,
                                                  (unsigned int*)Pb, nN);
    agg_kernel<<<aggBlocks, 256, 0, stream>>>(Pb, rowptr, ssrc, dinv, b2, Xb, nN);

    // pool + LSTM + FC
    hipMemsetAsync(psum, 0, (size_t)nG * HID * sizeof(float), stream);
    pool_partial<<<(nN + 63) / 64, 256, 0, stream>>>((const unsigned int*)Xb, batch, psum, nN);
    pool_finalize<<<nG, 128, 0, stream>>>(psum, batch, pooled, nN);
    lstm_fc_kernel<<<nG, 128, 0, stream>>>(pooled, W_ih, b_ih, b_hh, W_fc, b_fc, out);
}